// Round 1
// baseline (464.905 us; speedup 1.0000x reference)
//
#include <hip/hip_runtime.h>
#include <math.h>

#define BB 4
#define CINC 64
#define HH 128
#define WW 128
#define KK 9
#define HW (HH*WW)       // 16384
#define LSEQ (HH*WW)     // 16384
#define NCH 256          // chunks per batch
#define CLEN 64          // chunk length

// ---------------- workspace layout (in floats) ----------------
constexpr size_t OFF_RAW_O = 0;                      // (B,10,H,W)
constexpr size_t OFF_RAW_N = (size_t)BB*10*HW;
constexpr size_t YSEQ_O = OFF_RAW_O + OFF_RAW_N;     // (B,L,9)
constexpr size_t YSEQ_N = (size_t)BB*LSEQ*9;
constexpr size_t YNEW_O = YSEQ_O + YSEQ_N;           // (B,9,H,W)
constexpr size_t YNEW_N = (size_t)BB*9*HW;
constexpr size_t GN1_O = YNEW_O + YNEW_N;            // 20*(mu,inv)
constexpr size_t GN1_N = 64;
constexpr size_t CH18 = (size_t)BB*LSEQ*18;
constexpr size_t CH16 = (size_t)BB*LSEQ*16;
constexpr size_t DT_O = GN1_O + GN1_N;
constexpr size_t XI_O = DT_O + CH18;
constexpr size_t ZZ_O = XI_O + CH18;
constexpr size_t BS_O = ZZ_O + CH18;
constexpr size_t CS_O = BS_O + CH16;
constexpr size_t CARR = (size_t)BB*NCH*288;
constexpr size_t CP_O = CS_O + CH16;
constexpr size_t CHC_O = CP_O + CARR;
constexpr size_t HIN_O = CHC_O + CARR;
constexpr size_t YS_O = HIN_O + CARR;                // (B,L,18)
constexpr size_t YFIN_O = YS_O + CH18;               // (B,9,H,W)
constexpr size_t XT_O = YFIN_O + YNEW_N;             // (B,H,W,64)
constexpr size_t XT_N = (size_t)BB*HW*64;
constexpr size_t OUTPRE_O = XT_O + XT_N;             // (B,64,H,W)
constexpr size_t WT_O = OUTPRE_O + XT_N;             // (9,64,64) [k][ci][co]
constexpr size_t WOFF_O = WT_O + 9*64*64;            // (64,3,3,10) [ci][dy][dx][co]
constexpr size_t AMAT_O = WOFF_O + 64*9*10;          // (18,16)
constexpr size_t GN2_O = AMAT_O + 288;               // 64*(mu,inv)
constexpr size_t WS_TOTAL = GN2_O + 128;

// ---------------- K0: weight transposes + A matrix ----------------
__global__ void prep_kernel(const float* __restrict__ dsc_w, const float* __restrict__ offw,
                            const float* __restrict__ A_log,
                            float* __restrict__ wT, float* __restrict__ woffT,
                            float* __restrict__ Amat){
  int i = blockIdx.x*blockDim.x + threadIdx.x;
  if(i < 9*64*64){
    int k = i/(64*64); int r = i%(64*64); int ci = r/64; int co = r%64;
    wT[i] = dsc_w[((size_t)(co*64 + ci))*9 + k];   // dsc_w (co,ci,9,1)
  }
  int j = i - 9*64*64;
  if(j >= 0 && j < 64*9*10){
    int co = j%10; int r2 = j/10; int dx = r2%3; int r3 = r2/3; int dy = r3%3; int ci = r3/3;
    woffT[j] = offw[((size_t)(co*64 + ci)*3 + dy)*3 + dx]; // offw (18,64,3,3), co<10
  }
  int a = i - (9*64*64 + 64*9*10);
  if(a >= 0 && a < 288) Amat[a] = -expf(A_log[a]);
}

// ---------------- K1: x (B,C,H,W) -> xT (B,H,W,C) ----------------
__global__ __launch_bounds__(256) void transpose_x_kernel(const float* __restrict__ x,
                                                          float* __restrict__ xT){
  __shared__ float tile[64][65];
  int blk = blockIdx.x;            // B*H*2
  int w0 = (blk&1)*64;
  int h  = (blk>>1)&127;
  int b  = blk>>8;
  int lane = threadIdx.x&63, q = threadIdx.x>>6;
  #pragma unroll
  for(int r=0;r<16;r++){
    int ci = r*4 + q;
    tile[ci][lane] = x[((size_t)(b*64+ci)*HH + h)*WW + w0 + lane];
  }
  __syncthreads();
  #pragma unroll
  for(int r=0;r<16;r++){
    int w = r*4 + q;
    xT[(((size_t)(b*HH+h))*WW + w0 + w)*64 + lane] = tile[lane][w];
  }
}

// ---------------- K2: 3x3 offset conv (only out-ch 0..9) ----------------
__global__ __launch_bounds__(128) void off_conv_kernel(const float* __restrict__ x,
                                                       const float* __restrict__ woff,
                                                       const float* __restrict__ offb,
                                                       float* __restrict__ off_raw){
  __shared__ float lds[16][4][66];
  int blk = blockIdx.x;            // B * 64 * 2
  int w0 = (blk&1)*64;
  int h0 = ((blk>>1)&63)*2;
  int b  = blk>>7;
  int wl = threadIdx.x&63, hl = threadIdx.x>>6;     // hl 0..1
  float acc[10];
  #pragma unroll
  for(int c=0;c<10;c++) acc[c] = offb[c];
  for(int cc=0; cc<4; cc++){
    __syncthreads();
    for(int t=threadIdx.x; t<16*4*66; t+=128){
      int ci = t/(4*66); int rem = t%(4*66); int row = rem/66; int col = rem%66;
      int gh = h0-1+row, gw = w0-1+col;
      float v = 0.f;
      if(gh>=0 && gh<HH && gw>=0 && gw<WW)
        v = x[((size_t)(b*64+cc*16+ci)*HH + gh)*WW + gw];
      lds[ci][row][col] = v;
    }
    __syncthreads();
    for(int ci=0;ci<16;ci++){
      #pragma unroll
      for(int dy=0;dy<3;dy++){
        #pragma unroll
        for(int dx=0;dx<3;dx++){
          float xv = lds[ci][hl+dy][wl+dx];
          const float* wp = woff + (((cc*16+ci)*3+dy)*3+dx)*10;
          #pragma unroll
          for(int c=0;c<10;c++) acc[c] += xv*wp[c];
        }
      }
    }
  }
  int h = h0+hl;
  #pragma unroll
  for(int c=0;c<10;c++)
    off_raw[((size_t)(b*10+c)*HH + h)*WW + w0 + wl] = acc[c];
}

// ---------------- generic GroupNorm stats (contiguous groups) ----------------
__device__ inline float wave_red_sum(float v){
  #pragma unroll
  for(int off=32; off; off>>=1) v += __shfl_down(v, off, 64);
  return v;
}

__global__ __launch_bounds__(256) void gn_stats_kernel(const float* __restrict__ src,
                                                       float* __restrict__ out,
                                                       int per_grp, float eps){
  int g = blockIdx.x;
  const float* p = src + (size_t)g*per_grp;
  float s=0.f, s2=0.f;
  for(int i=threadIdx.x; i<per_grp; i+=256){ float v = p[i]; s += v; s2 += v*v; }
  __shared__ float sh[4], sh2[4];
  s = wave_red_sum(s); s2 = wave_red_sum(s2);
  int w = threadIdx.x>>6;
  if((threadIdx.x&63)==0){ sh[w]=s; sh2[w]=s2; }
  __syncthreads();
  if(threadIdx.x==0){
    float S=0.f,S2=0.f;
    for(int i=0;i<4;i++){S+=sh[i];S2+=sh2[i];}
    float mu = S/per_grp;
    float var = S2/per_grp - mu*mu;
    out[g*2] = mu; out[g*2+1] = rsqrtf(var+eps);
  }
}

// ---------------- K4: GN1 apply + tanh + cumsum + zigzag ----------------
__global__ __launch_bounds__(256) void gn1_apply_kernel(const float* __restrict__ off_raw,
                                                        const float* __restrict__ stats,
                                                        const float* __restrict__ gno_g,
                                                        const float* __restrict__ gno_b,
                                                        float* __restrict__ yseq,
                                                        float* __restrict__ ynew){
  int idx = blockIdx.x*blockDim.x + threadIdx.x;   // BB*HW
  int b = idx>>14; int pix = idx&16383; int h = pix>>7, w = pix&127;
  float t[9];
  #pragma unroll
  for(int c=0;c<9;c++){
    float v = off_raw[((size_t)(b*10+c))*HW + pix];
    int g = b*5 + (c>>1);
    float mu = stats[g*2], inv = stats[g*2+1];
    t[c] = tanhf((v-mu)*inv*gno_g[c] + gno_b[c]);
  }
  int l = (((h>>1)*WW + w)<<1) | (h&1);
  float* yq = yseq + ((size_t)(b*LSEQ + l))*9;
  #pragma unroll
  for(int c=0;c<9;c++) yq[c] = t[c];
  float rows[9];
  rows[4]=0.f;
  rows[5]=t[5]; rows[6]=rows[5]+t[6]; rows[7]=rows[6]+t[7]; rows[8]=rows[7]+t[8];
  rows[3]=t[3]; rows[2]=rows[3]+t[2]; rows[1]=rows[2]+t[1]; rows[0]=rows[1]+t[0];
  #pragma unroll
  for(int k=0;k<9;k++) ynew[((size_t)(b*9+k))*HW + pix] = (float)h + rows[k];
}

// ---------------- K5: mamba featurize (parallel over l) ----------------
__global__ __launch_bounds__(256) void mamba_feat_kernel(
    const float* __restrict__ yseq, const float* __restrict__ in_proj_w,
    const float* __restrict__ conv_w, const float* __restrict__ conv_b,
    const float* __restrict__ x_proj_w, const float* __restrict__ dt_w,
    const float* __restrict__ dt_b,
    float* __restrict__ DT, float* __restrict__ XI, float* __restrict__ ZZ,
    float* __restrict__ BSp, float* __restrict__ CSp){
  __shared__ float s_in[36*9], s_cw[18*4], s_cb[18], s_xw[33*18], s_dw[18], s_db[18];
  for(int i=threadIdx.x;i<324;i+=256) s_in[i]=in_proj_w[i];
  for(int i=threadIdx.x;i<72;i+=256)  s_cw[i]=conv_w[i];
  for(int i=threadIdx.x;i<594;i+=256) s_xw[i]=x_proj_w[i];
  if(threadIdx.x<18){ s_cb[threadIdx.x]=conv_b[threadIdx.x];
                      s_dw[threadIdx.x]=dt_w[threadIdx.x];
                      s_db[threadIdx.x]=dt_b[threadIdx.x]; }
  __syncthreads();
  int idx = blockIdx.x*blockDim.x + threadIdx.x;
  int b = idx>>14, l = idx&16383;
  float ys4[4][9];
  #pragma unroll
  for(int t=0;t<4;t++){
    int lp = l-3+t;
    if(lp>=0){
      const float* p = yseq + ((size_t)(b*LSEQ+lp))*9;
      #pragma unroll
      for(int m=0;m<9;m++) ys4[t][m]=p[m];
    } else {
      #pragma unroll
      for(int m=0;m<9;m++) ys4[t][m]=0.f;
    }
  }
  float xi[18];
  #pragma unroll
  for(int d=0;d<18;d++){
    float cacc = s_cb[d];
    #pragma unroll
    for(int t=0;t<4;t++){
      float xr = 0.f;
      #pragma unroll
      for(int m=0;m<9;m++) xr += ys4[t][m]*s_in[d*9+m];
      cacc += xr * s_cw[d*4+t];
    }
    xi[d] = cacc / (1.f + expf(-cacc));     // silu
  }
  size_t base = (size_t)(b*LSEQ+l);
  float dblv[33];
  #pragma unroll
  for(int j=0;j<33;j++){
    float a=0.f;
    #pragma unroll
    for(int d=0;d<18;d++) a += xi[d]*s_xw[j*18+d];
    dblv[j]=a;
  }
  #pragma unroll
  for(int d=0;d<18;d++) XI[base*18+d]=xi[d];
  #pragma unroll
  for(int d=0;d<18;d++){
    float a=0.f;
    #pragma unroll
    for(int m=0;m<9;m++) a += ys4[3][m]*s_in[(18+d)*9+m];
    ZZ[base*18+d]=a;
    float pre = dblv[0]*s_dw[d] + s_db[d];
    DT[base*18+d] = fmaxf(pre,0.f) + log1pf(expf(-fabsf(pre)));   // softplus
  }
  #pragma unroll
  for(int s=0;s<16;s++){ BSp[base*16+s]=dblv[1+s]; CSp[base*16+s]=dblv[17+s]; }
}

// ---------------- K6: chunk scan from zero state ----------------
__global__ void scan_pass1(const float* __restrict__ DT, const float* __restrict__ XI,
                           const float* __restrict__ BSp, const float* __restrict__ Amat,
                           float* __restrict__ CP, float* __restrict__ CH){
  int blk = blockIdx.x; int b = blk/NCH; int c = blk%NCH;
  int t = threadIdx.x;                  // 288: d = t>>4, s = t&15
  int d = t>>4, s = t&15;
  float A = Amat[t];
  float h=0.f, P=1.f;
  int l0 = c*CLEN;
  #pragma unroll 4
  for(int st=0; st<CLEN; ++st){
    size_t base = (size_t)b*LSEQ + (l0+st);
    float dt  = DT[base*18+d];
    float xiv = XI[base*18+d];
    float Bv  = BSp[base*16+s];
    float a = expf(dt*A);
    h = a*h + dt*Bv*xiv;
    P *= a;
  }
  size_t o = ((size_t)(b*NCH+c))*288 + t;
  CP[o]=P; CH[o]=h;
}

// ---------------- K7: carry propagation across chunks ----------------
__global__ void scan_carry(const float* __restrict__ CP, const float* __restrict__ CH,
                           float* __restrict__ HIN){
  int b = blockIdx.x; int t = threadIdx.x;   // 288
  float h = 0.f;
  for(int c=0;c<NCH;c++){
    size_t o = ((size_t)(b*NCH+c))*288 + t;
    HIN[o] = h;
    h = CP[o]*h + CH[o];
  }
}

// ---------------- K8: chunk scan with true init + y output ----------------
__global__ void scan_pass2(const float* __restrict__ DT, const float* __restrict__ XI,
                           const float* __restrict__ BSp, const float* __restrict__ CSp,
                           const float* __restrict__ Amat, const float* __restrict__ HIN,
                           float* __restrict__ YSo){
  int blk = blockIdx.x; int b = blk/NCH; int c = blk%NCH;
  int t = threadIdx.x;
  int d = t>>4, s = t&15;
  float A = Amat[t];
  float h = HIN[((size_t)(b*NCH+c))*288 + t];
  int l0 = c*CLEN;
  #pragma unroll 2
  for(int st=0; st<CLEN; ++st){
    size_t base = (size_t)b*LSEQ + (l0+st);
    float dt  = DT[base*18+d];
    float xiv = XI[base*18+d];
    float Bv  = BSp[base*16+s];
    float Cv  = CSp[base*16+s];
    float a = expf(dt*A);
    h = a*h + dt*Bv*xiv;
    float pc = h*Cv;
    pc += __shfl_xor(pc,1,16);
    pc += __shfl_xor(pc,2,16);
    pc += __shfl_xor(pc,4,16);
    pc += __shfl_xor(pc,8,16);
    if(s==0) YSo[base*18+d] = pc;
  }
}

// ---------------- K9: mamba epilogue + y_final ----------------
__global__ __launch_bounds__(256) void mamba_out_kernel(
    const float* __restrict__ YSo, const float* __restrict__ XI,
    const float* __restrict__ ZZ, const float* __restrict__ Dp,
    const float* __restrict__ out_w, const float* __restrict__ altho,
    const float* __restrict__ ynew, float* __restrict__ yfin){
  __shared__ float s_ow[9*18], s_dp[18];
  for(int i=threadIdx.x;i<162;i+=256) s_ow[i]=out_w[i];
  if(threadIdx.x<18) s_dp[threadIdx.x]=Dp[threadIdx.x];
  __syncthreads();
  int idx = blockIdx.x*blockDim.x + threadIdx.x;
  int b = idx>>14, l = idx&16383;
  size_t base = (size_t)(b*LSEQ+l);
  float y[18];
  #pragma unroll
  for(int d=0;d<18;d++){
    float z = ZZ[base*18+d];
    float sz = z/(1.f+expf(-z));
    y[d] = (YSo[base*18+d] + s_dp[d]*XI[base*18+d]) * sz;
  }
  float av = altho[0];
  float sp = fmaxf(av,0.f)+log1pf(expf(-fabsf(av)));
  float wgt = fmaxf(sp, 0.01f);
  int h = ((l>>8)<<1) | (l&1);
  int w = (l>>1)&127;
  int pix = h*WW + w;
  #pragma unroll
  for(int m=0;m<9;m++){
    float a=0.f;
    #pragma unroll
    for(int d=0;d<18;d++) a += y[d]*s_ow[m*18+d];
    size_t o = ((size_t)(b*9+m))*HW + pix;
    yfin[o] = wgt*a + ynew[o];
  }
}

// ---------------- K10: fused bilinear sample + 9x1 stride-9 conv ----------------
__global__ __launch_bounds__(256) void sample_conv_kernel(
    const float* __restrict__ xT, const float* __restrict__ yfin,
    const float* __restrict__ wT, const float* __restrict__ bias,
    float* __restrict__ outpre){
  __shared__ float F[64*64];            // [ci][px]
  int blk = blockIdx.x;                 // B*128*2
  int wo0 = (blk&1)*64;
  int ho  = (blk>>1)&127;
  int b   = blk>>8;
  int lane = threadIdx.x&63;
  int wv   = threadIdx.x>>6;            // 0..3
  int co0  = __builtin_amdgcn_readfirstlane(wv*16);
  int wo = wo0 + lane;
  float acc[16];
  #pragma unroll
  for(int i=0;i<16;i++) acc[i]=0.f;
  for(int k=0;k<9;k++){
    // --- gather: wave wv produces ci chunk [wv*16, wv*16+16) for all 64 px
    float yv = yfin[((size_t)(b*9+k))*HW + ho*WW + wo];
    float py = fminf(fmaxf(yv,0.f),127.f);
    float y0f = floorf(py);
    float wy = py - y0f;
    int iy0 = (int)y0f;
    int iy1 = min(iy0+1,127);
    int xc  = min(max(wo + k - 4, 0), 127);
    const float* p0 = xT + (((size_t)(b*HH+iy0))*WW + xc)*64 + wv*16;
    const float* p1 = xT + (((size_t)(b*HH+iy1))*WW + xc)*64 + wv*16;
    #pragma unroll
    for(int q=0;q<4;q++){
      float4 v0 = *(const float4*)(p0 + q*4);
      float4 v1 = *(const float4*)(p1 + q*4);
      int ci = wv*16 + q*4;
      F[(ci  )*64 + lane] = v0.x + wy*(v1.x - v0.x);
      F[(ci+1)*64 + lane] = v0.y + wy*(v1.y - v0.y);
      F[(ci+2)*64 + lane] = v0.z + wy*(v1.z - v0.z);
      F[(ci+3)*64 + lane] = v0.w + wy*(v1.w - v0.w);
    }
    __syncthreads();
    // --- compute: wave wv accumulates co [co0, co0+16)
    const float* wk = wT + k*64*64;
    #pragma unroll 4
    for(int ci=0; ci<64; ci++){
      float fv = F[ci*64 + lane];
      const float4* w4 = (const float4*)(wk + ci*64 + co0);
      float4 wa = w4[0], wb = w4[1], wc = w4[2], wd = w4[3];
      acc[0]+=fv*wa.x;  acc[1]+=fv*wa.y;  acc[2]+=fv*wa.z;  acc[3]+=fv*wa.w;
      acc[4]+=fv*wb.x;  acc[5]+=fv*wb.y;  acc[6]+=fv*wb.z;  acc[7]+=fv*wb.w;
      acc[8]+=fv*wc.x;  acc[9]+=fv*wc.y;  acc[10]+=fv*wc.z; acc[11]+=fv*wc.w;
      acc[12]+=fv*wd.x; acc[13]+=fv*wd.y; acc[14]+=fv*wd.z; acc[15]+=fv*wd.w;
    }
    __syncthreads();
  }
  #pragma unroll
  for(int cc=0;cc<16;cc++){
    int co = co0+cc;
    outpre[((size_t)(b*64+co))*HW + ho*WW + wo] = acc[cc] + bias[co];
  }
}

// ---------------- K12: final GN apply ----------------
__global__ __launch_bounds__(256) void gn2_apply_kernel(const float* __restrict__ src,
                                                        const float* __restrict__ stats,
                                                        const float* __restrict__ gam,
                                                        const float* __restrict__ bet,
                                                        float* __restrict__ dst){
  int idx = blockIdx.x*blockDim.x + threadIdx.x;  // BB*64*HW
  int c = (idx>>14)&63;
  int g = idx>>16;                                // (b*64+c)>>2
  float mu = stats[g*2], inv = stats[g*2+1];
  dst[idx] = (src[idx]-mu)*inv*gam[c] + bet[c];
}

extern "C" void kernel_launch(void* const* d_in, const int* in_sizes, int n_in,
                              void* d_out, int out_size, void* d_ws, size_t ws_size,
                              hipStream_t stream){
  const float* x        = (const float*)d_in[0];
  const float* offset_w = (const float*)d_in[1];
  const float* offset_b = (const float*)d_in[2];
  const float* gno_g    = (const float*)d_in[3];
  const float* gno_b    = (const float*)d_in[4];
  const float* altho    = (const float*)d_in[5];
  const float* in_proj  = (const float*)d_in[6];
  const float* conv1d_w = (const float*)d_in[7];
  const float* conv1d_b = (const float*)d_in[8];
  const float* x_proj   = (const float*)d_in[9];
  const float* dt_w     = (const float*)d_in[10];
  const float* dt_b     = (const float*)d_in[11];
  const float* A_log    = (const float*)d_in[12];
  const float* D_p      = (const float*)d_in[13];
  const float* out_proj = (const float*)d_in[14];
  const float* dsc_w    = (const float*)d_in[15];
  const float* dsc_b    = (const float*)d_in[16];
  const float* gn_g     = (const float*)d_in[17];
  const float* gn_b     = (const float*)d_in[18];
  float* out = (float*)d_out;
  float* ws  = (float*)d_ws;
  if(ws_size < WS_TOTAL*sizeof(float)) return;   // refuse to corrupt memory

  float* off_raw = ws + OFF_RAW_O;
  float* yseq    = ws + YSEQ_O;
  float* ynew    = ws + YNEW_O;
  float* gn1     = ws + GN1_O;
  float* DT      = ws + DT_O;
  float* XI      = ws + XI_O;
  float* ZZ      = ws + ZZ_O;
  float* BSp     = ws + BS_O;
  float* CSp     = ws + CS_O;
  float* CP      = ws + CP_O;
  float* CH      = ws + CHC_O;
  float* HIN     = ws + HIN_O;
  float* YSo     = ws + YS_O;
  float* yfin    = ws + YFIN_O;
  float* xT      = ws + XT_O;
  float* outpre  = ws + OUTPRE_O;
  float* wT      = ws + WT_O;
  float* woffT   = ws + WOFF_O;
  float* Amat    = ws + AMAT_O;
  float* gn2     = ws + GN2_O;

  prep_kernel<<<dim3(168), dim3(256), 0, stream>>>(dsc_w, offset_w, A_log, wT, woffT, Amat);
  transpose_x_kernel<<<dim3(1024), dim3(256), 0, stream>>>(x, xT);
  off_conv_kernel<<<dim3(512), dim3(128), 0, stream>>>(x, woffT, offset_b, off_raw);
  gn_stats_kernel<<<dim3(20), dim3(256), 0, stream>>>(off_raw, gn1, 2*HW, 1e-5f);
  gn1_apply_kernel<<<dim3(256), dim3(256), 0, stream>>>(off_raw, gn1, gno_g, gno_b, yseq, ynew);
  mamba_feat_kernel<<<dim3(256), dim3(256), 0, stream>>>(yseq, in_proj, conv1d_w, conv1d_b,
                                                         x_proj, dt_w, dt_b,
                                                         DT, XI, ZZ, BSp, CSp);
  scan_pass1<<<dim3(BB*NCH), dim3(288), 0, stream>>>(DT, XI, BSp, Amat, CP, CH);
  scan_carry<<<dim3(BB), dim3(288), 0, stream>>>(CP, CH, HIN);
  scan_pass2<<<dim3(BB*NCH), dim3(288), 0, stream>>>(DT, XI, BSp, CSp, Amat, HIN, YSo);
  mamba_out_kernel<<<dim3(256), dim3(256), 0, stream>>>(YSo, XI, ZZ, D_p, out_proj, altho,
                                                        ynew, yfin);
  sample_conv_kernel<<<dim3(1024), dim3(256), 0, stream>>>(xT, yfin, wT, dsc_b, outpre);
  gn_stats_kernel<<<dim3(64), dim3(256), 0, stream>>>(outpre, gn2, 4*HW, 1e-5f);
  gn2_apply_kernel<<<dim3(16384), dim3(256), 0, stream>>>(outpre, gn2, gn_g, gn_b, out);
}

// Round 2
// 448.959 us; speedup vs baseline: 1.0355x; 1.0355x over previous
//
#include <hip/hip_runtime.h>
#include <math.h>

#define BB 4
#define CINC 64
#define HH 128
#define WW 128
#define KK 9
#define HW (HH*WW)       // 16384
#define LSEQ (HH*WW)     // 16384
#define NCH 256          // chunks per batch
#define CLEN 64          // chunk length

// ---------------- workspace layout (in floats) ----------------
constexpr size_t OFF_RAW_O = 0;                      // (B,10,H,W)
constexpr size_t OFF_RAW_N = (size_t)BB*10*HW;
constexpr size_t YSEQ_O = OFF_RAW_O + OFF_RAW_N;     // (B,L,9)
constexpr size_t YSEQ_N = (size_t)BB*LSEQ*9;
constexpr size_t YNEW_O = YSEQ_O + YSEQ_N;           // (B,9,H,W)
constexpr size_t YNEW_N = (size_t)BB*9*HW;
constexpr size_t GN1_O = YNEW_O + YNEW_N;            // 20*(mu,inv)
constexpr size_t GN1_N = 64;
constexpr size_t CH18 = (size_t)BB*LSEQ*18;
constexpr size_t CH16 = (size_t)BB*LSEQ*16;
constexpr size_t DT_O = GN1_O + GN1_N;
constexpr size_t XI_O = DT_O + CH18;
constexpr size_t ZZ_O = XI_O + CH18;
constexpr size_t BS_O = ZZ_O + CH18;
constexpr size_t CS_O = BS_O + CH16;
constexpr size_t CARR = (size_t)BB*NCH*288;
constexpr size_t CP_O = CS_O + CH16;
constexpr size_t CHC_O = CP_O + CARR;
constexpr size_t HIN_O = CHC_O + CARR;
constexpr size_t YS_O = HIN_O + CARR;                // (B,L,18)
constexpr size_t YFIN_O = YS_O + CH18;               // (B,9,H,W)
constexpr size_t XT_O = YFIN_O + YNEW_N;             // (B,H,W,64)
constexpr size_t XT_N = (size_t)BB*HW*64;
constexpr size_t OUTPRE_O = XT_O + XT_N;             // (B,64,H,W)
constexpr size_t WT_O = OUTPRE_O + XT_N;             // (9,64,64) [k][ci][co]
constexpr size_t WOFF_O = WT_O + 9*64*64;            // (64,3,3,10) [ci][dy][dx][co]
constexpr size_t AMAT_O = WOFF_O + 64*9*10;          // (18,16)
constexpr size_t GN2_O = AMAT_O + 288;               // 64*(mu,inv)
constexpr size_t WS_TOTAL = GN2_O + 128;

// ---------------- K0: weight transposes + A matrix ----------------
__global__ void prep_kernel(const float* __restrict__ dsc_w, const float* __restrict__ offw,
                            const float* __restrict__ A_log,
                            float* __restrict__ wT, float* __restrict__ woffT,
                            float* __restrict__ Amat){
  int i = blockIdx.x*blockDim.x + threadIdx.x;
  if(i < 9*64*64){
    int k = i/(64*64); int r = i%(64*64); int ci = r/64; int co = r%64;
    wT[i] = dsc_w[((size_t)(co*64 + ci))*9 + k];   // dsc_w (co,ci,9,1)
  }
  int j = i - 9*64*64;
  if(j >= 0 && j < 64*9*10){
    int co = j%10; int r2 = j/10; int dx = r2%3; int r3 = r2/3; int dy = r3%3; int ci = r3/3;
    woffT[j] = offw[((size_t)(co*64 + ci)*3 + dy)*3 + dx]; // offw (18,64,3,3), co<10
  }
  int a = i - (9*64*64 + 64*9*10);
  if(a >= 0 && a < 288) Amat[a] = -expf(A_log[a]);
}

// ---------------- K1: x (B,C,H,W) -> xT (B,H,W,C) ----------------
__global__ __launch_bounds__(256) void transpose_x_kernel(const float* __restrict__ x,
                                                          float* __restrict__ xT){
  __shared__ float tile[64][65];
  int blk = blockIdx.x;            // B*H*2
  int w0 = (blk&1)*64;
  int h  = (blk>>1)&127;
  int b  = blk>>8;
  int lane = threadIdx.x&63, q = threadIdx.x>>6;
  #pragma unroll
  for(int r=0;r<16;r++){
    int ci = r*4 + q;
    tile[ci][lane] = x[((size_t)(b*64+ci)*HH + h)*WW + w0 + lane];
  }
  __syncthreads();
  #pragma unroll
  for(int r=0;r<16;r++){
    int w = r*4 + q;
    xT[(((size_t)(b*HH+h))*WW + w0 + w)*64 + lane] = tile[lane][w];
  }
}

// ---------------- K2: 3x3 offset conv (only out-ch 0..9) ----------------
__global__ __launch_bounds__(128) void off_conv_kernel(const float* __restrict__ x,
                                                       const float* __restrict__ woff,
                                                       const float* __restrict__ offb,
                                                       float* __restrict__ off_raw){
  __shared__ float lds[16][4][66];
  int blk = blockIdx.x;            // B * 64 * 2
  int w0 = (blk&1)*64;
  int h0 = ((blk>>1)&63)*2;
  int b  = blk>>7;
  int wl = threadIdx.x&63, hl = threadIdx.x>>6;     // hl 0..1
  float acc[10];
  #pragma unroll
  for(int c=0;c<10;c++) acc[c] = offb[c];
  for(int cc=0; cc<4; cc++){
    __syncthreads();
    for(int t=threadIdx.x; t<16*4*66; t+=128){
      int ci = t/(4*66); int rem = t%(4*66); int row = rem/66; int col = rem%66;
      int gh = h0-1+row, gw = w0-1+col;
      float v = 0.f;
      if(gh>=0 && gh<HH && gw>=0 && gw<WW)
        v = x[((size_t)(b*64+cc*16+ci)*HH + gh)*WW + gw];
      lds[ci][row][col] = v;
    }
    __syncthreads();
    for(int ci=0;ci<16;ci++){
      #pragma unroll
      for(int dy=0;dy<3;dy++){
        #pragma unroll
        for(int dx=0;dx<3;dx++){
          float xv = lds[ci][hl+dy][wl+dx];
          const float* wp = woff + (((cc*16+ci)*3+dy)*3+dx)*10;
          #pragma unroll
          for(int c=0;c<10;c++) acc[c] += xv*wp[c];
        }
      }
    }
  }
  int h = h0+hl;
  #pragma unroll
  for(int c=0;c<10;c++)
    off_raw[((size_t)(b*10+c)*HH + h)*WW + w0 + wl] = acc[c];
}

// ---------------- generic GroupNorm stats (contiguous groups) ----------------
__device__ inline float wave_red_sum(float v){
  #pragma unroll
  for(int off=32; off; off>>=1) v += __shfl_down(v, off, 64);
  return v;
}

__global__ __launch_bounds__(256) void gn_stats_kernel(const float* __restrict__ src,
                                                       float* __restrict__ out,
                                                       int per_grp, float eps){
  int g = blockIdx.x;
  const float* p = src + (size_t)g*per_grp;
  float s=0.f, s2=0.f;
  for(int i=threadIdx.x; i<per_grp; i+=256){ float v = p[i]; s += v; s2 += v*v; }
  __shared__ float sh[4], sh2[4];
  s = wave_red_sum(s); s2 = wave_red_sum(s2);
  int w = threadIdx.x>>6;
  if((threadIdx.x&63)==0){ sh[w]=s; sh2[w]=s2; }
  __syncthreads();
  if(threadIdx.x==0){
    float S=0.f,S2=0.f;
    for(int i=0;i<4;i++){S+=sh[i];S2+=sh2[i];}
    float mu = S/per_grp;
    float var = S2/per_grp - mu*mu;
    out[g*2] = mu; out[g*2+1] = rsqrtf(var+eps);
  }
}

// ---------------- K4: GN1 apply + tanh + cumsum + zigzag ----------------
__global__ __launch_bounds__(256) void gn1_apply_kernel(const float* __restrict__ off_raw,
                                                        const float* __restrict__ stats,
                                                        const float* __restrict__ gno_g,
                                                        const float* __restrict__ gno_b,
                                                        float* __restrict__ yseq,
                                                        float* __restrict__ ynew){
  int idx = blockIdx.x*blockDim.x + threadIdx.x;   // BB*HW
  int b = idx>>14; int pix = idx&16383; int h = pix>>7, w = pix&127;
  float t[9];
  #pragma unroll
  for(int c=0;c<9;c++){
    float v = off_raw[((size_t)(b*10+c))*HW + pix];
    int g = b*5 + (c>>1);
    float mu = stats[g*2], inv = stats[g*2+1];
    t[c] = tanhf((v-mu)*inv*gno_g[c] + gno_b[c]);
  }
  int l = (((h>>1)*WW + w)<<1) | (h&1);
  float* yq = yseq + ((size_t)(b*LSEQ + l))*9;
  #pragma unroll
  for(int c=0;c<9;c++) yq[c] = t[c];
  float rows[9];
  rows[4]=0.f;
  rows[5]=t[5]; rows[6]=rows[5]+t[6]; rows[7]=rows[6]+t[7]; rows[8]=rows[7]+t[8];
  rows[3]=t[3]; rows[2]=rows[3]+t[2]; rows[1]=rows[2]+t[1]; rows[0]=rows[1]+t[0];
  #pragma unroll
  for(int k=0;k<9;k++) ynew[((size_t)(b*9+k))*HW + pix] = (float)h + rows[k];
}

// ---------------- K5: mamba featurize (parallel over l) ----------------
__global__ __launch_bounds__(256) void mamba_feat_kernel(
    const float* __restrict__ yseq, const float* __restrict__ in_proj_w,
    const float* __restrict__ conv_w, const float* __restrict__ conv_b,
    const float* __restrict__ x_proj_w, const float* __restrict__ dt_w,
    const float* __restrict__ dt_b,
    float* __restrict__ DT, float* __restrict__ XI, float* __restrict__ ZZ,
    float* __restrict__ BSp, float* __restrict__ CSp){
  __shared__ float s_in[36*9], s_cw[18*4], s_cb[18], s_xw[33*18], s_dw[18], s_db[18];
  for(int i=threadIdx.x;i<324;i+=256) s_in[i]=in_proj_w[i];
  for(int i=threadIdx.x;i<72;i+=256)  s_cw[i]=conv_w[i];
  for(int i=threadIdx.x;i<594;i+=256) s_xw[i]=x_proj_w[i];
  if(threadIdx.x<18){ s_cb[threadIdx.x]=conv_b[threadIdx.x];
                      s_dw[threadIdx.x]=dt_w[threadIdx.x];
                      s_db[threadIdx.x]=dt_b[threadIdx.x]; }
  __syncthreads();
  int idx = blockIdx.x*blockDim.x + threadIdx.x;
  int b = idx>>14, l = idx&16383;
  float ys4[4][9];
  #pragma unroll
  for(int t=0;t<4;t++){
    int lp = l-3+t;
    if(lp>=0){
      const float* p = yseq + ((size_t)(b*LSEQ+lp))*9;
      #pragma unroll
      for(int m=0;m<9;m++) ys4[t][m]=p[m];
    } else {
      #pragma unroll
      for(int m=0;m<9;m++) ys4[t][m]=0.f;
    }
  }
  float xi[18];
  #pragma unroll
  for(int d=0;d<18;d++){
    float cacc = s_cb[d];
    #pragma unroll
    for(int t=0;t<4;t++){
      float xr = 0.f;
      #pragma unroll
      for(int m=0;m<9;m++) xr += ys4[t][m]*s_in[d*9+m];
      cacc += xr * s_cw[d*4+t];
    }
    xi[d] = cacc / (1.f + expf(-cacc));     // silu
  }
  size_t base = (size_t)(b*LSEQ+l);
  float dblv[33];
  #pragma unroll
  for(int j=0;j<33;j++){
    float a=0.f;
    #pragma unroll
    for(int d=0;d<18;d++) a += xi[d]*s_xw[j*18+d];
    dblv[j]=a;
  }
  #pragma unroll
  for(int d=0;d<18;d++) XI[base*18+d]=xi[d];
  #pragma unroll
  for(int d=0;d<18;d++){
    float a=0.f;
    #pragma unroll
    for(int m=0;m<9;m++) a += ys4[3][m]*s_in[(18+d)*9+m];
    ZZ[base*18+d]=a;
    float pre = dblv[0]*s_dw[d] + s_db[d];
    DT[base*18+d] = fmaxf(pre,0.f) + log1pf(expf(-fabsf(pre)));   // softplus
  }
  #pragma unroll
  for(int s=0;s<16;s++){ BSp[base*16+s]=dblv[1+s]; CSp[base*16+s]=dblv[17+s]; }
}

// ---------------- K6: chunk scan from zero state ----------------
__global__ void scan_pass1(const float* __restrict__ DT, const float* __restrict__ XI,
                           const float* __restrict__ BSp, const float* __restrict__ Amat,
                           float* __restrict__ CP, float* __restrict__ CH){
  int blk = blockIdx.x; int b = blk/NCH; int c = blk%NCH;
  int t = threadIdx.x;                  // 288: d = t>>4, s = t&15
  int d = t>>4, s = t&15;
  float A = Amat[t];
  float h=0.f, P=1.f;
  int l0 = c*CLEN;
  #pragma unroll 4
  for(int st=0; st<CLEN; ++st){
    size_t base = (size_t)b*LSEQ + (l0+st);
    float dt  = DT[base*18+d];
    float xiv = XI[base*18+d];
    float Bv  = BSp[base*16+s];
    float a = expf(dt*A);
    h = a*h + dt*Bv*xiv;
    P *= a;
  }
  size_t o = ((size_t)(b*NCH+c))*288 + t;
  CP[o]=P; CH[o]=h;
}

// ---------------- K7: parallel carry scan (wave per chain) ----------------
// chains: (b,t), 256 chunk-carries each; composition (P1,H1)∘(P2,H2)=(P1P2, P2H1+H2)
__global__ __launch_bounds__(256) void scan_carry_kernel(const float* __restrict__ CP,
                                                         const float* __restrict__ CH,
                                                         float* __restrict__ HIN){
  int wid = blockIdx.x*4 + (threadIdx.x>>6);   // 0..1151
  int lane = threadIdx.x&63;
  int b = wid/288, t = wid%288;
  int c0 = lane*4;
  float P[4], Hh[4];
  #pragma unroll
  for(int i=0;i<4;i++){
    size_t o = ((size_t)(b*NCH + c0+i))*288 + t;
    P[i]=CP[o]; Hh[i]=CH[o];
  }
  // local aggregate in order
  float aP = P[0], aH = Hh[0];
  #pragma unroll
  for(int i=1;i<4;i++){ aH = P[i]*aH + Hh[i]; aP = aP*P[i]; }
  // inclusive wave scan
  float sP = aP, sH = aH;
  #pragma unroll
  for(int off=1; off<64; off<<=1){
    float pP = __shfl_up(sP, off, 64);
    float pH = __shfl_up(sH, off, 64);
    if(lane >= off){ sH = sP*pH + sH; sP = pP*sP; }
  }
  // exclusive = inclusive shifted down one lane
  float eP = __shfl_up(sP, 1, 64);
  float eH = __shfl_up(sH, 1, 64);
  if(lane==0){ eP=1.f; eH=0.f; }
  float cHh = eH;
  #pragma unroll
  for(int i=0;i<4;i++){
    size_t o = ((size_t)(b*NCH + c0+i))*288 + t;
    HIN[o] = cHh;
    cHh = P[i]*cHh + Hh[i];
  }
  (void)eP;
}

// ---------------- K8: chunk scan with true init + y output ----------------
__global__ void scan_pass2(const float* __restrict__ DT, const float* __restrict__ XI,
                           const float* __restrict__ BSp, const float* __restrict__ CSp,
                           const float* __restrict__ Amat, const float* __restrict__ HIN,
                           float* __restrict__ YSo){
  int blk = blockIdx.x; int b = blk/NCH; int c = blk%NCH;
  int t = threadIdx.x;
  int d = t>>4, s = t&15;
  float A = Amat[t];
  float h = HIN[((size_t)(b*NCH+c))*288 + t];
  int l0 = c*CLEN;
  #pragma unroll 2
  for(int st=0; st<CLEN; ++st){
    size_t base = (size_t)b*LSEQ + (l0+st);
    float dt  = DT[base*18+d];
    float xiv = XI[base*18+d];
    float Bv  = BSp[base*16+s];
    float Cv  = CSp[base*16+s];
    float a = expf(dt*A);
    h = a*h + dt*Bv*xiv;
    float pc = h*Cv;
    pc += __shfl_xor(pc,1,16);
    pc += __shfl_xor(pc,2,16);
    pc += __shfl_xor(pc,4,16);
    pc += __shfl_xor(pc,8,16);
    if(s==0) YSo[base*18+d] = pc;
  }
}

// ---------------- K9: mamba epilogue + y_final ----------------
__global__ __launch_bounds__(256) void mamba_out_kernel(
    const float* __restrict__ YSo, const float* __restrict__ XI,
    const float* __restrict__ ZZ, const float* __restrict__ Dp,
    const float* __restrict__ out_w, const float* __restrict__ altho,
    const float* __restrict__ ynew, float* __restrict__ yfin){
  __shared__ float s_ow[9*18], s_dp[18];
  for(int i=threadIdx.x;i<162;i+=256) s_ow[i]=out_w[i];
  if(threadIdx.x<18) s_dp[threadIdx.x]=Dp[threadIdx.x];
  __syncthreads();
  int idx = blockIdx.x*blockDim.x + threadIdx.x;
  int b = idx>>14, l = idx&16383;
  size_t base = (size_t)(b*LSEQ+l);
  float y[18];
  #pragma unroll
  for(int d=0;d<18;d++){
    float z = ZZ[base*18+d];
    float sz = z/(1.f+expf(-z));
    y[d] = (YSo[base*18+d] + s_dp[d]*XI[base*18+d]) * sz;
  }
  float av = altho[0];
  float sp = fmaxf(av,0.f)+log1pf(expf(-fabsf(av)));
  float wgt = fmaxf(sp, 0.01f);
  int h = ((l>>8)<<1) | (l&1);
  int w = (l>>1)&127;
  int pix = h*WW + w;
  #pragma unroll
  for(int m=0;m<9;m++){
    float a=0.f;
    #pragma unroll
    for(int d=0;d<18;d++) a += y[d]*s_ow[m*18+d];
    size_t o = ((size_t)(b*9+m))*HW + pix;
    yfin[o] = wgt*a + ynew[o];
  }
}

// ---------------- K10: fused bilinear sample + 9x1 stride-9 conv ----------------
// XCD-swizzled blocks + double-buffered LDS (1 barrier per k)
__global__ __launch_bounds__(256) void sample_conv_kernel(
    const float* __restrict__ xT, const float* __restrict__ yfin,
    const float* __restrict__ wT, const float* __restrict__ bias,
    float* __restrict__ outpre){
  __shared__ float F[2][64*64];         // [buf][ci][px]
  int blk0 = blockIdx.x;                // 1024 = 8 XCDs * 128
  int blk = (blk0&7)*128 + (blk0>>3);   // contiguous (b,ho) range per XCD -> L2-resident
  int wo0 = (blk&1)*64;
  int ho  = (blk>>1)&127;
  int b   = blk>>8;
  int lane = threadIdx.x&63;
  int wv   = threadIdx.x>>6;            // 0..3
  int co0  = __builtin_amdgcn_readfirstlane(wv*16);
  int wo = wo0 + lane;
  float acc[16];
  #pragma unroll
  for(int i=0;i<16;i++) acc[i]=0.f;

  float4 g0[4], g1[4]; float gwy;
  auto gather = [&](int k){
    float yv = yfin[((size_t)(b*9+k))*HW + ho*WW + wo];
    float py = fminf(fmaxf(yv,0.f),127.f);
    float y0f = floorf(py);
    gwy = py - y0f;
    int iy0 = (int)y0f;
    int iy1 = min(iy0+1,127);
    int xc  = min(max(wo + k - 4, 0), 127);
    const float* p0 = xT + (((size_t)(b*HH+iy0))*WW + xc)*64 + wv*16;
    const float* p1 = xT + (((size_t)(b*HH+iy1))*WW + xc)*64 + wv*16;
    #pragma unroll
    for(int q=0;q<4;q++){ g0[q]=*(const float4*)(p0+q*4); g1[q]=*(const float4*)(p1+q*4); }
  };
  auto writeF = [&](int buf){
    #pragma unroll
    for(int q=0;q<4;q++){
      int ci = wv*16 + q*4;
      F[buf][(ci  )*64 + lane] = g0[q].x + gwy*(g1[q].x - g0[q].x);
      F[buf][(ci+1)*64 + lane] = g0[q].y + gwy*(g1[q].y - g0[q].y);
      F[buf][(ci+2)*64 + lane] = g0[q].z + gwy*(g1[q].z - g0[q].z);
      F[buf][(ci+3)*64 + lane] = g0[q].w + gwy*(g1[q].w - g0[q].w);
    }
  };

  gather(0); writeF(0);
  __syncthreads();
  for(int k=0;k<9;k++){
    if(k<8) gather(k+1);                // issue next-tile loads early
    const float* wk = wT + k*64*64;
    const float* Fb = F[k&1];
    #pragma unroll 4
    for(int ci=0; ci<64; ci++){
      float fv = Fb[ci*64 + lane];
      const float4* w4 = (const float4*)(wk + ci*64 + co0);
      float4 wa = w4[0], wb = w4[1], wc = w4[2], wd = w4[3];
      acc[0]+=fv*wa.x;  acc[1]+=fv*wa.y;  acc[2]+=fv*wa.z;  acc[3]+=fv*wa.w;
      acc[4]+=fv*wb.x;  acc[5]+=fv*wb.y;  acc[6]+=fv*wb.z;  acc[7]+=fv*wb.w;
      acc[8]+=fv*wc.x;  acc[9]+=fv*wc.y;  acc[10]+=fv*wc.z; acc[11]+=fv*wc.w;
      acc[12]+=fv*wd.x; acc[13]+=fv*wd.y; acc[14]+=fv*wd.z; acc[15]+=fv*wd.w;
    }
    if(k<8){
      writeF((k+1)&1);
      __syncthreads();
    }
  }
  #pragma unroll
  for(int cc=0;cc<16;cc++){
    int co = co0+cc;
    outpre[((size_t)(b*64+co))*HW + ho*WW + wo] = acc[cc] + bias[co];
  }
}

// ---------------- K12: final GN apply ----------------
__global__ __launch_bounds__(256) void gn2_apply_kernel(const float* __restrict__ src,
                                                        const float* __restrict__ stats,
                                                        const float* __restrict__ gam,
                                                        const float* __restrict__ bet,
                                                        float* __restrict__ dst){
  int idx = blockIdx.x*blockDim.x + threadIdx.x;  // BB*64*HW
  int c = (idx>>14)&63;
  int g = idx>>16;                                // (b*64+c)>>2
  float mu = stats[g*2], inv = stats[g*2+1];
  dst[idx] = (src[idx]-mu)*inv*gam[c] + bet[c];
}

extern "C" void kernel_launch(void* const* d_in, const int* in_sizes, int n_in,
                              void* d_out, int out_size, void* d_ws, size_t ws_size,
                              hipStream_t stream){
  const float* x        = (const float*)d_in[0];
  const float* offset_w = (const float*)d_in[1];
  const float* offset_b = (const float*)d_in[2];
  const float* gno_g    = (const float*)d_in[3];
  const float* gno_b    = (const float*)d_in[4];
  const float* altho    = (const float*)d_in[5];
  const float* in_proj  = (const float*)d_in[6];
  const float* conv1d_w = (const float*)d_in[7];
  const float* conv1d_b = (const float*)d_in[8];
  const float* x_proj   = (const float*)d_in[9];
  const float* dt_w     = (const float*)d_in[10];
  const float* dt_b     = (const float*)d_in[11];
  const float* A_log    = (const float*)d_in[12];
  const float* D_p      = (const float*)d_in[13];
  const float* out_proj = (const float*)d_in[14];
  const float* dsc_w    = (const float*)d_in[15];
  const float* dsc_b    = (const float*)d_in[16];
  const float* gn_g     = (const float*)d_in[17];
  const float* gn_b     = (const float*)d_in[18];
  float* out = (float*)d_out;
  float* ws  = (float*)d_ws;
  if(ws_size < WS_TOTAL*sizeof(float)) return;

  float* off_raw = ws + OFF_RAW_O;
  float* yseq    = ws + YSEQ_O;
  float* ynew    = ws + YNEW_O;
  float* gn1     = ws + GN1_O;
  float* DT      = ws + DT_O;
  float* XI      = ws + XI_O;
  float* ZZ      = ws + ZZ_O;
  float* BSp     = ws + BS_O;
  float* CSp     = ws + CS_O;
  float* CP      = ws + CP_O;
  float* CH      = ws + CHC_O;
  float* HIN     = ws + HIN_O;
  float* YSo     = ws + YS_O;
  float* yfin    = ws + YFIN_O;
  float* xT      = ws + XT_O;
  float* outpre  = ws + OUTPRE_O;
  float* wT      = ws + WT_O;
  float* woffT   = ws + WOFF_O;
  float* Amat    = ws + AMAT_O;
  float* gn2     = ws + GN2_O;

  prep_kernel<<<dim3(168), dim3(256), 0, stream>>>(dsc_w, offset_w, A_log, wT, woffT, Amat);
  transpose_x_kernel<<<dim3(1024), dim3(256), 0, stream>>>(x, xT);
  off_conv_kernel<<<dim3(512), dim3(128), 0, stream>>>(x, woffT, offset_b, off_raw);
  gn_stats_kernel<<<dim3(20), dim3(256), 0, stream>>>(off_raw, gn1, 2*HW, 1e-5f);
  gn1_apply_kernel<<<dim3(256), dim3(256), 0, stream>>>(off_raw, gn1, gno_g, gno_b, yseq, ynew);
  mamba_feat_kernel<<<dim3(256), dim3(256), 0, stream>>>(yseq, in_proj, conv1d_w, conv1d_b,
                                                         x_proj, dt_w, dt_b,
                                                         DT, XI, ZZ, BSp, CSp);
  scan_pass1<<<dim3(BB*NCH), dim3(288), 0, stream>>>(DT, XI, BSp, Amat, CP, CH);
  scan_carry_kernel<<<dim3(288), dim3(256), 0, stream>>>(CP, CH, HIN);
  scan_pass2<<<dim3(BB*NCH), dim3(288), 0, stream>>>(DT, XI, BSp, CSp, Amat, HIN, YSo);
  mamba_out_kernel<<<dim3(256), dim3(256), 0, stream>>>(YSo, XI, ZZ, D_p, out_proj, altho,
                                                        ynew, yfin);
  sample_conv_kernel<<<dim3(1024), dim3(256), 0, stream>>>(xT, yfin, wT, dsc_b, outpre);
  gn_stats_kernel<<<dim3(64), dim3(256), 0, stream>>>(outpre, gn2, 4*HW, 1e-5f);
  gn2_apply_kernel<<<dim3(16384), dim3(256), 0, stream>>>(outpre, gn2, gn_g, gn_b, out);
}

// Round 4
// 357.851 us; speedup vs baseline: 1.2992x; 1.2546x over previous
//
#include <hip/hip_runtime.h>
#include <math.h>

#define BB 4
#define CINC 64
#define HH 128
#define WW 128
#define KK 9
#define HW (HH*WW)       // 16384
#define LSEQ (HH*WW)     // 16384
#define NCH 256          // chunks per batch
#define CLEN 64          // chunk length

typedef _Float16 half8 __attribute__((ext_vector_type(8)));
typedef float floatx16 __attribute__((ext_vector_type(16)));

// ---------------- workspace layout (in floats) ----------------
constexpr size_t OFF_RAW_O = 0;                      // (B,10,H,W)
constexpr size_t OFF_RAW_N = (size_t)BB*10*HW;
constexpr size_t YSEQ_O = OFF_RAW_O + OFF_RAW_N;     // (B,L,9)
constexpr size_t YSEQ_N = (size_t)BB*LSEQ*9;
constexpr size_t YNEW_O = YSEQ_O + YSEQ_N;           // (B,9,H,W)
constexpr size_t YNEW_N = (size_t)BB*9*HW;
constexpr size_t GN1_O = YNEW_O + YNEW_N;            // 20*(mu,inv)
constexpr size_t GN1_N = 64;
constexpr size_t CH18 = (size_t)BB*LSEQ*18;
constexpr size_t CH16 = (size_t)BB*LSEQ*16;
constexpr size_t DT_O = GN1_O + GN1_N;
constexpr size_t XI_O = DT_O + CH18;
constexpr size_t ZZ_O = XI_O + CH18;
constexpr size_t BS_O = ZZ_O + CH18;
constexpr size_t CS_O = BS_O + CH16;
constexpr size_t CARR = (size_t)BB*NCH*288;
constexpr size_t CP_O = CS_O + CH16;
constexpr size_t CHC_O = CP_O + CARR;
constexpr size_t HIN_O = CHC_O + CARR;
constexpr size_t YS_O = HIN_O + CARR;                // (B,L,18)
constexpr size_t YFIN_O = YS_O + CH18;               // (B,9,H,W)
constexpr size_t XT_O = YFIN_O + YNEW_N;             // (B,H,W,64)
constexpr size_t XT_N = (size_t)BB*HW*64;
constexpr size_t OUTPRE_O = XT_O + XT_N;             // (B,64,H,W)
constexpr size_t WT_O = OUTPRE_O + XT_N;             // AH (36864 half) + AL (36864 half)
constexpr size_t WOFF_O = WT_O + 36864;              // (64,3,3,10) [ci][dy][dx][co]
constexpr size_t AMAT_O = WOFF_O + 64*9*10;          // (18,16)
constexpr size_t GN2_O = AMAT_O + 288;               // 64*(mu,inv)
constexpr size_t WS_TOTAL = GN2_O + 128;

// ---------------- K0: MFMA weight frags + offset-conv transpose + A matrix ----------------
// AH/AL layout: idx = ((kstep*64 + co)*2 + g)*8 + jj ; kstep = k*4+q ; ci = q*16+g*8+jj
__global__ void prep_kernel(const float* __restrict__ dsc_w, const float* __restrict__ offw,
                            const float* __restrict__ A_log,
                            _Float16* __restrict__ AH, _Float16* __restrict__ AL,
                            float* __restrict__ woffT, float* __restrict__ Amat){
  int i = blockIdx.x*blockDim.x + threadIdx.x;
  if(i < 36864){
    int jj = i&7, gg = (i>>3)&1, co = (i>>4)&63, ks = i>>10;
    int k = ks>>2, q = ks&3;
    int ci = q*16 + gg*8 + jj;
    float w = dsc_w[((size_t)(co*64 + ci))*9 + k];   // dsc_w (co,ci,9,1)
    _Float16 h = (_Float16)w;
    AH[i] = h;
    AL[i] = (_Float16)(w - (float)h);
  }
  int j = i - 36864;
  if(j >= 0 && j < 64*9*10){
    int co = j%10; int r2 = j/10; int dx = r2%3; int r3 = r2/3; int dy = r3%3; int ci = r3/3;
    woffT[j] = offw[((size_t)(co*64 + ci)*3 + dy)*3 + dx]; // offw (18,64,3,3), co<10
  }
  int a = i - (36864 + 5760);
  if(a >= 0 && a < 288) Amat[a] = -__expf(A_log[a]);
}

// ---------------- K1: x (B,C,H,W) -> xT (B,H,W,C) ----------------
__global__ __launch_bounds__(256) void transpose_x_kernel(const float* __restrict__ x,
                                                          float* __restrict__ xT){
  __shared__ float tile[64][65];
  int blk = blockIdx.x;            // B*H*2
  int w0 = (blk&1)*64;
  int h  = (blk>>1)&127;
  int b  = blk>>8;
  int lane = threadIdx.x&63, q = threadIdx.x>>6;
  #pragma unroll
  for(int r=0;r<16;r++){
    int ci = r*4 + q;
    tile[ci][lane] = x[((size_t)(b*64+ci)*HH + h)*WW + w0 + lane];
  }
  __syncthreads();
  #pragma unroll
  for(int r=0;r<16;r++){
    int w = r*4 + q;
    xT[(((size_t)(b*HH+h))*WW + w0 + w)*64 + lane] = tile[lane][w];
  }
}

// ---------------- K2: 3x3 offset conv (only out-ch 0..9) ----------------
__global__ __launch_bounds__(128) void off_conv_kernel(const float* __restrict__ x,
                                                       const float* __restrict__ woff,
                                                       const float* __restrict__ offb,
                                                       float* __restrict__ off_raw){
  __shared__ float lds[16][4][66];
  int blk = blockIdx.x;            // B * 64 * 2
  int w0 = (blk&1)*64;
  int h0 = ((blk>>1)&63)*2;
  int b  = blk>>7;
  int wl = threadIdx.x&63, hl = threadIdx.x>>6;     // hl 0..1
  float acc[10];
  #pragma unroll
  for(int c=0;c<10;c++) acc[c] = offb[c];
  for(int cc=0; cc<4; cc++){
    __syncthreads();
    for(int t=threadIdx.x; t<16*4*66; t+=128){
      int ci = t/(4*66); int rem = t%(4*66); int row = rem/66; int col = rem%66;
      int gh = h0-1+row, gw = w0-1+col;
      float v = 0.f;
      if(gh>=0 && gh<HH && gw>=0 && gw<WW)
        v = x[((size_t)(b*64+cc*16+ci)*HH + gh)*WW + gw];
      lds[ci][row][col] = v;
    }
    __syncthreads();
    for(int ci=0;ci<16;ci++){
      #pragma unroll
      for(int dy=0;dy<3;dy++){
        #pragma unroll
        for(int dx=0;dx<3;dx++){
          float xv = lds[ci][hl+dy][wl+dx];
          const float* wp = woff + (((cc*16+ci)*3+dy)*3+dx)*10;
          #pragma unroll
          for(int c=0;c<10;c++) acc[c] += xv*wp[c];
        }
      }
    }
  }
  int h = h0+hl;
  #pragma unroll
  for(int c=0;c<10;c++)
    off_raw[((size_t)(b*10+c)*HH + h)*WW + w0 + wl] = acc[c];
}

// ---------------- generic GroupNorm stats (contiguous groups) ----------------
__device__ inline float wave_red_sum(float v){
  #pragma unroll
  for(int off=32; off; off>>=1) v += __shfl_down(v, off, 64);
  return v;
}

__global__ __launch_bounds__(256) void gn_stats_kernel(const float* __restrict__ src,
                                                       float* __restrict__ out,
                                                       int per_grp, float eps){
  int g = blockIdx.x;
  const float4* p = (const float4*)(src + (size_t)g*per_grp);
  int n4 = per_grp>>2;
  float s=0.f, s2=0.f;
  for(int i=threadIdx.x; i<n4; i+=256){
    float4 v = p[i];
    s += v.x+v.y+v.z+v.w;
    s2 += v.x*v.x+v.y*v.y+v.z*v.z+v.w*v.w;
  }
  __shared__ float sh[4], sh2[4];
  s = wave_red_sum(s); s2 = wave_red_sum(s2);
  int w = threadIdx.x>>6;
  if((threadIdx.x&63)==0){ sh[w]=s; sh2[w]=s2; }
  __syncthreads();
  if(threadIdx.x==0){
    float S=0.f,S2=0.f;
    for(int i=0;i<4;i++){S+=sh[i];S2+=sh2[i];}
    float mu = S/per_grp;
    float var = S2/per_grp - mu*mu;
    out[g*2] = mu; out[g*2+1] = rsqrtf(var+eps);
  }
}

// ---------------- K4: GN1 apply + tanh + cumsum + zigzag ----------------
__global__ __launch_bounds__(256) void gn1_apply_kernel(const float* __restrict__ off_raw,
                                                        const float* __restrict__ stats,
                                                        const float* __restrict__ gno_g,
                                                        const float* __restrict__ gno_b,
                                                        float* __restrict__ yseq,
                                                        float* __restrict__ ynew){
  int idx = blockIdx.x*blockDim.x + threadIdx.x;   // BB*HW
  int b = idx>>14; int pix = idx&16383; int h = pix>>7, w = pix&127;
  float t[9];
  #pragma unroll
  for(int c=0;c<9;c++){
    float v = off_raw[((size_t)(b*10+c))*HW + pix];
    int g = b*5 + (c>>1);
    float mu = stats[g*2], inv = stats[g*2+1];
    float xx = (v-mu)*inv*gno_g[c] + gno_b[c];
    xx = fminf(fmaxf(xx,-15.f),15.f);
    float e2 = __expf(2.f*xx);
    t[c] = (e2-1.f)/(e2+1.f);
  }
  int l = (((h>>1)*WW + w)<<1) | (h&1);
  float* yq = yseq + ((size_t)(b*LSEQ + l))*9;
  #pragma unroll
  for(int c=0;c<9;c++) yq[c] = t[c];
  float rows[9];
  rows[4]=0.f;
  rows[5]=t[5]; rows[6]=rows[5]+t[6]; rows[7]=rows[6]+t[7]; rows[8]=rows[7]+t[8];
  rows[3]=t[3]; rows[2]=rows[3]+t[2]; rows[1]=rows[2]+t[1]; rows[0]=rows[1]+t[0];
  #pragma unroll
  for(int k=0;k<9;k++) ynew[((size_t)(b*9+k))*HW + pix] = (float)h + rows[k];
}

// ---------------- K5: mamba featurize (parallel over l) ----------------
__global__ __launch_bounds__(256) void mamba_feat_kernel(
    const float* __restrict__ yseq, const float* __restrict__ in_proj_w,
    const float* __restrict__ conv_w, const float* __restrict__ conv_b,
    const float* __restrict__ x_proj_w, const float* __restrict__ dt_w,
    const float* __restrict__ dt_b,
    float* __restrict__ DT, float* __restrict__ XI, float* __restrict__ ZZ,
    float* __restrict__ BSp, float* __restrict__ CSp){
  __shared__ float s_in[36*9], s_cw[18*4], s_cb[18], s_xw[33*18], s_dw[18], s_db[18];
  for(int i=threadIdx.x;i<324;i+=256) s_in[i]=in_proj_w[i];
  for(int i=threadIdx.x;i<72;i+=256)  s_cw[i]=conv_w[i];
  for(int i=threadIdx.x;i<594;i+=256) s_xw[i]=x_proj_w[i];
  if(threadIdx.x<18){ s_cb[threadIdx.x]=conv_b[threadIdx.x];
                      s_dw[threadIdx.x]=dt_w[threadIdx.x];
                      s_db[threadIdx.x]=dt_b[threadIdx.x]; }
  __syncthreads();
  int idx = blockIdx.x*blockDim.x + threadIdx.x;
  int b = idx>>14, l = idx&16383;
  float ys4[4][9];
  #pragma unroll
  for(int t=0;t<4;t++){
    int lp = l-3+t;
    if(lp>=0){
      const float* p = yseq + ((size_t)(b*LSEQ+lp))*9;
      #pragma unroll
      for(int m=0;m<9;m++) ys4[t][m]=p[m];
    } else {
      #pragma unroll
      for(int m=0;m<9;m++) ys4[t][m]=0.f;
    }
  }
  float xi[18];
  #pragma unroll
  for(int d=0;d<18;d++){
    float cacc = s_cb[d];
    #pragma unroll
    for(int t=0;t<4;t++){
      float xr = 0.f;
      #pragma unroll
      for(int m=0;m<9;m++) xr += ys4[t][m]*s_in[d*9+m];
      cacc += xr * s_cw[d*4+t];
    }
    xi[d] = cacc / (1.f + __expf(-cacc));     // silu
  }
  size_t base = (size_t)(b*LSEQ+l);
  float dblv[33];
  #pragma unroll
  for(int j=0;j<33;j++){
    float a=0.f;
    #pragma unroll
    for(int d=0;d<18;d++) a += xi[d]*s_xw[j*18+d];
    dblv[j]=a;
  }
  #pragma unroll
  for(int d=0;d<18;d++) XI[base*18+d]=xi[d];
  #pragma unroll
  for(int d=0;d<18;d++){
    float a=0.f;
    #pragma unroll
    for(int m=0;m<9;m++) a += ys4[3][m]*s_in[(18+d)*9+m];
    ZZ[base*18+d]=a;
    float pre = dblv[0]*s_dw[d] + s_db[d];
    DT[base*18+d] = fmaxf(pre,0.f) + __logf(1.f + __expf(-fabsf(pre)));   // softplus
  }
  #pragma unroll
  for(int s=0;s<16;s++){ BSp[base*16+s]=dblv[1+s]; CSp[base*16+s]=dblv[17+s]; }
}

// ---------------- K6: chunk scan from zero state ----------------
__global__ void scan_pass1(const float* __restrict__ DT, const float* __restrict__ XI,
                           const float* __restrict__ BSp, const float* __restrict__ Amat,
                           float* __restrict__ CP, float* __restrict__ CH){
  int blk = blockIdx.x; int b = blk/NCH; int c = blk%NCH;
  int t = threadIdx.x;                  // 288: d = t>>4, s = t&15
  int d = t>>4, s = t&15;
  float A = Amat[t];
  float h=0.f, P=1.f;
  int l0 = c*CLEN;
  #pragma unroll 4
  for(int st=0; st<CLEN; ++st){
    size_t base = (size_t)b*LSEQ + (l0+st);
    float dt  = DT[base*18+d];
    float xiv = XI[base*18+d];
    float Bv  = BSp[base*16+s];
    float a = __expf(dt*A);
    h = a*h + dt*Bv*xiv;
    P *= a;
  }
  size_t o = ((size_t)(b*NCH+c))*288 + t;
  CP[o]=P; CH[o]=h;
}

// ---------------- K7: parallel carry scan (wave per chain) ----------------
__global__ __launch_bounds__(256) void scan_carry_kernel(const float* __restrict__ CP,
                                                         const float* __restrict__ CH,
                                                         float* __restrict__ HIN){
  int wid = blockIdx.x*4 + (threadIdx.x>>6);   // 0..1151
  int lane = threadIdx.x&63;
  int b = wid/288, t = wid%288;
  int c0 = lane*4;
  float P[4], Hh[4];
  #pragma unroll
  for(int i=0;i<4;i++){
    size_t o = ((size_t)(b*NCH + c0+i))*288 + t;
    P[i]=CP[o]; Hh[i]=CH[o];
  }
  float aP = P[0], aH = Hh[0];
  #pragma unroll
  for(int i=1;i<4;i++){ aH = P[i]*aH + Hh[i]; aP = aP*P[i]; }
  float sP = aP, sH = aH;
  #pragma unroll
  for(int off=1; off<64; off<<=1){
    float pP = __shfl_up(sP, off, 64);
    float pH = __shfl_up(sH, off, 64);
    if(lane >= off){ sH = sP*pH + sH; sP = pP*sP; }
  }
  float eH = __shfl_up(sH, 1, 64);
  if(lane==0){ eH=0.f; }
  float cHh = eH;
  #pragma unroll
  for(int i=0;i<4;i++){
    size_t o = ((size_t)(b*NCH + c0+i))*288 + t;
    HIN[o] = cHh;
    cHh = P[i]*cHh + Hh[i];
  }
}

// ---------------- K8: chunk scan with true init + y output ----------------
__global__ void scan_pass2(const float* __restrict__ DT, const float* __restrict__ XI,
                           const float* __restrict__ BSp, const float* __restrict__ CSp,
                           const float* __restrict__ Amat, const float* __restrict__ HIN,
                           float* __restrict__ YSo){
  int blk = blockIdx.x; int b = blk/NCH; int c = blk%NCH;
  int t = threadIdx.x;
  int d = t>>4, s = t&15;
  float A = Amat[t];
  float h = HIN[((size_t)(b*NCH+c))*288 + t];
  int l0 = c*CLEN;
  #pragma unroll 2
  for(int st=0; st<CLEN; ++st){
    size_t base = (size_t)b*LSEQ + (l0+st);
    float dt  = DT[base*18+d];
    float xiv = XI[base*18+d];
    float Bv  = BSp[base*16+s];
    float Cv  = CSp[base*16+s];
    float a = __expf(dt*A);
    h = a*h + dt*Bv*xiv;
    float pc = h*Cv;
    pc += __shfl_xor(pc,1,16);
    pc += __shfl_xor(pc,2,16);
    pc += __shfl_xor(pc,4,16);
    pc += __shfl_xor(pc,8,16);
    if(s==0) YSo[base*18+d] = pc;
  }
}

// ---------------- K9: mamba epilogue + y_final ----------------
__global__ __launch_bounds__(256) void mamba_out_kernel(
    const float* __restrict__ YSo, const float* __restrict__ XI,
    const float* __restrict__ ZZ, const float* __restrict__ Dp,
    const float* __restrict__ out_w, const float* __restrict__ altho,
    const float* __restrict__ ynew, float* __restrict__ yfin){
  __shared__ float s_ow[9*18], s_dp[18];
  for(int i=threadIdx.x;i<162;i+=256) s_ow[i]=out_w[i];
  if(threadIdx.x<18) s_dp[threadIdx.x]=Dp[threadIdx.x];
  __syncthreads();
  int idx = blockIdx.x*blockDim.x + threadIdx.x;
  int b = idx>>14, l = idx&16383;
  size_t base = (size_t)(b*LSEQ+l);
  float y[18];
  #pragma unroll
  for(int d=0;d<18;d++){
    float z = ZZ[base*18+d];
    float sz = z/(1.f+__expf(-z));
    y[d] = (YSo[base*18+d] + s_dp[d]*XI[base*18+d]) * sz;
  }
  float av = altho[0];
  float sp = fmaxf(av,0.f)+__logf(1.f+__expf(-fabsf(av)));
  float wgt = fmaxf(sp, 0.01f);
  int h = ((l>>8)<<1) | (l&1);
  int w = (l>>1)&127;
  int pix = h*WW + w;
  #pragma unroll
  for(int m=0;m<9;m++){
    float a=0.f;
    #pragma unroll
    for(int d=0;d<18;d++) a += y[d]*s_ow[m*18+d];
    size_t o = ((size_t)(b*9+m))*HW + pix;
    yfin[o] = wgt*a + ynew[o];
  }
}

// ---------------- K10: fused bilinear sample + 9x1 stride-9 conv, MFMA fp16 3-term ----
// out[co,px] = sum_{k,ci} W[k,ci,co] * F[k,ci,px]; W=Wh+Wl (fp16 split, Wh regs, Wl L2),
// F=Fh+Fl (fp16 split, LDS).  acc = Ah*Bh + Ah*Bl + Al*Bh   (Al*Bl ~ 1e-8, dropped)
__global__ __launch_bounds__(256,2) void sample_conv_kernel(
    const float* __restrict__ xT, const float* __restrict__ yfin,
    const _Float16* __restrict__ AH, const _Float16* __restrict__ AL,
    const float* __restrict__ bias, float* __restrict__ outpre){
  __shared__ _Float16 F[2][2][64][72];   // [buf][hi/lo][px][ci padded to 72]
  int blk0 = blockIdx.x;                 // 1024 = 8 XCDs * 128
  int blk = (blk0&7)*128 + (blk0>>3);    // XCD-contiguous -> L2-resident xT rows
  int wo0 = (blk&1)*64;
  int ho  = (blk>>1)&127;
  int b   = blk>>8;
  int lane = threadIdx.x&63;
  int wv   = threadIdx.x>>6;             // 0..3
  int l32  = lane&31, g = lane>>5;
  int co0 = (wv&1)*32, pxh = (wv>>1)*32; // wave tile: 32 co x 32 px
  int px = lane;                         // gather role: lane = px
  int wo = wo0 + px;

  // ---- A-hi fragments, K=576 -> 36 ksteps, resident in VGPRs
  half8 ah[36];
  {
    const _Float16* basep = AH + ((size_t)(co0 + l32)*2 + g)*8;
    #pragma unroll
    for(int ks=0; ks<36; ks++)
      ah[ks] = *(const half8*)(basep + (size_t)ks*1024);
  }
  const _Float16* albase = AL + ((size_t)(co0 + l32)*2 + g)*8;

  floatx16 acc;
  #pragma unroll
  for(int r=0;r<16;r++) acc[r]=0.f;

  float4 ga[4], gb[4]; float wyv = 0.f;
  auto gather = [&](int k){
    float yv = yfin[((size_t)(b*9+k))*HW + ho*WW + wo];
    float py = fminf(fmaxf(yv,0.f),127.f);
    float y0f = floorf(py);
    wyv = py - y0f;
    int iy0 = (int)y0f;
    int iy1 = min(iy0+1,127);
    int xc  = min(max(wo + k - 4, 0), 127);
    const float* p0 = xT + (((size_t)(b*HH+iy0))*WW + xc)*64 + wv*16;
    const float* p1 = xT + (((size_t)(b*HH+iy1))*WW + xc)*64 + wv*16;
    #pragma unroll
    for(int q2=0;q2<4;q2++){ ga[q2]=*(const float4*)(p0+q2*4); gb[q2]=*(const float4*)(p1+q2*4); }
  };
  auto writeF = [&](int buf){
    #pragma unroll
    for(int hseg=0; hseg<2; hseg++){
      half8 vh, vl;
      #pragma unroll
      for(int e=0;e<8;e++){
        int q2 = hseg*2 + (e>>2);
        float v0 = (e&3)==0 ? ga[q2].x : (e&3)==1 ? ga[q2].y : (e&3)==2 ? ga[q2].z : ga[q2].w;
        float v1 = (e&3)==0 ? gb[q2].x : (e&3)==1 ? gb[q2].y : (e&3)==2 ? gb[q2].z : gb[q2].w;
        float v = v0 + wyv*(v1-v0);
        _Float16 hx = (_Float16)v;
        vh[e] = hx;
        vl[e] = (_Float16)(v - (float)hx);
      }
      *(half8*)&F[buf][0][px][wv*16 + hseg*8] = vh;
      *(half8*)&F[buf][1][px][wv*16 + hseg*8] = vl;
    }
  };

  gather(0); writeF(0);
  __syncthreads();
  #pragma unroll
  for(int k=0;k<9;k++){
    if(k<8) gather(k+1);
    int buf = k&1;
    #pragma unroll
    for(int q=0;q<4;q++){
      half8 bh = *(const half8*)&F[buf][0][pxh + l32][q*16 + g*8];
      half8 bl = *(const half8*)&F[buf][1][pxh + l32][q*16 + g*8];
      half8 al = *(const half8*)(albase + (size_t)(k*4+q)*1024);
      acc = __builtin_amdgcn_mfma_f32_32x32x16_f16(ah[k*4+q], bh, acc, 0,0,0);
      acc = __builtin_amdgcn_mfma_f32_32x32x16_f16(ah[k*4+q], bl, acc, 0,0,0);
      acc = __builtin_amdgcn_mfma_f32_32x32x16_f16(al,        bh, acc, 0,0,0);
    }
    if(k<8) writeF((k+1)&1);
    __syncthreads();
  }
  // C/D: col = lane&31 (px), row = (reg&3) + 8*(reg>>2) + 4*(lane>>5) (co)
  #pragma unroll
  for(int r=0;r<16;r++){
    int row = (r&3) + 8*(r>>2) + 4*g;
    int co = co0 + row;
    outpre[((size_t)(b*64+co))*HW + ho*WW + wo0 + pxh + l32] = acc[r] + bias[co];
  }
}

// ---------------- K12: final GN apply ----------------
__global__ __launch_bounds__(256) void gn2_apply_kernel(const float* __restrict__ src,
                                                        const float* __restrict__ stats,
                                                        const float* __restrict__ gam,
                                                        const float* __restrict__ bet,
                                                        float* __restrict__ dst){
  int idx = blockIdx.x*blockDim.x + threadIdx.x;  // BB*64*HW
  int c = (idx>>14)&63;
  int g = idx>>16;
  float mu = stats[g*2], inv = stats[g*2+1];
  dst[idx] = (src[idx]-mu)*inv*gam[c] + bet[c];
}

extern "C" void kernel_launch(void* const* d_in, const int* in_sizes, int n_in,
                              void* d_out, int out_size, void* d_ws, size_t ws_size,
                              hipStream_t stream){
  const float* x        = (const float*)d_in[0];
  const float* offset_w = (const float*)d_in[1];
  const float* offset_b = (const float*)d_in[2];
  const float* gno_g    = (const float*)d_in[3];
  const float* gno_b    = (const float*)d_in[4];
  const float* altho    = (const float*)d_in[5];
  const float* in_proj  = (const float*)d_in[6];
  const float* conv1d_w = (const float*)d_in[7];
  const float* conv1d_b = (const float*)d_in[8];
  const float* x_proj   = (const float*)d_in[9];
  const float* dt_w     = (const float*)d_in[10];
  const float* dt_b     = (const float*)d_in[11];
  const float* A_log    = (const float*)d_in[12];
  const float* D_p      = (const float*)d_in[13];
  const float* out_proj = (const float*)d_in[14];
  const float* dsc_w    = (const float*)d_in[15];
  const float* dsc_b    = (const float*)d_in[16];
  const float* gn_g     = (const float*)d_in[17];
  const float* gn_b     = (const float*)d_in[18];
  float* out = (float*)d_out;
  float* ws  = (float*)d_ws;
  if(ws_size < WS_TOTAL*sizeof(float)) return;

  float* off_raw = ws + OFF_RAW_O;
  float* yseq    = ws + YSEQ_O;
  float* ynew    = ws + YNEW_O;
  float* gn1     = ws + GN1_O;
  float* DT      = ws + DT_O;
  float* XI      = ws + XI_O;
  float* ZZ      = ws + ZZ_O;
  float* BSp     = ws + BS_O;
  float* CSp     = ws + CS_O;
  float* CP      = ws + CP_O;
  float* CH      = ws + CHC_O;
  float* HIN     = ws + HIN_O;
  float* YSo     = ws + YS_O;
  float* yfin    = ws + YFIN_O;
  float* xT      = ws + XT_O;
  float* outpre  = ws + OUTPRE_O;
  _Float16* AH   = (_Float16*)(ws + WT_O);
  _Float16* AL   = (_Float16*)(ws + WT_O) + 36864;
  float* woffT   = ws + WOFF_O;
  float* Amat    = ws + AMAT_O;
  float* gn2     = ws + GN2_O;

  prep_kernel<<<dim3(168), dim3(256), 0, stream>>>(dsc_w, offset_w, A_log, AH, AL, woffT, Amat);
  transpose_x_kernel<<<dim3(1024), dim3(256), 0, stream>>>(x, xT);
  off_conv_kernel<<<dim3(512), dim3(128), 0, stream>>>(x, woffT, offset_b, off_raw);
  gn_stats_kernel<<<dim3(20), dim3(256), 0, stream>>>(off_raw, gn1, 2*HW, 1e-5f);
  gn1_apply_kernel<<<dim3(256), dim3(256), 0, stream>>>(off_raw, gn1, gno_g, gno_b, yseq, ynew);
  mamba_feat_kernel<<<dim3(256), dim3(256), 0, stream>>>(yseq, in_proj, conv1d_w, conv1d_b,
                                                         x_proj, dt_w, dt_b,
                                                         DT, XI, ZZ, BSp, CSp);
  scan_pass1<<<dim3(BB*NCH), dim3(288), 0, stream>>>(DT, XI, BSp, Amat, CP, CH);
  scan_carry_kernel<<<dim3(288), dim3(256), 0, stream>>>(CP, CH, HIN);
  scan_pass2<<<dim3(BB*NCH), dim3(288), 0, stream>>>(DT, XI, BSp, CSp, Amat, HIN, YSo);
  mamba_out_kernel<<<dim3(256), dim3(256), 0, stream>>>(YSo, XI, ZZ, D_p, out_proj, altho,
                                                        ynew, yfin);
  sample_conv_kernel<<<dim3(1024), dim3(256), 0, stream>>>(xT, yfin, AH, AL, dsc_b, outpre);
  gn_stats_kernel<<<dim3(64), dim3(256), 0, stream>>>(outpre, gn2, 4*HW, 1e-5f);
  gn2_apply_kernel<<<dim3(16384), dim3(256), 0, stream>>>(outpre, gn2, gn_g, gn_b, out);
}

// Round 5
// 349.809 us; speedup vs baseline: 1.3290x; 1.0230x over previous
//
#include <hip/hip_runtime.h>
#include <math.h>

#define BB 4
#define HH 128
#define WW 128
#define HW (HH*WW)       // 16384
#define LSEQ HW          // 16384
#define NCH 256          // chunks per batch
#define CLEN 64          // chunk length

typedef _Float16 half8 __attribute__((ext_vector_type(8)));
typedef float floatx4 __attribute__((ext_vector_type(4)));
typedef float floatx16 __attribute__((ext_vector_type(16)));

// ---------------- workspace layout (in floats) ----------------
constexpr size_t OFF_RAW_O = 0;                      // (B,10,H,W)
constexpr size_t OFF_RAW_N = (size_t)BB*10*HW;
constexpr size_t YSEQT_O = OFF_RAW_O + OFF_RAW_N;    // (B,9,L)
constexpr size_t YSEQT_N = (size_t)BB*9*LSEQ;
constexpr size_t YNEW_O = YSEQT_O + YSEQT_N;         // (B,9,H,W)
constexpr size_t YNEW_N = (size_t)BB*9*HW;
constexpr size_t GN1_O = YNEW_O + YNEW_N;            // 20*(mu,inv)
constexpr size_t GN1_N = 64;
constexpr size_t CH18 = (size_t)BB*18*LSEQ;
constexpr size_t CH16 = (size_t)BB*16*LSEQ;
constexpr size_t DT_O = GN1_O + GN1_N;               // (B,18,L)
constexpr size_t XI_O = DT_O + CH18;                 // (B,18,L)
constexpr size_t ZZ_O = XI_O + CH18;                 // (B,18,L)
constexpr size_t BS_O = ZZ_O + CH18;                 // (B,16,L)
constexpr size_t CS_O = BS_O + CH16;                 // (B,16,L)
constexpr size_t CARR = (size_t)BB*NCH*288;
constexpr size_t CP_O = CS_O + CH16;
constexpr size_t CHC_O = CP_O + CARR;
constexpr size_t HIN_O = CHC_O + CARR;
constexpr size_t YS_O = HIN_O + CARR;                // (B,18,L)
constexpr size_t YFIN_O = YS_O + CH18;               // (B,9,H,W)
constexpr size_t XTH_O = YFIN_O + YNEW_N;            // (B,H,W,64) halfs -> /2 floats
constexpr size_t XTH_N = (size_t)BB*HW*32;
constexpr size_t XTL_O = XTH_O + XTH_N;
constexpr size_t OUTPRE_O = XTL_O + XTH_N;           // (B,64,H,W)
constexpr size_t OUTPRE_N = (size_t)BB*64*HW;
constexpr size_t WT_O = OUTPRE_O + OUTPRE_N;         // AH(36864 h) + AL(36864 h)
constexpr size_t AO_O = WT_O + 36864;                // AOH(9216 h) + AOL(9216 h)
constexpr size_t AMAT_O = AO_O + 9216;               // (18,16)
constexpr size_t GN2_O = AMAT_O + 288;               // 64*(mu,inv)
constexpr size_t WS_TOTAL = GN2_O + 128;

// ---------------- K0: MFMA weight frags + A matrix ----------------
// AH/AL (32x32 sample_conv): idx = ((kstep*64 + co)*2 + g)*8 + jj ; ci = q*16+g*8+jj, kstep=k*4+q
// AOH/AOL (16x16 off_conv):  idx = ((tap*2+ks)*64 + lane)*8 + jj ; co=lane&15, ci=ks*32+(lane>>4)*8+jj
__global__ void prep_kernel(const float* __restrict__ dsc_w, const float* __restrict__ offw,
                            const float* __restrict__ A_log,
                            _Float16* __restrict__ AH, _Float16* __restrict__ AL,
                            _Float16* __restrict__ AOH, _Float16* __restrict__ AOL,
                            float* __restrict__ Amat){
  int i = blockIdx.x*blockDim.x + threadIdx.x;
  if(i < 36864){
    int jj = i&7, gg = (i>>3)&1, co = (i>>4)&63, ks = i>>10;
    int k = ks>>2, q = ks&3;
    int ci = q*16 + gg*8 + jj;
    float w = dsc_w[((size_t)(co*64 + ci))*9 + k];   // dsc_w (co,ci,9,1)
    _Float16 h = (_Float16)w;
    AH[i] = h;
    AL[i] = (_Float16)(w - (float)h);
  }
  int j = i - 36864;
  if(j >= 0 && j < 9216){
    int jj = j&7, lane = (j>>3)&63, ksl = j>>9;      // ksl 0..17
    int tap = ksl>>1, ks = ksl&1;
    int co = lane&15, kg = lane>>4;
    int ci = ks*32 + kg*8 + jj;
    int dy = tap/3, dx = tap%3;
    float w = (co<10) ? offw[((size_t)(co*64 + ci)*3 + dy)*3 + dx] : 0.f;
    _Float16 h = (_Float16)w;
    AOH[j] = h;
    AOL[j] = (_Float16)(w - (float)h);
  }
  int a = i - 46080;
  if(a >= 0 && a < 288) Amat[a] = -__expf(A_log[a]);
}

// ---------------- K1: x (B,C,H,W) -> xTh/xTl (B,H,W,C) fp16 split ----------------
__global__ __launch_bounds__(256) void transpose_x_kernel(const float* __restrict__ x,
                                                          _Float16* __restrict__ xTh,
                                                          _Float16* __restrict__ xTl){
  __shared__ float tile[64][65];
  int blk = blockIdx.x;            // B*H*2
  int w0 = (blk&1)*64;
  int h  = (blk>>1)&127;
  int b  = blk>>8;
  int lane = threadIdx.x&63, q = threadIdx.x>>6;
  #pragma unroll
  for(int r=0;r<16;r++){
    int ci = r*4 + q;
    tile[ci][lane] = x[((size_t)(b*64+ci)*HH + h)*WW + w0 + lane];
  }
  __syncthreads();
  #pragma unroll
  for(int r=0;r<16;r++){
    int w = r*4 + q;
    float v = tile[lane][w];
    size_t o = (((size_t)(b*HH+h))*WW + w0 + w)*64 + lane;
    _Float16 hv = (_Float16)v;
    xTh[o] = hv;
    xTl[o] = (_Float16)(v - (float)hv);
  }
}

// ---------------- K2: 3x3 offset conv (out-ch 0..9) via 9 shifted MFMA GEMMs ------
// no LDS: B-frags straight from L2-resident xTh/xTl, A-frags from L1
__global__ __launch_bounds__(256) void off_conv_kernel(
    const _Float16* __restrict__ xTh, const _Float16* __restrict__ xTl,
    const _Float16* __restrict__ AOH, const _Float16* __restrict__ AOL,
    const float* __restrict__ offb, float* __restrict__ off_raw){
  int blk0 = blockIdx.x;               // 512 = 8 XCDs * 64
  int blk = (blk0&7)*64 + (blk0>>3);   // XCD-contiguous h ranges
  int h = blk&127, b = blk>>7;
  int lane = threadIdx.x&63, wv = threadIdx.x>>6;
  int col = lane&15, kg = lane>>4;
  floatx4 acc[2];
  acc[0] = (floatx4)0.f; acc[1] = (floatx4)0.f;
  for(int dy=0; dy<3; dy++){
    int hr = h + dy - 1;
    if(hr < 0 || hr >= HH) continue;
    for(int dx=0; dx<3; dx++){
      int tap = dy*3 + dx;
      #pragma unroll
      for(int ks=0; ks<2; ks++){
        half8 ah = *(const half8*)(AOH + (size_t)((tap*2+ks)*64 + lane)*8);
        half8 al = *(const half8*)(AOL + (size_t)((tap*2+ks)*64 + lane)*8);
        #pragma unroll
        for(int tt=0; tt<2; tt++){
          int px = wv*32 + tt*16 + col;
          int wc = px + dx - 1;
          half8 bh = {}, bl = {};
          if(wc >= 0 && wc < WW){
            size_t o = (((size_t)(b*HH+hr))*WW + wc)*64 + ks*32 + kg*8;
            bh = *(const half8*)(xTh + o);
            bl = *(const half8*)(xTl + o);
          }
          acc[tt] = __builtin_amdgcn_mfma_f32_16x16x32_f16(ah, bh, acc[tt], 0,0,0);
          acc[tt] = __builtin_amdgcn_mfma_f32_16x16x32_f16(ah, bl, acc[tt], 0,0,0);
          acc[tt] = __builtin_amdgcn_mfma_f32_16x16x32_f16(al, bh, acc[tt], 0,0,0);
        }
      }
    }
  }
  // C/D 16x16: col = lane&15 (px), row = kg*4 + r (co)
  #pragma unroll
  for(int tt=0; tt<2; tt++){
    #pragma unroll
    for(int r=0; r<4; r++){
      int co = kg*4 + r;
      if(co < 10){
        int px = wv*32 + tt*16 + col;
        off_raw[((size_t)(b*10+co)*HH + h)*WW + px] = acc[tt][r] + offb[co];
      }
    }
  }
}

// ---------------- generic GroupNorm stats (contiguous groups) ----------------
__device__ inline float wave_red_sum(float v){
  #pragma unroll
  for(int off=32; off; off>>=1) v += __shfl_down(v, off, 64);
  return v;
}

__global__ __launch_bounds__(256) void gn_stats_kernel(const float* __restrict__ src,
                                                       float* __restrict__ out,
                                                       int per_grp, float eps){
  int g = blockIdx.x;
  const float4* p = (const float4*)(src + (size_t)g*per_grp);
  int n4 = per_grp>>2;
  float s=0.f, s2=0.f;
  for(int i=threadIdx.x; i<n4; i+=256){
    float4 v = p[i];
    s += v.x+v.y+v.z+v.w;
    s2 += v.x*v.x+v.y*v.y+v.z*v.z+v.w*v.w;
  }
  __shared__ float sh[4], sh2[4];
  s = wave_red_sum(s); s2 = wave_red_sum(s2);
  int w = threadIdx.x>>6;
  if((threadIdx.x&63)==0){ sh[w]=s; sh2[w]=s2; }
  __syncthreads();
  if(threadIdx.x==0){
    float S=0.f,S2=0.f;
    for(int i=0;i<4;i++){S+=sh[i];S2+=sh2[i];}
    float mu = S/per_grp;
    float var = S2/per_grp - mu*mu;
    out[g*2] = mu; out[g*2+1] = rsqrtf(var+eps);
  }
}

// ---------------- K4: GN1 apply + tanh + cumsum + zigzag ----------------
__global__ __launch_bounds__(256) void gn1_apply_kernel(const float* __restrict__ off_raw,
                                                        const float* __restrict__ stats,
                                                        const float* __restrict__ gno_g,
                                                        const float* __restrict__ gno_b,
                                                        float* __restrict__ yseqT,
                                                        float* __restrict__ ynew){
  int idx = blockIdx.x*blockDim.x + threadIdx.x;   // BB*HW
  int b = idx>>14; int pix = idx&16383; int h = pix>>7, w = pix&127;
  float t[9];
  #pragma unroll
  for(int c=0;c<9;c++){
    float v = off_raw[((size_t)(b*10+c))*HW + pix];
    int g = b*5 + (c>>1);
    float mu = stats[g*2], inv = stats[g*2+1];
    float xx = (v-mu)*inv*gno_g[c] + gno_b[c];
    xx = fminf(fmaxf(xx,-15.f),15.f);
    float e2 = __expf(2.f*xx);
    t[c] = (e2-1.f)/(e2+1.f);
  }
  int l = (((h>>1)*WW + w)<<1) | (h&1);
  #pragma unroll
  for(int c=0;c<9;c++) yseqT[((size_t)(b*9+c))*LSEQ + l] = t[c];
  float rows[9];
  rows[4]=0.f;
  rows[5]=t[5]; rows[6]=rows[5]+t[6]; rows[7]=rows[6]+t[7]; rows[8]=rows[7]+t[8];
  rows[3]=t[3]; rows[2]=rows[3]+t[2]; rows[1]=rows[2]+t[1]; rows[0]=rows[1]+t[0];
  #pragma unroll
  for(int k=0;k<9;k++) ynew[((size_t)(b*9+k))*HW + pix] = (float)h + rows[k];
}

// ---------------- K5: mamba featurize (parallel over l, coalesced I/O) -------------
__global__ __launch_bounds__(256) void mamba_feat_kernel(
    const float* __restrict__ yseqT, const float* __restrict__ in_proj_w,
    const float* __restrict__ conv_w, const float* __restrict__ conv_b,
    const float* __restrict__ x_proj_w, const float* __restrict__ dt_w,
    const float* __restrict__ dt_b,
    float* __restrict__ DT_T, float* __restrict__ XI_T, float* __restrict__ ZZ_T,
    float* __restrict__ BS_T, float* __restrict__ CS_T){
  __shared__ float s_in[36*9], s_cw[18*4], s_cb[18], s_xw[33*18], s_dw[18], s_db[18];
  for(int i=threadIdx.x;i<324;i+=256) s_in[i]=in_proj_w[i];
  for(int i=threadIdx.x;i<72;i+=256)  s_cw[i]=conv_w[i];
  for(int i=threadIdx.x;i<594;i+=256) s_xw[i]=x_proj_w[i];
  if(threadIdx.x<18){ s_cb[threadIdx.x]=conv_b[threadIdx.x];
                      s_dw[threadIdx.x]=dt_w[threadIdx.x];
                      s_db[threadIdx.x]=dt_b[threadIdx.x]; }
  __syncthreads();
  int idx = blockIdx.x*blockDim.x + threadIdx.x;
  int b = idx>>14, l = idx&16383;
  float ys4[4][9];
  #pragma unroll
  for(int m=0;m<9;m++){
    const float* p = yseqT + (size_t)(b*9+m)*LSEQ;
    #pragma unroll
    for(int t=0;t<4;t++){
      int lp = l-3+t;
      ys4[t][m] = (lp>=0) ? p[lp] : 0.f;
    }
  }
  float xi[18];
  #pragma unroll
  for(int d=0;d<18;d++){
    float cacc = s_cb[d];
    #pragma unroll
    for(int t=0;t<4;t++){
      float xr = 0.f;
      #pragma unroll
      for(int m=0;m<9;m++) xr += ys4[t][m]*s_in[d*9+m];
      cacc += xr * s_cw[d*4+t];
    }
    xi[d] = cacc / (1.f + __expf(-cacc));     // silu
  }
  float dblv[33];
  #pragma unroll
  for(int j=0;j<33;j++){
    float a=0.f;
    #pragma unroll
    for(int d=0;d<18;d++) a += xi[d]*s_xw[j*18+d];
    dblv[j]=a;
  }
  #pragma unroll
  for(int d=0;d<18;d++) XI_T[(size_t)(b*18+d)*LSEQ + l] = xi[d];
  #pragma unroll
  for(int d=0;d<18;d++){
    float a=0.f;
    #pragma unroll
    for(int m=0;m<9;m++) a += ys4[3][m]*s_in[(18+d)*9+m];
    ZZ_T[(size_t)(b*18+d)*LSEQ + l] = a;
    float pre = dblv[0]*s_dw[d] + s_db[d];
    DT_T[(size_t)(b*18+d)*LSEQ + l] = fmaxf(pre,0.f) + __logf(1.f + __expf(-fabsf(pre)));
  }
  #pragma unroll
  for(int s=0;s<16;s++){
    BS_T[(size_t)(b*16+s)*LSEQ + l] = dblv[1+s];
    CS_T[(size_t)(b*16+s)*LSEQ + l] = dblv[17+s];
  }
}

// ---------------- K6: chunk scan from zero state ----------------
__global__ void scan_pass1(const float* __restrict__ DT_T, const float* __restrict__ XI_T,
                           const float* __restrict__ BS_T, const float* __restrict__ Amat,
                           float* __restrict__ CP, float* __restrict__ CH){
  int blk = blockIdx.x; int b = blk/NCH; int c = blk%NCH;
  int t = threadIdx.x;                  // 288: d = t>>4, s = t&15
  int d = t>>4, s = t&15;
  float A = Amat[t];
  int l0 = c*CLEN;
  const float* dtp = DT_T + (size_t)(b*18+d)*LSEQ + l0;
  const float* xip = XI_T + (size_t)(b*18+d)*LSEQ + l0;
  const float* bsp = BS_T + (size_t)(b*16+s)*LSEQ + l0;
  float h=0.f, P=1.f;
  #pragma unroll 4
  for(int st=0; st<CLEN; ++st){
    float dt  = dtp[st];
    float xiv = xip[st];
    float Bv  = bsp[st];
    float a = __expf(dt*A);
    h = a*h + dt*Bv*xiv;
    P *= a;
  }
  size_t o = ((size_t)(b*NCH+c))*288 + t;
  CP[o]=P; CH[o]=h;
}

// ---------------- K7: parallel carry scan (wave per chain) ----------------
__global__ __launch_bounds__(256) void scan_carry_kernel(const float* __restrict__ CP,
                                                         const float* __restrict__ CH,
                                                         float* __restrict__ HIN){
  int wid = blockIdx.x*4 + (threadIdx.x>>6);   // 0..1151
  int lane = threadIdx.x&63;
  int b = wid/288, t = wid%288;
  int c0 = lane*4;
  float P[4], Hh[4];
  #pragma unroll
  for(int i=0;i<4;i++){
    size_t o = ((size_t)(b*NCH + c0+i))*288 + t;
    P[i]=CP[o]; Hh[i]=CH[o];
  }
  float aP = P[0], aH = Hh[0];
  #pragma unroll
  for(int i=1;i<4;i++){ aH = P[i]*aH + Hh[i]; aP = aP*P[i]; }
  float sP = aP, sH = aH;
  #pragma unroll
  for(int off=1; off<64; off<<=1){
    float pP = __shfl_up(sP, off, 64);
    float pH = __shfl_up(sH, off, 64);
    if(lane >= off){ sH = sP*pH + sH; sP = pP*sP; }
  }
  float eH = __shfl_up(sH, 1, 64);
  if(lane==0){ eH=0.f; }
  float cHh = eH;
  #pragma unroll
  for(int i=0;i<4;i++){
    size_t o = ((size_t)(b*NCH + c0+i))*288 + t;
    HIN[o] = cHh;
    cHh = P[i]*cHh + Hh[i];
  }
}

// ---------------- K8: chunk scan with true init + y output ----------------
__global__ void scan_pass2(const float* __restrict__ DT_T, const float* __restrict__ XI_T,
                           const float* __restrict__ BS_T, const float* __restrict__ CS_T,
                           const float* __restrict__ Amat, const float* __restrict__ HIN,
                           float* __restrict__ YST){
  int blk = blockIdx.x; int b = blk/NCH; int c = blk%NCH;
  int t = threadIdx.x;
  int d = t>>4, s = t&15;
  float A = Amat[t];
  float h = HIN[((size_t)(b*NCH+c))*288 + t];
  int l0 = c*CLEN;
  const float* dtp = DT_T + (size_t)(b*18+d)*LSEQ + l0;
  const float* xip = XI_T + (size_t)(b*18+d)*LSEQ + l0;
  const float* bsp = BS_T + (size_t)(b*16+s)*LSEQ + l0;
  const float* csp = CS_T + (size_t)(b*16+s)*LSEQ + l0;
  float* ysp = YST + (size_t)(b*18+d)*LSEQ + l0;
  #pragma unroll 2
  for(int st=0; st<CLEN; ++st){
    float dt  = dtp[st];
    float xiv = xip[st];
    float Bv  = bsp[st];
    float Cv  = csp[st];
    float a = __expf(dt*A);
    h = a*h + dt*Bv*xiv;
    float pc = h*Cv;
    pc += __shfl_xor(pc,1,16);
    pc += __shfl_xor(pc,2,16);
    pc += __shfl_xor(pc,4,16);
    pc += __shfl_xor(pc,8,16);
    if(s==0) ysp[st] = pc;
  }
}

// ---------------- K9: mamba epilogue + y_final ----------------
__global__ __launch_bounds__(256) void mamba_out_kernel(
    const float* __restrict__ YST, const float* __restrict__ XI_T,
    const float* __restrict__ ZZ_T, const float* __restrict__ Dp,
    const float* __restrict__ out_w, const float* __restrict__ altho,
    const float* __restrict__ ynew, float* __restrict__ yfin){
  __shared__ float s_ow[9*18], s_dp[18];
  for(int i=threadIdx.x;i<162;i+=256) s_ow[i]=out_w[i];
  if(threadIdx.x<18) s_dp[threadIdx.x]=Dp[threadIdx.x];
  __syncthreads();
  int idx = blockIdx.x*blockDim.x + threadIdx.x;
  int b = idx>>14, l = idx&16383;
  float y[18];
  #pragma unroll
  for(int d=0;d<18;d++){
    size_t o = (size_t)(b*18+d)*LSEQ + l;
    float z = ZZ_T[o];
    float sz = z/(1.f+__expf(-z));
    y[d] = (YST[o] + s_dp[d]*XI_T[o]) * sz;
  }
  float av = altho[0];
  float sp = fmaxf(av,0.f)+__logf(1.f+__expf(-fabsf(av)));
  float wgt = fmaxf(sp, 0.01f);
  int h = ((l>>8)<<1) | (l&1);
  int w = (l>>1)&127;
  int pix = h*WW + w;
  #pragma unroll
  for(int m=0;m<9;m++){
    float a=0.f;
    #pragma unroll
    for(int d=0;d<18;d++) a += y[d]*s_ow[m*18+d];
    size_t o = ((size_t)(b*9+m))*HW + pix;
    yfin[o] = wgt*a + ynew[o];
  }
}

// ---------------- K10: fused bilinear sample + 9x1 stride-9 conv, MFMA fp16 3-term ----
__global__ __launch_bounds__(256,2) void sample_conv_kernel(
    const _Float16* __restrict__ xTh, const _Float16* __restrict__ xTl,
    const float* __restrict__ yfin,
    const _Float16* __restrict__ AH, const _Float16* __restrict__ AL,
    const float* __restrict__ bias, float* __restrict__ outpre){
  __shared__ _Float16 F[2][2][64][72];   // [buf][hi/lo][px][ci padded to 72]
  int blk0 = blockIdx.x;                 // 1024 = 8 XCDs * 128
  int blk = (blk0&7)*128 + (blk0>>3);    // XCD-contiguous -> L2-resident rows
  int wo0 = (blk&1)*64;
  int ho  = (blk>>1)&127;
  int b   = blk>>8;
  int lane = threadIdx.x&63;
  int wv   = threadIdx.x>>6;             // 0..3
  int l32  = lane&31, g = lane>>5;
  int co0 = (wv&1)*32, pxh = (wv>>1)*32; // wave tile: 32 co x 32 px
  int px = lane;                         // gather role: lane = px
  int wo = wo0 + px;

  // ---- A-hi fragments, K=576 -> 36 ksteps, resident in VGPRs
  half8 ah[36];
  {
    const _Float16* basep = AH + ((size_t)(co0 + l32)*2 + g)*8;
    #pragma unroll
    for(int ks=0; ks<36; ks++)
      ah[ks] = *(const half8*)(basep + (size_t)ks*1024);
  }
  const _Float16* albase = AL + ((size_t)(co0 + l32)*2 + g)*8;

  floatx16 acc;
  #pragma unroll
  for(int r=0;r<16;r++) acc[r]=0.f;

  half8 h0[2], l0[2], h1[2], l1[2]; float wyv = 0.f;
  auto gather = [&](int k){
    float yv = yfin[((size_t)(b*9+k))*HW + ho*WW + wo];
    float py = fminf(fmaxf(yv,0.f),127.f);
    float y0f = floorf(py);
    wyv = py - y0f;
    int iy0 = (int)y0f;
    int iy1 = min(iy0+1,127);
    int xc  = min(max(wo + k - 4, 0), 127);
    size_t o0 = (((size_t)(b*HH+iy0))*WW + xc)*64 + wv*16;
    size_t o1 = (((size_t)(b*HH+iy1))*WW + xc)*64 + wv*16;
    #pragma unroll
    for(int q=0;q<2;q++){
      h0[q] = *(const half8*)(xTh + o0 + q*8);
      l0[q] = *(const half8*)(xTl + o0 + q*8);
      h1[q] = *(const half8*)(xTh + o1 + q*8);
      l1[q] = *(const half8*)(xTl + o1 + q*8);
    }
  };
  auto writeF = [&](int buf){
    #pragma unroll
    for(int q=0;q<2;q++){
      half8 vh, vl;
      #pragma unroll
      for(int e=0;e<8;e++){
        float v0 = (float)h0[q][e] + (float)l0[q][e];
        float v1 = (float)h1[q][e] + (float)l1[q][e];
        float v = v0 + wyv*(v1-v0);
        _Float16 hx = (_Float16)v;
        vh[e] = hx;
        vl[e] = (_Float16)(v - (float)hx);
      }
      *(half8*)&F[buf][0][px][wv*16 + q*8] = vh;
      *(half8*)&F[buf][1][px][wv*16 + q*8] = vl;
    }
  };

  gather(0); writeF(0);
  __syncthreads();
  #pragma unroll
  for(int k=0;k<9;k++){
    if(k<8) gather(k+1);
    int buf = k&1;
    #pragma unroll
    for(int q=0;q<4;q++){
      half8 bh = *(const half8*)&F[buf][0][pxh + l32][q*16 + g*8];
      half8 bl = *(const half8*)&F[buf][1][pxh + l32][q*16 + g*8];
      half8 al = *(const half8*)(albase + (size_t)(k*4+q)*1024);
      acc = __builtin_amdgcn_mfma_f32_32x32x16_f16(ah[k*4+q], bh, acc, 0,0,0);
      acc = __builtin_amdgcn_mfma_f32_32x32x16_f16(ah[k*4+q], bl, acc, 0,0,0);
      acc = __builtin_amdgcn_mfma_f32_32x32x16_f16(al,        bh, acc, 0,0,0);
    }
    if(k<8) writeF((k+1)&1);
    __syncthreads();
  }
  // C/D: col = lane&31 (px), row = (reg&3) + 8*(reg>>2) + 4*(lane>>5) (co)
  #pragma unroll
  for(int r=0;r<16;r++){
    int row = (r&3) + 8*(r>>2) + 4*g;
    int co = co0 + row;
    outpre[((size_t)(b*64+co))*HW + ho*WW + wo0 + pxh + l32] = acc[r] + bias[co];
  }
}

// ---------------- K12: final GN apply ----------------
__global__ __launch_bounds__(256) void gn2_apply_kernel(const float* __restrict__ src,
                                                        const float* __restrict__ stats,
                                                        const float* __restrict__ gam,
                                                        const float* __restrict__ bet,
                                                        float* __restrict__ dst){
  int idx = blockIdx.x*blockDim.x + threadIdx.x;  // BB*64*HW
  int c = (idx>>14)&63;
  int g = idx>>16;
  float mu = stats[g*2], inv = stats[g*2+1];
  dst[idx] = (src[idx]-mu)*inv*gam[c] + bet[c];
}

extern "C" void kernel_launch(void* const* d_in, const int* in_sizes, int n_in,
                              void* d_out, int out_size, void* d_ws, size_t ws_size,
                              hipStream_t stream){
  const float* x        = (const float*)d_in[0];
  const float* offset_w = (const float*)d_in[1];
  const float* offset_b = (const float*)d_in[2];
  const float* gno_g    = (const float*)d_in[3];
  const float* gno_b    = (const float*)d_in[4];
  const float* altho    = (const float*)d_in[5];
  const float* in_proj  = (const float*)d_in[6];
  const float* conv1d_w = (const float*)d_in[7];
  const float* conv1d_b = (const float*)d_in[8];
  const float* x_proj   = (const float*)d_in[9];
  const float* dt_w     = (const float*)d_in[10];
  const float* dt_b     = (const float*)d_in[11];
  const float* A_log    = (const float*)d_in[12];
  const float* D_p      = (const float*)d_in[13];
  const float* out_proj = (const float*)d_in[14];
  const float* dsc_w    = (const float*)d_in[15];
  const float* dsc_b    = (const float*)d_in[16];
  const float* gn_g     = (const float*)d_in[17];
  const float* gn_b     = (const float*)d_in[18];
  float* out = (float*)d_out;
  float* ws  = (float*)d_ws;
  if(ws_size < WS_TOTAL*sizeof(float)) return;

  float* off_raw = ws + OFF_RAW_O;
  float* yseqT   = ws + YSEQT_O;
  float* ynew    = ws + YNEW_O;
  float* gn1     = ws + GN1_O;
  float* DT_T    = ws + DT_O;
  float* XI_T    = ws + XI_O;
  float* ZZ_T    = ws + ZZ_O;
  float* BS_T    = ws + BS_O;
  float* CS_T    = ws + CS_O;
  float* CP      = ws + CP_O;
  float* CH      = ws + CHC_O;
  float* HIN     = ws + HIN_O;
  float* YST     = ws + YS_O;
  float* yfin    = ws + YFIN_O;
  _Float16* xTh  = (_Float16*)(ws + XTH_O);
  _Float16* xTl  = (_Float16*)(ws + XTL_O);
  float* outpre  = ws + OUTPRE_O;
  _Float16* AH   = (_Float16*)(ws + WT_O);
  _Float16* AL   = (_Float16*)(ws + WT_O) + 36864;
  _Float16* AOH  = (_Float16*)(ws + AO_O);
  _Float16* AOL  = (_Float16*)(ws + AO_O) + 9216;
  float* Amat    = ws + AMAT_O;
  float* gn2     = ws + GN2_O;

  prep_kernel<<<dim3(182), dim3(256), 0, stream>>>(dsc_w, offset_w, A_log, AH, AL, AOH, AOL, Amat);
  transpose_x_kernel<<<dim3(1024), dim3(256), 0, stream>>>(x, xTh, xTl);
  off_conv_kernel<<<dim3(512), dim3(256), 0, stream>>>(xTh, xTl, AOH, AOL, offset_b, off_raw);
  gn_stats_kernel<<<dim3(20), dim3(256), 0, stream>>>(off_raw, gn1, 2*HW, 1e-5f);
  gn1_apply_kernel<<<dim3(256), dim3(256), 0, stream>>>(off_raw, gn1, gno_g, gno_b, yseqT, ynew);
  mamba_feat_kernel<<<dim3(256), dim3(256), 0, stream>>>(yseqT, in_proj, conv1d_w, conv1d_b,
                                                         x_proj, dt_w, dt_b,
                                                         DT_T, XI_T, ZZ_T, BS_T, CS_T);
  scan_pass1<<<dim3(BB*NCH), dim3(288), 0, stream>>>(DT_T, XI_T, BS_T, Amat, CP, CH);
  scan_carry_kernel<<<dim3(288), dim3(256), 0, stream>>>(CP, CH, HIN);
  scan_pass2<<<dim3(BB*NCH), dim3(288), 0, stream>>>(DT_T, XI_T, BS_T, CS_T, Amat, HIN, YST);
  mamba_out_kernel<<<dim3(256), dim3(256), 0, stream>>>(YST, XI_T, ZZ_T, D_p, out_proj, altho,
                                                        ynew, yfin);
  sample_conv_kernel<<<dim3(1024), dim3(256), 0, stream>>>(xTh, xTl, yfin, AH, AL, dsc_b, outpre);
  gn_stats_kernel<<<dim3(64), dim3(256), 0, stream>>>(outpre, gn2, 4*HW, 1e-5f);
  gn2_apply_kernel<<<dim3(16384), dim3(256), 0, stream>>>(outpre, gn2, gn_g, gn_b, out);
}

// Round 6
// 316.963 us; speedup vs baseline: 1.4667x; 1.1036x over previous
//
#include <hip/hip_runtime.h>
#include <math.h>

#define BB 4
#define HH 128
#define WW 128
#define HW (HH*WW)       // 16384
#define LSEQ HW          // 16384
#define NCH 1024         // chunks per batch
#define CLEN 16          // chunk length

typedef _Float16 half8 __attribute__((ext_vector_type(8)));
typedef float floatx4 __attribute__((ext_vector_type(4)));
typedef float floatx16 __attribute__((ext_vector_type(16)));

// ---------------- workspace layout (in floats) ----------------
constexpr size_t OFF_RAW_O = 0;                      // (B,10,H,W)
constexpr size_t OFF_RAW_N = (size_t)BB*10*HW;
constexpr size_t YSEQT_O = OFF_RAW_O + OFF_RAW_N;    // (B,9,L)
constexpr size_t YSEQT_N = (size_t)BB*9*LSEQ;
constexpr size_t YNEW_O = YSEQT_O + YSEQT_N;         // (B,9,H,W)
constexpr size_t YNEW_N = (size_t)BB*9*HW;
constexpr size_t GN1_O = YNEW_O + YNEW_N;            // 20*(mu,inv)
constexpr size_t GN1_N = 64;
constexpr size_t CH18 = (size_t)BB*18*LSEQ;
constexpr size_t CH16 = (size_t)BB*16*LSEQ;
constexpr size_t DT_O = GN1_O + GN1_N;               // (B,L,18)
constexpr size_t XI_O = DT_O + CH18;                 // (B,L,18)
constexpr size_t ZZ_O = XI_O + CH18;                 // (B,L,18)
constexpr size_t BS_O = ZZ_O + CH18;                 // (B,L,16)
constexpr size_t CS_O = BS_O + CH16;                 // (B,L,16)
constexpr size_t CARR = (size_t)BB*NCH*288;
constexpr size_t CP_O = CS_O + CH16;                 // (B,NCH,288)
constexpr size_t CHC_O = CP_O + CARR;
constexpr size_t HIN_O = CHC_O + CARR;
constexpr size_t YS_O = HIN_O + CARR;                // (B,L,18)
constexpr size_t YFIN_O = YS_O + CH18;               // (B,9,H,W)
constexpr size_t XTH_O = YFIN_O + YNEW_N;            // (B,H,W,64) halfs -> /2 floats
constexpr size_t XTH_N = (size_t)BB*HW*32;
constexpr size_t XTL_O = XTH_O + XTH_N;
constexpr size_t OUTPRE_O = XTL_O + XTH_N;           // (B,64,H,W)
constexpr size_t OUTPRE_N = (size_t)BB*64*HW;
constexpr size_t WT_O = OUTPRE_O + OUTPRE_N;         // AH(36864 h) + AL(36864 h)
constexpr size_t AO_O = WT_O + 36864;                // AOH(9216 h) + AOL(9216 h)
constexpr size_t AMAT_O = AO_O + 9216;               // (18,16)
constexpr size_t GN2_O = AMAT_O + 288;               // 64*(mu,inv)
constexpr size_t WS_TOTAL = GN2_O + 128;

// ---------------- K0: MFMA weight frags + A matrix ----------------
__global__ void prep_kernel(const float* __restrict__ dsc_w, const float* __restrict__ offw,
                            const float* __restrict__ A_log,
                            _Float16* __restrict__ AH, _Float16* __restrict__ AL,
                            _Float16* __restrict__ AOH, _Float16* __restrict__ AOL,
                            float* __restrict__ Amat){
  int i = blockIdx.x*blockDim.x + threadIdx.x;
  if(i < 36864){
    int jj = i&7, gg = (i>>3)&1, co = (i>>4)&63, ks = i>>10;
    int k = ks>>2, q = ks&3;
    int ci = q*16 + gg*8 + jj;
    float w = dsc_w[((size_t)(co*64 + ci))*9 + k];   // dsc_w (co,ci,9,1)
    _Float16 h = (_Float16)w;
    AH[i] = h;
    AL[i] = (_Float16)(w - (float)h);
  }
  int j = i - 36864;
  if(j >= 0 && j < 9216){
    int jj = j&7, lane = (j>>3)&63, ksl = j>>9;      // ksl 0..17
    int tap = ksl>>1, ks = ksl&1;
    int co = lane&15, kg = lane>>4;
    int ci = ks*32 + kg*8 + jj;
    int dy = tap/3, dx = tap%3;
    float w = (co<10) ? offw[((size_t)(co*64 + ci)*3 + dy)*3 + dx] : 0.f;
    _Float16 h = (_Float16)w;
    AOH[j] = h;
    AOL[j] = (_Float16)(w - (float)h);
  }
  int a = i - 46080;
  if(a >= 0 && a < 288) Amat[a] = -__expf(A_log[a]);
}

// ---------------- K1: x (B,C,H,W) -> xTh/xTl (B,H,W,C) fp16 split ----------------
__global__ __launch_bounds__(256) void transpose_x_kernel(const float* __restrict__ x,
                                                          _Float16* __restrict__ xTh,
                                                          _Float16* __restrict__ xTl){
  __shared__ float tile[64][65];
  int blk = blockIdx.x;            // B*H*2
  int w0 = (blk&1)*64;
  int h  = (blk>>1)&127;
  int b  = blk>>8;
  int lane = threadIdx.x&63, q = threadIdx.x>>6;
  #pragma unroll
  for(int r=0;r<16;r++){
    int ci = r*4 + q;
    tile[ci][lane] = x[((size_t)(b*64+ci)*HH + h)*WW + w0 + lane];
  }
  __syncthreads();
  #pragma unroll
  for(int r=0;r<16;r++){
    int w = r*4 + q;
    float v = tile[lane][w];
    size_t o = (((size_t)(b*HH+h))*WW + w0 + w)*64 + lane;
    _Float16 hv = (_Float16)v;
    xTh[o] = hv;
    xTl[o] = (_Float16)(v - (float)hv);
  }
}

// ---------------- K2: 3x3 offset conv (out-ch 0..9) via 9 shifted MFMA GEMMs ------
__global__ __launch_bounds__(256) void off_conv_kernel(
    const _Float16* __restrict__ xTh, const _Float16* __restrict__ xTl,
    const _Float16* __restrict__ AOH, const _Float16* __restrict__ AOL,
    const float* __restrict__ offb, float* __restrict__ off_raw){
  int blk0 = blockIdx.x;               // 512 = 8 XCDs * 64
  int blk = (blk0&7)*64 + (blk0>>3);   // XCD-contiguous h ranges
  int h = blk&127, b = blk>>7;
  int lane = threadIdx.x&63, wv = threadIdx.x>>6;
  int col = lane&15, kg = lane>>4;
  floatx4 acc[2];
  acc[0] = (floatx4)0.f; acc[1] = (floatx4)0.f;
  for(int dy=0; dy<3; dy++){
    int hr = h + dy - 1;
    if(hr < 0 || hr >= HH) continue;
    for(int dx=0; dx<3; dx++){
      int tap = dy*3 + dx;
      #pragma unroll
      for(int ks=0; ks<2; ks++){
        half8 ah = *(const half8*)(AOH + (size_t)((tap*2+ks)*64 + lane)*8);
        half8 al = *(const half8*)(AOL + (size_t)((tap*2+ks)*64 + lane)*8);
        #pragma unroll
        for(int tt=0; tt<2; tt++){
          int px = wv*32 + tt*16 + col;
          int wc = px + dx - 1;
          half8 bh = {}, bl = {};
          if(wc >= 0 && wc < WW){
            size_t o = (((size_t)(b*HH+hr))*WW + wc)*64 + ks*32 + kg*8;
            bh = *(const half8*)(xTh + o);
            bl = *(const half8*)(xTl + o);
          }
          acc[tt] = __builtin_amdgcn_mfma_f32_16x16x32_f16(ah, bh, acc[tt], 0,0,0);
          acc[tt] = __builtin_amdgcn_mfma_f32_16x16x32_f16(ah, bl, acc[tt], 0,0,0);
          acc[tt] = __builtin_amdgcn_mfma_f32_16x16x32_f16(al, bh, acc[tt], 0,0,0);
        }
      }
    }
  }
  #pragma unroll
  for(int tt=0; tt<2; tt++){
    #pragma unroll
    for(int r=0; r<4; r++){
      int co = kg*4 + r;
      if(co < 10){
        int px = wv*32 + tt*16 + col;
        off_raw[((size_t)(b*10+co)*HH + h)*WW + px] = acc[tt][r] + offb[co];
      }
    }
  }
}

// ---------------- generic GroupNorm stats (contiguous groups) ----------------
__device__ inline float wave_red_sum(float v){
  #pragma unroll
  for(int off=32; off; off>>=1) v += __shfl_down(v, off, 64);
  return v;
}

__global__ __launch_bounds__(256) void gn_stats_kernel(const float* __restrict__ src,
                                                       float* __restrict__ out,
                                                       int per_grp, float eps){
  int g = blockIdx.x;
  const float4* p = (const float4*)(src + (size_t)g*per_grp);
  int n4 = per_grp>>2;
  float s=0.f, s2=0.f;
  for(int i=threadIdx.x; i<n4; i+=256){
    float4 v = p[i];
    s += v.x+v.y+v.z+v.w;
    s2 += v.x*v.x+v.y*v.y+v.z*v.z+v.w*v.w;
  }
  __shared__ float sh[4], sh2[4];
  s = wave_red_sum(s); s2 = wave_red_sum(s2);
  int w = threadIdx.x>>6;
  if((threadIdx.x&63)==0){ sh[w]=s; sh2[w]=s2; }
  __syncthreads();
  if(threadIdx.x==0){
    float S=0.f,S2=0.f;
    for(int i=0;i<4;i++){S+=sh[i];S2+=sh2[i];}
    float mu = S/per_grp;
    float var = S2/per_grp - mu*mu;
    out[g*2] = mu; out[g*2+1] = rsqrtf(var+eps);
  }
}

// ---------------- K4: GN1 apply + tanh + cumsum + zigzag ----------------
__global__ __launch_bounds__(256) void gn1_apply_kernel(const float* __restrict__ off_raw,
                                                        const float* __restrict__ stats,
                                                        const float* __restrict__ gno_g,
                                                        const float* __restrict__ gno_b,
                                                        float* __restrict__ yseqT,
                                                        float* __restrict__ ynew){
  int idx = blockIdx.x*blockDim.x + threadIdx.x;   // BB*HW
  int b = idx>>14; int pix = idx&16383; int h = pix>>7, w = pix&127;
  float t[9];
  #pragma unroll
  for(int c=0;c<9;c++){
    float v = off_raw[((size_t)(b*10+c))*HW + pix];
    int g = b*5 + (c>>1);
    float mu = stats[g*2], inv = stats[g*2+1];
    float xx = (v-mu)*inv*gno_g[c] + gno_b[c];
    xx = fminf(fmaxf(xx,-15.f),15.f);
    float e2 = __expf(2.f*xx);
    t[c] = (e2-1.f)/(e2+1.f);
  }
  int l = (((h>>1)*WW + w)<<1) | (h&1);
  #pragma unroll
  for(int c=0;c<9;c++) yseqT[((size_t)(b*9+c))*LSEQ + l] = t[c];
  float rows[9];
  rows[4]=0.f;
  rows[5]=t[5]; rows[6]=rows[5]+t[6]; rows[7]=rows[6]+t[7]; rows[8]=rows[7]+t[8];
  rows[3]=t[3]; rows[2]=rows[3]+t[2]; rows[1]=rows[2]+t[1]; rows[0]=rows[1]+t[0];
  #pragma unroll
  for(int k=0;k<9;k++) ynew[((size_t)(b*9+k))*HW + pix] = (float)h + rows[k];
}

// ---------------- K5: mamba featurize (parallel over l, l-major outputs) -----------
__global__ __launch_bounds__(256) void mamba_feat_kernel(
    const float* __restrict__ yseqT, const float* __restrict__ in_proj_w,
    const float* __restrict__ conv_w, const float* __restrict__ conv_b,
    const float* __restrict__ x_proj_w, const float* __restrict__ dt_w,
    const float* __restrict__ dt_b,
    float* __restrict__ DT_L, float* __restrict__ XI_L, float* __restrict__ ZZ_L,
    float* __restrict__ BS_L, float* __restrict__ CS_L){
  __shared__ float s_in[36*9], s_cw[18*4], s_cb[18], s_xw[33*18], s_dw[18], s_db[18];
  for(int i=threadIdx.x;i<324;i+=256) s_in[i]=in_proj_w[i];
  for(int i=threadIdx.x;i<72;i+=256)  s_cw[i]=conv_w[i];
  for(int i=threadIdx.x;i<594;i+=256) s_xw[i]=x_proj_w[i];
  if(threadIdx.x<18){ s_cb[threadIdx.x]=conv_b[threadIdx.x];
                      s_dw[threadIdx.x]=dt_w[threadIdx.x];
                      s_db[threadIdx.x]=dt_b[threadIdx.x]; }
  __syncthreads();
  int idx = blockIdx.x*blockDim.x + threadIdx.x;
  int b = idx>>14, l = idx&16383;
  float ys4[4][9];
  #pragma unroll
  for(int m=0;m<9;m++){
    const float* p = yseqT + (size_t)(b*9+m)*LSEQ;
    #pragma unroll
    for(int t=0;t<4;t++){
      int lp = l-3+t;
      ys4[t][m] = (lp>=0) ? p[lp] : 0.f;
    }
  }
  float xi[18];
  #pragma unroll
  for(int d=0;d<18;d++){
    float cacc = s_cb[d];
    #pragma unroll
    for(int t=0;t<4;t++){
      float xr = 0.f;
      #pragma unroll
      for(int m=0;m<9;m++) xr += ys4[t][m]*s_in[d*9+m];
      cacc += xr * s_cw[d*4+t];
    }
    xi[d] = cacc / (1.f + __expf(-cacc));     // silu
  }
  float dblv[33];
  #pragma unroll
  for(int j=0;j<33;j++){
    float a=0.f;
    #pragma unroll
    for(int d=0;d<18;d++) a += xi[d]*s_xw[j*18+d];
    dblv[j]=a;
  }
  size_t lb = (size_t)b*LSEQ + l;
  #pragma unroll
  for(int d=0;d<18;d++) XI_L[lb*18 + d] = xi[d];
  #pragma unroll
  for(int d=0;d<18;d++){
    float a=0.f;
    #pragma unroll
    for(int m=0;m<9;m++) a += ys4[3][m]*s_in[(18+d)*9+m];
    ZZ_L[lb*18 + d] = a;
    float pre = dblv[0]*s_dw[d] + s_db[d];
    DT_L[lb*18 + d] = fmaxf(pre,0.f) + __logf(1.f + __expf(-fabsf(pre)));
  }
  #pragma unroll
  for(int s=0;s<16;s++){
    BS_L[lb*16 + s] = dblv[1+s];
    CS_L[lb*16 + s] = dblv[17+s];
  }
}

// ---------------- K6: chunk scan, thread = (b,chunk,d) holding 16 s-states ---------
__global__ __launch_bounds__(288) void scan_pass1(const float* __restrict__ DT_L,
                                                  const float* __restrict__ XI_L,
                                                  const float* __restrict__ BS_L,
                                                  const float* __restrict__ Amat,
                                                  float* __restrict__ CP, float* __restrict__ CH){
  int blk = blockIdx.x;                  // B * NCH/16
  int b = blk>>6; int ckb = (blk&63)<<4;
  int tid = threadIdx.x;
  int d = tid%18, ck = tid/18;
  int c = ckb + ck;
  int l0 = c*CLEN;
  float A[16];
  #pragma unroll
  for(int i=0;i<4;i++){
    float4 t = *(const float4*)(Amat + d*16 + i*4);
    A[i*4]=t.x; A[i*4+1]=t.y; A[i*4+2]=t.z; A[i*4+3]=t.w;
  }
  float h[16], P[16];
  #pragma unroll
  for(int s=0;s<16;s++){ h[s]=0.f; P[s]=1.f; }
  const float* dtp = DT_L + ((size_t)b*LSEQ + l0)*18 + d;
  const float* xip = XI_L + ((size_t)b*LSEQ + l0)*18 + d;
  const float* bsp = BS_L + ((size_t)b*LSEQ + l0)*16;
  #pragma unroll 4
  for(int st=0; st<CLEN; ++st){
    float dt  = dtp[st*18];
    float dx  = dt*xip[st*18];
    float Bv[16];
    #pragma unroll
    for(int i=0;i<4;i++){
      float4 t = *(const float4*)(bsp + st*16 + i*4);
      Bv[i*4]=t.x; Bv[i*4+1]=t.y; Bv[i*4+2]=t.z; Bv[i*4+3]=t.w;
    }
    #pragma unroll
    for(int s=0;s<16;s++){
      float a = __expf(dt*A[s]);
      h[s] = a*h[s] + dx*Bv[s];
      P[s] *= a;
    }
  }
  float* cpp = CP + ((size_t)(b*NCH+c))*288 + d*16;
  float* chp = CH + ((size_t)(b*NCH+c))*288 + d*16;
  #pragma unroll
  for(int i=0;i<4;i++){
    float4 tp; tp.x=P[i*4]; tp.y=P[i*4+1]; tp.z=P[i*4+2]; tp.w=P[i*4+3];
    float4 th; th.x=h[i*4]; th.y=h[i*4+1]; th.z=h[i*4+2]; th.w=h[i*4+3];
    *(float4*)(cpp+i*4)=tp; *(float4*)(chp+i*4)=th;
  }
}

// ---------------- K7: parallel carry scan (wave per (b,t) chain, 16 chunks/lane) ----
__global__ __launch_bounds__(256) void scan_carry_kernel(const float* __restrict__ CP,
                                                         const float* __restrict__ CH,
                                                         float* __restrict__ HIN){
  int wid = blockIdx.x*4 + (threadIdx.x>>6);   // 0..1151
  int lane = threadIdx.x&63;
  int b = wid/288, t = wid%288;
  int c0 = lane*16;
  float P[16], Hh[16];
  #pragma unroll
  for(int i=0;i<16;i++){
    size_t o = ((size_t)(b*NCH + c0+i))*288 + t;
    P[i]=CP[o]; Hh[i]=CH[o];
  }
  float aP = P[0], aH = Hh[0];
  #pragma unroll
  for(int i=1;i<16;i++){ aH = P[i]*aH + Hh[i]; aP = aP*P[i]; }
  float sP = aP, sH = aH;
  #pragma unroll
  for(int off=1; off<64; off<<=1){
    float pP = __shfl_up(sP, off, 64);
    float pH = __shfl_up(sH, off, 64);
    if(lane >= off){ sH = sP*pH + sH; sP = pP*sP; }
  }
  float eH = __shfl_up(sH, 1, 64);
  if(lane==0){ eH=0.f; }
  float cHh = eH;
  #pragma unroll
  for(int i=0;i<16;i++){
    size_t o = ((size_t)(b*NCH + c0+i))*288 + t;
    HIN[o] = cHh;
    cHh = P[i]*cHh + Hh[i];
  }
}

// ---------------- K8: chunk scan with true init + y output (in-thread C-dot) -------
__global__ __launch_bounds__(288) void scan_pass2(const float* __restrict__ DT_L,
                                                  const float* __restrict__ XI_L,
                                                  const float* __restrict__ BS_L,
                                                  const float* __restrict__ CS_L,
                                                  const float* __restrict__ Amat,
                                                  const float* __restrict__ HIN,
                                                  float* __restrict__ YST_L){
  int blk = blockIdx.x;
  int b = blk>>6; int ckb = (blk&63)<<4;
  int tid = threadIdx.x;
  int d = tid%18, ck = tid/18;
  int c = ckb + ck;
  int l0 = c*CLEN;
  float A[16];
  #pragma unroll
  for(int i=0;i<4;i++){
    float4 t = *(const float4*)(Amat + d*16 + i*4);
    A[i*4]=t.x; A[i*4+1]=t.y; A[i*4+2]=t.z; A[i*4+3]=t.w;
  }
  float h[16];
  {
    const float* hp = HIN + ((size_t)(b*NCH+c))*288 + d*16;
    #pragma unroll
    for(int i=0;i<4;i++){
      float4 t = *(const float4*)(hp + i*4);
      h[i*4]=t.x; h[i*4+1]=t.y; h[i*4+2]=t.z; h[i*4+3]=t.w;
    }
  }
  const float* dtp = DT_L + ((size_t)b*LSEQ + l0)*18 + d;
  const float* xip = XI_L + ((size_t)b*LSEQ + l0)*18 + d;
  const float* bsp = BS_L + ((size_t)b*LSEQ + l0)*16;
  const float* csp = CS_L + ((size_t)b*LSEQ + l0)*16;
  float* ysp = YST_L + ((size_t)b*LSEQ + l0)*18 + d;
  #pragma unroll 4
  for(int st=0; st<CLEN; ++st){
    float dt  = dtp[st*18];
    float dx  = dt*xip[st*18];
    float Bv[16], Cv[16];
    #pragma unroll
    for(int i=0;i<4;i++){
      float4 t = *(const float4*)(bsp + st*16 + i*4);
      Bv[i*4]=t.x; Bv[i*4+1]=t.y; Bv[i*4+2]=t.z; Bv[i*4+3]=t.w;
      float4 u = *(const float4*)(csp + st*16 + i*4);
      Cv[i*4]=u.x; Cv[i*4+1]=u.y; Cv[i*4+2]=u.z; Cv[i*4+3]=u.w;
    }
    float pc = 0.f;
    #pragma unroll
    for(int s=0;s<16;s++){
      float a = __expf(dt*A[s]);
      h[s] = a*h[s] + dx*Bv[s];
      pc += h[s]*Cv[s];
    }
    ysp[st*18] = pc;
  }
}

// ---------------- K9: mamba epilogue + y_final ----------------
__global__ __launch_bounds__(256) void mamba_out_kernel(
    const float* __restrict__ YST_L, const float* __restrict__ XI_L,
    const float* __restrict__ ZZ_L, const float* __restrict__ Dp,
    const float* __restrict__ out_w, const float* __restrict__ altho,
    const float* __restrict__ ynew, float* __restrict__ yfin){
  __shared__ float s_ow[9*18], s_dp[18];
  for(int i=threadIdx.x;i<162;i+=256) s_ow[i]=out_w[i];
  if(threadIdx.x<18) s_dp[threadIdx.x]=Dp[threadIdx.x];
  __syncthreads();
  int idx = blockIdx.x*blockDim.x + threadIdx.x;
  int b = idx>>14, l = idx&16383;
  size_t lb = (size_t)b*LSEQ + l;
  float y[18];
  #pragma unroll
  for(int d=0;d<18;d++){
    float z = ZZ_L[lb*18+d];
    float sz = z/(1.f+__expf(-z));
    y[d] = (YST_L[lb*18+d] + s_dp[d]*XI_L[lb*18+d]) * sz;
  }
  float av = altho[0];
  float sp = fmaxf(av,0.f)+__logf(1.f+__expf(-fabsf(av)));
  float wgt = fmaxf(sp, 0.01f);
  int h = ((l>>8)<<1) | (l&1);
  int w = (l>>1)&127;
  int pix = h*WW + w;
  #pragma unroll
  for(int m=0;m<9;m++){
    float a=0.f;
    #pragma unroll
    for(int d=0;d<18;d++) a += y[d]*s_ow[m*18+d];
    size_t o = ((size_t)(b*9+m))*HW + pix;
    yfin[o] = wgt*a + ynew[o];
  }
}

// ---------------- K10: fused bilinear sample + 9x1 stride-9 conv, MFMA fp16 3-term ----
__global__ __launch_bounds__(256,2) void sample_conv_kernel(
    const _Float16* __restrict__ xTh, const _Float16* __restrict__ xTl,
    const float* __restrict__ yfin,
    const _Float16* __restrict__ AH, const _Float16* __restrict__ AL,
    const float* __restrict__ bias, float* __restrict__ outpre){
  __shared__ _Float16 F[2][2][64][72];   // [buf][hi/lo][px][ci padded to 72]
  int blk0 = blockIdx.x;                 // 1024 = 8 XCDs * 128
  int blk = (blk0&7)*128 + (blk0>>3);    // XCD-contiguous -> L2-resident rows
  int wo0 = (blk&1)*64;
  int ho  = (blk>>1)&127;
  int b   = blk>>8;
  int lane = threadIdx.x&63;
  int wv   = threadIdx.x>>6;             // 0..3
  int l32  = lane&31, g = lane>>5;
  int co0 = (wv&1)*32, pxh = (wv>>1)*32; // wave tile: 32 co x 32 px
  int px = lane;                         // gather role: lane = px
  int wo = wo0 + px;

  half8 ah[36];
  {
    const _Float16* basep = AH + ((size_t)(co0 + l32)*2 + g)*8;
    #pragma unroll
    for(int ks=0; ks<36; ks++)
      ah[ks] = *(const half8*)(basep + (size_t)ks*1024);
  }
  const _Float16* albase = AL + ((size_t)(co0 + l32)*2 + g)*8;

  floatx16 acc;
  #pragma unroll
  for(int r=0;r<16;r++) acc[r]=0.f;

  half8 h0[2], l0[2], h1[2], l1[2]; float wyv = 0.f;
  auto gather = [&](int k){
    float yv = yfin[((size_t)(b*9+k))*HW + ho*WW + wo];
    float py = fminf(fmaxf(yv,0.f),127.f);
    float y0f = floorf(py);
    wyv = py - y0f;
    int iy0 = (int)y0f;
    int iy1 = min(iy0+1,127);
    int xc  = min(max(wo + k - 4, 0), 127);
    size_t o0 = (((size_t)(b*HH+iy0))*WW + xc)*64 + wv*16;
    size_t o1 = (((size_t)(b*HH+iy1))*WW + xc)*64 + wv*16;
    #pragma unroll
    for(int q=0;q<2;q++){
      h0[q] = *(const half8*)(xTh + o0 + q*8);
      l0[q] = *(const half8*)(xTl + o0 + q*8);
      h1[q] = *(const half8*)(xTh + o1 + q*8);
      l1[q] = *(const half8*)(xTl + o1 + q*8);
    }
  };
  auto writeF = [&](int buf){
    #pragma unroll
    for(int q=0;q<2;q++){
      half8 vh, vl;
      #pragma unroll
      for(int e=0;e<8;e++){
        float v0 = (float)h0[q][e] + (float)l0[q][e];
        float v1 = (float)h1[q][e] + (float)l1[q][e];
        float v = v0 + wyv*(v1-v0);
        _Float16 hx = (_Float16)v;
        vh[e] = hx;
        vl[e] = (_Float16)(v - (float)hx);
      }
      *(half8*)&F[buf][0][px][wv*16 + q*8] = vh;
      *(half8*)&F[buf][1][px][wv*16 + q*8] = vl;
    }
  };

  gather(0); writeF(0);
  __syncthreads();
  #pragma unroll
  for(int k=0;k<9;k++){
    if(k<8) gather(k+1);
    int buf = k&1;
    #pragma unroll
    for(int q=0;q<4;q++){
      half8 bh = *(const half8*)&F[buf][0][pxh + l32][q*16 + g*8];
      half8 bl = *(const half8*)&F[buf][1][pxh + l32][q*16 + g*8];
      half8 al = *(const half8*)(albase + (size_t)(k*4+q)*1024);
      acc = __builtin_amdgcn_mfma_f32_32x32x16_f16(ah[k*4+q], bh, acc, 0,0,0);
      acc = __builtin_amdgcn_mfma_f32_32x32x16_f16(ah[k*4+q], bl, acc, 0,0,0);
      acc = __builtin_amdgcn_mfma_f32_32x32x16_f16(al,        bh, acc, 0,0,0);
    }
    if(k<8) writeF((k+1)&1);
    __syncthreads();
  }
  #pragma unroll
  for(int r=0;r<16;r++){
    int row = (r&3) + 8*(r>>2) + 4*g;
    int co = co0 + row;
    outpre[((size_t)(b*64+co))*HW + ho*WW + wo0 + pxh + l32] = acc[r] + bias[co];
  }
}

// ---------------- K12: final GN apply ----------------
__global__ __launch_bounds__(256) void gn2_apply_kernel(const float* __restrict__ src,
                                                        const float* __restrict__ stats,
                                                        const float* __restrict__ gam,
                                                        const float* __restrict__ bet,
                                                        float* __restrict__ dst){
  int idx = blockIdx.x*blockDim.x + threadIdx.x;  // BB*64*HW
  int c = (idx>>14)&63;
  int g = idx>>16;
  float mu = stats[g*2], inv = stats[g*2+1];
  dst[idx] = (src[idx]-mu)*inv*gam[c] + bet[c];
}

extern "C" void kernel_launch(void* const* d_in, const int* in_sizes, int n_in,
                              void* d_out, int out_size, void* d_ws, size_t ws_size,
                              hipStream_t stream){
  const float* x        = (const float*)d_in[0];
  const float* offset_w = (const float*)d_in[1];
  const float* offset_b = (const float*)d_in[2];
  const float* gno_g    = (const float*)d_in[3];
  const float* gno_b    = (const float*)d_in[4];
  const float* altho    = (const float*)d_in[5];
  const float* in_proj  = (const float*)d_in[6];
  const float* conv1d_w = (const float*)d_in[7];
  const float* conv1d_b = (const float*)d_in[8];
  const float* x_proj   = (const float*)d_in[9];
  const float* dt_w     = (const float*)d_in[10];
  const float* dt_b     = (const float*)d_in[11];
  const float* A_log    = (const float*)d_in[12];
  const float* D_p      = (const float*)d_in[13];
  const float* out_proj = (const float*)d_in[14];
  const float* dsc_w    = (const float*)d_in[15];
  const float* dsc_b    = (const float*)d_in[16];
  const float* gn_g     = (const float*)d_in[17];
  const float* gn_b     = (const float*)d_in[18];
  float* out = (float*)d_out;
  float* ws  = (float*)d_ws;
  if(ws_size < WS_TOTAL*sizeof(float)) return;

  float* off_raw = ws + OFF_RAW_O;
  float* yseqT   = ws + YSEQT_O;
  float* ynew    = ws + YNEW_O;
  float* gn1     = ws + GN1_O;
  float* DT_L    = ws + DT_O;
  float* XI_L    = ws + XI_O;
  float* ZZ_L    = ws + ZZ_O;
  float* BS_L    = ws + BS_O;
  float* CS_L    = ws + CS_O;
  float* CP      = ws + CP_O;
  float* CH      = ws + CHC_O;
  float* HIN     = ws + HIN_O;
  float* YST_L   = ws + YS_O;
  float* yfin    = ws + YFIN_O;
  _Float16* xTh  = (_Float16*)(ws + XTH_O);
  _Float16* xTl  = (_Float16*)(ws + XTL_O);
  float* outpre  = ws + OUTPRE_O;
  _Float16* AH   = (_Float16*)(ws + WT_O);
  _Float16* AL   = (_Float16*)(ws + WT_O) + 36864;
  _Float16* AOH  = (_Float16*)(ws + AO_O);
  _Float16* AOL  = (_Float16*)(ws + AO_O) + 9216;
  float* Amat    = ws + AMAT_O;
  float* gn2     = ws + GN2_O;

  prep_kernel<<<dim3(182), dim3(256), 0, stream>>>(dsc_w, offset_w, A_log, AH, AL, AOH, AOL, Amat);
  transpose_x_kernel<<<dim3(1024), dim3(256), 0, stream>>>(x, xTh, xTl);
  off_conv_kernel<<<dim3(512), dim3(256), 0, stream>>>(xTh, xTl, AOH, AOL, offset_b, off_raw);
  gn_stats_kernel<<<dim3(20), dim3(256), 0, stream>>>(off_raw, gn1, 2*HW, 1e-5f);
  gn1_apply_kernel<<<dim3(256), dim3(256), 0, stream>>>(off_raw, gn1, gno_g, gno_b, yseqT, ynew);
  mamba_feat_kernel<<<dim3(256), dim3(256), 0, stream>>>(yseqT, in_proj, conv1d_w, conv1d_b,
                                                         x_proj, dt_w, dt_b,
                                                         DT_L, XI_L, ZZ_L, BS_L, CS_L);
  scan_pass1<<<dim3(BB*NCH/16), dim3(288), 0, stream>>>(DT_L, XI_L, BS_L, Amat, CP, CH);
  scan_carry_kernel<<<dim3(288), dim3(256), 0, stream>>>(CP, CH, HIN);
  scan_pass2<<<dim3(BB*NCH/16), dim3(288), 0, stream>>>(DT_L, XI_L, BS_L, CS_L, Amat, HIN, YST_L);
  mamba_out_kernel<<<dim3(256), dim3(256), 0, stream>>>(YST_L, XI_L, ZZ_L, D_p, out_proj, altho,
                                                        ynew, yfin);
  sample_conv_kernel<<<dim3(1024), dim3(256), 0, stream>>>(xTh, xTl, yfin, AH, AL, dsc_b, outpre);
  gn_stats_kernel<<<dim3(64), dim3(256), 0, stream>>>(outpre, gn2, 4*HW, 1e-5f);
  gn2_apply_kernel<<<dim3(16384), dim3(256), 0, stream>>>(outpre, gn2, gn_g, gn_b, out);
}

// Round 7
// 241.010 us; speedup vs baseline: 1.9290x; 1.3151x over previous
//
#include <hip/hip_runtime.h>
#include <math.h>

#define BB 4
#define HH 128
#define WW 128
#define HW (HH*WW)       // 16384
#define LSEQ HW          // 16384
#define NCH 1024         // chunks per batch
#define CLEN 16          // chunk length

typedef _Float16 half8 __attribute__((ext_vector_type(8)));
typedef float floatx4 __attribute__((ext_vector_type(4)));
typedef float floatx16 __attribute__((ext_vector_type(16)));

// ---------------- workspace layout (in floats) ----------------
constexpr size_t OFF_RAW_O = 0;                      // (B,10,H,W)
constexpr size_t OFF_RAW_N = (size_t)BB*10*HW;
constexpr size_t YSEQT_O = OFF_RAW_O + OFF_RAW_N;    // (B,9,L)
constexpr size_t YSEQT_N = (size_t)BB*9*LSEQ;
constexpr size_t YNEW_O = YSEQT_O + YSEQT_N;         // (B,9,H,W)
constexpr size_t YNEW_N = (size_t)BB*9*HW;
constexpr size_t GN1_O = YNEW_O + YNEW_N;            // raw sums (B,5,2) = 40
constexpr size_t GN1_N = 64;
constexpr size_t CH18 = (size_t)BB*18*LSEQ;
constexpr size_t CH16 = (size_t)BB*16*LSEQ;
constexpr size_t DT_O = GN1_O + GN1_N;               // (B,L,18)
constexpr size_t XI_O = DT_O + CH18;                 // (B,L,18)
constexpr size_t ZZ_O = XI_O + CH18;                 // (B,L,18)
constexpr size_t BS_O = ZZ_O + CH18;                 // (B,L,16)
constexpr size_t CS_O = BS_O + CH16;                 // (B,L,16)
constexpr size_t CARR = (size_t)BB*NCH*288;
constexpr size_t CP_O = CS_O + CH16;                 // (B,288,NCH)  t-major!
constexpr size_t CHC_O = CP_O + CARR;
constexpr size_t HIN_O = CHC_O + CARR;
constexpr size_t YS_O = HIN_O + CARR;                // (B,L,18)
constexpr size_t YFIN_O = YS_O + CH18;               // (B,9,H,W)
constexpr size_t XTH_O = YFIN_O + YNEW_N;            // (B,H,W,64) halfs
constexpr size_t XTH_N = (size_t)BB*HW*32;
constexpr size_t XTL_O = XTH_O + XTH_N;
constexpr size_t OUTPRE_O = XTL_O + XTH_N;           // (B,64,H,W)
constexpr size_t OUTPRE_N = (size_t)BB*64*HW;
constexpr size_t WT_O = OUTPRE_O + OUTPRE_N;         // AH(36864 h) + AL(36864 h)
constexpr size_t AO_O = WT_O + 36864;                // AOH(9216 h) + AOL(9216 h)
constexpr size_t AMAT_O = AO_O + 9216;               // (18,16)
constexpr size_t GN2_O = AMAT_O + 288;               // raw sums (B,16,2) = 128
constexpr size_t WS_TOTAL = GN2_O + 128;

// ---------------- K0: MFMA weight frags + A matrix + zero stat sums ----------------
__global__ void prep_kernel(const float* __restrict__ dsc_w, const float* __restrict__ offw,
                            const float* __restrict__ A_log,
                            _Float16* __restrict__ AH, _Float16* __restrict__ AL,
                            _Float16* __restrict__ AOH, _Float16* __restrict__ AOL,
                            float* __restrict__ Amat,
                            float* __restrict__ gn1s, float* __restrict__ gn2s){
  int i = blockIdx.x*blockDim.x + threadIdx.x;
  if(blockIdx.x==0){
    if(threadIdx.x<40) gn1s[threadIdx.x]=0.f;
    if(threadIdx.x>=64 && threadIdx.x<192) gn2s[threadIdx.x-64]=0.f;
  }
  if(i < 36864){
    int jj = i&7, gg = (i>>3)&1, co = (i>>4)&63, ks = i>>10;
    int k = ks>>2, q = ks&3;
    int ci = q*16 + gg*8 + jj;
    float w = dsc_w[((size_t)(co*64 + ci))*9 + k];   // dsc_w (co,ci,9,1)
    _Float16 h = (_Float16)w;
    AH[i] = h;
    AL[i] = (_Float16)(w - (float)h);
  }
  int j = i - 36864;
  if(j >= 0 && j < 9216){
    int jj = j&7, lane = (j>>3)&63, ksl = j>>9;      // ksl 0..17
    int tap = ksl>>1, ks = ksl&1;
    int co = lane&15, kg = lane>>4;
    int ci = ks*32 + kg*8 + jj;
    int dy = tap/3, dx = tap%3;
    float w = (co<10) ? offw[((size_t)(co*64 + ci)*3 + dy)*3 + dx] : 0.f;
    _Float16 h = (_Float16)w;
    AOH[j] = h;
    AOL[j] = (_Float16)(w - (float)h);
  }
  int a = i - 46080;
  if(a >= 0 && a < 288) Amat[a] = -__expf(A_log[a]);
}

// ---------------- K1: x (B,C,H,W) -> xTh/xTl (B,H,W,C) fp16 split ----------------
__global__ __launch_bounds__(256) void transpose_x_kernel(const float* __restrict__ x,
                                                          _Float16* __restrict__ xTh,
                                                          _Float16* __restrict__ xTl){
  __shared__ float tile[64][65];
  int blk = blockIdx.x;            // B*H*2
  int w0 = (blk&1)*64;
  int h  = (blk>>1)&127;
  int b  = blk>>8;
  int lane = threadIdx.x&63, q = threadIdx.x>>6;
  #pragma unroll
  for(int r=0;r<16;r++){
    int ci = r*4 + q;
    tile[ci][lane] = x[((size_t)(b*64+ci)*HH + h)*WW + w0 + lane];
  }
  __syncthreads();
  #pragma unroll
  for(int r=0;r<16;r++){
    int w = r*4 + q;
    float v = tile[lane][w];
    size_t o = (((size_t)(b*HH+h))*WW + w0 + w)*64 + lane;
    _Float16 hv = (_Float16)v;
    xTh[o] = hv;
    xTl[o] = (_Float16)(v - (float)hv);
  }
}

// ---------------- K2: 3x3 offset conv (out-ch 0..9), 2-term MFMA + fused GN1 stats --
__global__ __launch_bounds__(256) void off_conv_kernel(
    const _Float16* __restrict__ xTh,
    const _Float16* __restrict__ AOH, const _Float16* __restrict__ AOL,
    const float* __restrict__ offb, float* __restrict__ off_raw,
    float* __restrict__ gn1sums){
  __shared__ float sred[6][2];
  int blk0 = blockIdx.x;               // 512 = 8 XCDs * 64
  int blk = (blk0&7)*64 + (blk0>>3);   // XCD-contiguous h ranges
  int h = blk&127, b = blk>>7;
  int lane = threadIdx.x&63, wv = threadIdx.x>>6;
  int col = lane&15, kg = lane>>4;
  if(threadIdx.x<10) ((float*)sred)[threadIdx.x]=0.f;
  __syncthreads();
  floatx4 acc[2];
  acc[0] = (floatx4)0.f; acc[1] = (floatx4)0.f;
  for(int dy=0; dy<3; dy++){
    int hr = h + dy - 1;
    if(hr < 0 || hr >= HH) continue;
    for(int dx=0; dx<3; dx++){
      int tap = dy*3 + dx;
      #pragma unroll
      for(int ks=0; ks<2; ks++){
        half8 ah = *(const half8*)(AOH + (size_t)((tap*2+ks)*64 + lane)*8);
        half8 al = *(const half8*)(AOL + (size_t)((tap*2+ks)*64 + lane)*8);
        #pragma unroll
        for(int tt=0; tt<2; tt++){
          int px = wv*32 + tt*16 + col;
          int wc = px + dx - 1;
          half8 bh = {};
          if(wc >= 0 && wc < WW)
            bh = *(const half8*)(xTh + (((size_t)(b*HH+hr))*WW + wc)*64 + ks*32 + kg*8);
          acc[tt] = __builtin_amdgcn_mfma_f32_16x16x32_f16(ah, bh, acc[tt], 0,0,0);
          acc[tt] = __builtin_amdgcn_mfma_f32_16x16x32_f16(al, bh, acc[tt], 0,0,0);
        }
      }
    }
  }
  float gs[2][2] = {{0.f,0.f},{0.f,0.f}};
  #pragma unroll
  for(int tt=0; tt<2; tt++){
    #pragma unroll
    for(int r=0; r<4; r++){
      int co = kg*4 + r;
      if(co < 10){
        int px = wv*32 + tt*16 + col;
        float v = acc[tt][r] + offb[co];
        off_raw[((size_t)(b*10+co)*HH + h)*WW + px] = v;
        gs[r>>1][0] += v; gs[r>>1][1] += v*v;
      }
    }
  }
  #pragma unroll
  for(int m=1;m<16;m<<=1){
    gs[0][0]+=__shfl_xor(gs[0][0],m,16); gs[0][1]+=__shfl_xor(gs[0][1],m,16);
    gs[1][0]+=__shfl_xor(gs[1][0],m,16); gs[1][1]+=__shfl_xor(gs[1][1],m,16);
  }
  if((lane&15)==0){
    int g0 = kg*2;
    if(g0<5){ atomicAdd(&sred[g0][0],gs[0][0]); atomicAdd(&sred[g0][1],gs[0][1]); }
    if(g0+1<5){ atomicAdd(&sred[g0+1][0],gs[1][0]); atomicAdd(&sred[g0+1][1],gs[1][1]); }
  }
  __syncthreads();
  if(threadIdx.x<10) atomicAdd(&gn1sums[b*10+threadIdx.x], ((float*)sred)[threadIdx.x]);
}

// ---------------- K4: GN1 apply (inline stats) + tanh + cumsum + zigzag ----------------
__global__ __launch_bounds__(256) void gn1_apply_kernel(const float* __restrict__ off_raw,
                                                        const float* __restrict__ gn1sums,
                                                        const float* __restrict__ gno_g,
                                                        const float* __restrict__ gno_b,
                                                        float* __restrict__ yseqT,
                                                        float* __restrict__ ynew){
  int idx = blockIdx.x*blockDim.x + threadIdx.x;   // BB*HW
  int b = idx>>14; int pix = idx&16383; int h = pix>>7, w = pix&127;
  float t[9];
  #pragma unroll
  for(int c=0;c<9;c++){
    float v = off_raw[((size_t)(b*10+c))*HW + pix];
    int gi = b*10 + (c>>1)*2;
    float S = gn1sums[gi], S2 = gn1sums[gi+1];
    float mu = S*(1.f/32768.f);
    float inv = rsqrtf(S2*(1.f/32768.f) - mu*mu + 1e-5f);
    float xx = (v-mu)*inv*gno_g[c] + gno_b[c];
    xx = fminf(fmaxf(xx,-15.f),15.f);
    float e2 = __expf(2.f*xx);
    t[c] = (e2-1.f)/(e2+1.f);
  }
  int l = (((h>>1)*WW + w)<<1) | (h&1);
  #pragma unroll
  for(int c=0;c<9;c++) yseqT[((size_t)(b*9+c))*LSEQ + l] = t[c];
  float rows[9];
  rows[4]=0.f;
  rows[5]=t[5]; rows[6]=rows[5]+t[6]; rows[7]=rows[6]+t[7]; rows[8]=rows[7]+t[8];
  rows[3]=t[3]; rows[2]=rows[3]+t[2]; rows[1]=rows[2]+t[1]; rows[0]=rows[1]+t[0];
  #pragma unroll
  for(int k=0;k<9;k++) ynew[((size_t)(b*9+k))*HW + pix] = (float)h + rows[k];
}

// ---------------- K5: mamba featurize (parallel over l, l-major outputs) -----------
__global__ __launch_bounds__(256) void mamba_feat_kernel(
    const float* __restrict__ yseqT, const float* __restrict__ in_proj_w,
    const float* __restrict__ conv_w, const float* __restrict__ conv_b,
    const float* __restrict__ x_proj_w, const float* __restrict__ dt_w,
    const float* __restrict__ dt_b,
    float* __restrict__ DT_L, float* __restrict__ XI_L, float* __restrict__ ZZ_L,
    float* __restrict__ BS_L, float* __restrict__ CS_L){
  __shared__ float s_in[36*9], s_cw[18*4], s_cb[18], s_xw[33*18], s_dw[18], s_db[18];
  for(int i=threadIdx.x;i<324;i+=256) s_in[i]=in_proj_w[i];
  for(int i=threadIdx.x;i<72;i+=256)  s_cw[i]=conv_w[i];
  for(int i=threadIdx.x;i<594;i+=256) s_xw[i]=x_proj_w[i];
  if(threadIdx.x<18){ s_cb[threadIdx.x]=conv_b[threadIdx.x];
                      s_dw[threadIdx.x]=dt_w[threadIdx.x];
                      s_db[threadIdx.x]=dt_b[threadIdx.x]; }
  __syncthreads();
  int idx = blockIdx.x*blockDim.x + threadIdx.x;
  int b = idx>>14, l = idx&16383;
  float ys4[4][9];
  #pragma unroll
  for(int m=0;m<9;m++){
    const float* p = yseqT + (size_t)(b*9+m)*LSEQ;
    #pragma unroll
    for(int t=0;t<4;t++){
      int lp = l-3+t;
      ys4[t][m] = (lp>=0) ? p[lp] : 0.f;
    }
  }
  float xi[18];
  #pragma unroll
  for(int d=0;d<18;d++){
    float cacc = s_cb[d];
    #pragma unroll
    for(int t=0;t<4;t++){
      float xr = 0.f;
      #pragma unroll
      for(int m=0;m<9;m++) xr += ys4[t][m]*s_in[d*9+m];
      cacc += xr * s_cw[d*4+t];
    }
    xi[d] = cacc / (1.f + __expf(-cacc));     // silu
  }
  float dblv[33];
  #pragma unroll
  for(int j=0;j<33;j++){
    float a=0.f;
    #pragma unroll
    for(int d=0;d<18;d++) a += xi[d]*s_xw[j*18+d];
    dblv[j]=a;
  }
  size_t lb = (size_t)b*LSEQ + l;
  #pragma unroll
  for(int d=0;d<18;d++) XI_L[lb*18 + d] = xi[d];
  #pragma unroll
  for(int d=0;d<18;d++){
    float a=0.f;
    #pragma unroll
    for(int m=0;m<9;m++) a += ys4[3][m]*s_in[(18+d)*9+m];
    ZZ_L[lb*18 + d] = a;
    float pre = dblv[0]*s_dw[d] + s_db[d];
    DT_L[lb*18 + d] = fmaxf(pre,0.f) + __logf(1.f + __expf(-fabsf(pre)));
  }
  #pragma unroll
  for(int s=0;s<16;s++){
    BS_L[lb*16 + s] = dblv[1+s];
    CS_L[lb*16 + s] = dblv[17+s];
  }
}

// ---------------- K6: chunk scan, thread=(b,chunk,d), 16 s-states; t-major carry out --
__global__ __launch_bounds__(288) void scan_pass1(const float* __restrict__ DT_L,
                                                  const float* __restrict__ XI_L,
                                                  const float* __restrict__ BS_L,
                                                  const float* __restrict__ Amat,
                                                  float* __restrict__ CP, float* __restrict__ CH){
  __shared__ float tile[16][18][17];     // [s][d][ck]
  int blk = blockIdx.x;                  // B * NCH/16
  int b = blk>>6; int ckb = (blk&63)<<4;
  int tid = threadIdx.x;
  int d = tid%18, ck = tid/18;
  int c = ckb + ck;
  int l0 = c*CLEN;
  float A[16];
  #pragma unroll
  for(int i=0;i<4;i++){
    float4 t = *(const float4*)(Amat + d*16 + i*4);
    A[i*4]=t.x; A[i*4+1]=t.y; A[i*4+2]=t.z; A[i*4+3]=t.w;
  }
  float h[16], P[16];
  #pragma unroll
  for(int s=0;s<16;s++){ h[s]=0.f; P[s]=1.f; }
  const float* dtp = DT_L + ((size_t)b*LSEQ + l0)*18 + d;
  const float* xip = XI_L + ((size_t)b*LSEQ + l0)*18 + d;
  const float* bsp = BS_L + ((size_t)b*LSEQ + l0)*16;
  #pragma unroll 4
  for(int st=0; st<CLEN; ++st){
    float dt  = dtp[st*18];
    float dx  = dt*xip[st*18];
    float Bv[16];
    #pragma unroll
    for(int i=0;i<4;i++){
      float4 t = *(const float4*)(bsp + st*16 + i*4);
      Bv[i*4]=t.x; Bv[i*4+1]=t.y; Bv[i*4+2]=t.z; Bv[i*4+3]=t.w;
    }
    #pragma unroll
    for(int s=0;s<16;s++){
      float a = __expf(dt*A[s]);
      h[s] = a*h[s] + dx*Bv[s];
      P[s] *= a;
    }
  }
  // stage P -> (b,t,c) coalesced
  #pragma unroll
  for(int s=0;s<16;s++) tile[s][d][ck] = P[s];
  __syncthreads();
  {
    int t = tid; int d2 = t>>4, s2 = t&15;
    float* dst = CP + ((size_t)(b*288 + t))*NCH + ckb;
    const float* src = &tile[s2][d2][0];
    #pragma unroll
    for(int i=0;i<4;i++) ((float4*)dst)[i] = *(const float4*)(src + i*4);
  }
  __syncthreads();
  #pragma unroll
  for(int s=0;s<16;s++) tile[s][d][ck] = h[s];
  __syncthreads();
  {
    int t = tid; int d2 = t>>4, s2 = t&15;
    float* dst = CH + ((size_t)(b*288 + t))*NCH + ckb;
    const float* src = &tile[s2][d2][0];
    #pragma unroll
    for(int i=0;i<4;i++) ((float4*)dst)[i] = *(const float4*)(src + i*4);
  }
}

// ---------------- K7: parallel carry scan (wave per (b,t) chain), fully coalesced ----
__global__ __launch_bounds__(256) void scan_carry_kernel(const float* __restrict__ CP,
                                                         const float* __restrict__ CH,
                                                         float* __restrict__ HIN){
  int wid = blockIdx.x*4 + (threadIdx.x>>6);   // 0..1151
  int lane = threadIdx.x&63;
  int b = wid/288, t = wid%288;
  size_t base = ((size_t)(b*288 + t))*NCH;
  int c0 = lane*16;
  float P[16], Hh[16];
  #pragma unroll
  for(int i=0;i<4;i++){
    float4 tp = *(const float4*)(CP + base + c0 + i*4);
    float4 th = *(const float4*)(CH + base + c0 + i*4);
    P[i*4]=tp.x; P[i*4+1]=tp.y; P[i*4+2]=tp.z; P[i*4+3]=tp.w;
    Hh[i*4]=th.x; Hh[i*4+1]=th.y; Hh[i*4+2]=th.z; Hh[i*4+3]=th.w;
  }
  float aP = P[0], aH = Hh[0];
  #pragma unroll
  for(int i=1;i<16;i++){ aH = P[i]*aH + Hh[i]; aP = aP*P[i]; }
  float sP = aP, sH = aH;
  #pragma unroll
  for(int off=1; off<64; off<<=1){
    float pP = __shfl_up(sP, off, 64);
    float pH = __shfl_up(sH, off, 64);
    if(lane >= off){ sH = sP*pH + sH; sP = pP*sP; }
  }
  float eH = __shfl_up(sH, 1, 64);
  if(lane==0){ eH=0.f; }
  float cHh = eH;
  float outv[16];
  #pragma unroll
  for(int i=0;i<16;i++){
    outv[i] = cHh;
    cHh = P[i]*cHh + Hh[i];
  }
  #pragma unroll
  for(int i=0;i<4;i++){
    float4 tv; tv.x=outv[i*4]; tv.y=outv[i*4+1]; tv.z=outv[i*4+2]; tv.w=outv[i*4+3];
    *(float4*)(HIN + base + c0 + i*4) = tv;
  }
}

// ---------------- K8: chunk scan with true init (LDS-staged load) + y output -------
__global__ __launch_bounds__(288) void scan_pass2(const float* __restrict__ DT_L,
                                                  const float* __restrict__ XI_L,
                                                  const float* __restrict__ BS_L,
                                                  const float* __restrict__ CS_L,
                                                  const float* __restrict__ Amat,
                                                  const float* __restrict__ HIN,
                                                  float* __restrict__ YST_L){
  __shared__ float tile[16][18][17];     // [s][d][ck]
  int blk = blockIdx.x;
  int b = blk>>6; int ckb = (blk&63)<<4;
  int tid = threadIdx.x;
  int d = tid%18, ck = tid/18;
  int c = ckb + ck;
  int l0 = c*CLEN;
  {
    int t = tid; int d2 = t>>4, s2 = t&15;
    const float* src = HIN + ((size_t)(b*288 + t))*NCH + ckb;
    float* dst = &tile[s2][d2][0];
    #pragma unroll
    for(int i=0;i<4;i++) *(float4*)(dst + i*4) = ((const float4*)src)[i];
  }
  __syncthreads();
  float A[16];
  #pragma unroll
  for(int i=0;i<4;i++){
    float4 t = *(const float4*)(Amat + d*16 + i*4);
    A[i*4]=t.x; A[i*4+1]=t.y; A[i*4+2]=t.z; A[i*4+3]=t.w;
  }
  float h[16];
  #pragma unroll
  for(int s=0;s<16;s++) h[s] = tile[s][d][ck];
  const float* dtp = DT_L + ((size_t)b*LSEQ + l0)*18 + d;
  const float* xip = XI_L + ((size_t)b*LSEQ + l0)*18 + d;
  const float* bsp = BS_L + ((size_t)b*LSEQ + l0)*16;
  const float* csp = CS_L + ((size_t)b*LSEQ + l0)*16;
  float* ysp = YST_L + ((size_t)b*LSEQ + l0)*18 + d;
  #pragma unroll 4
  for(int st=0; st<CLEN; ++st){
    float dt  = dtp[st*18];
    float dx  = dt*xip[st*18];
    float Bv[16], Cv[16];
    #pragma unroll
    for(int i=0;i<4;i++){
      float4 t = *(const float4*)(bsp + st*16 + i*4);
      Bv[i*4]=t.x; Bv[i*4+1]=t.y; Bv[i*4+2]=t.z; Bv[i*4+3]=t.w;
      float4 u = *(const float4*)(csp + st*16 + i*4);
      Cv[i*4]=u.x; Cv[i*4+1]=u.y; Cv[i*4+2]=u.z; Cv[i*4+3]=u.w;
    }
    float pc = 0.f;
    #pragma unroll
    for(int s=0;s<16;s++){
      float a = __expf(dt*A[s]);
      h[s] = a*h[s] + dx*Bv[s];
      pc += h[s]*Cv[s];
    }
    ysp[st*18] = pc;
  }
}

// ---------------- K9: mamba epilogue + y_final ----------------
__global__ __launch_bounds__(256) void mamba_out_kernel(
    const float* __restrict__ YST_L, const float* __restrict__ XI_L,
    const float* __restrict__ ZZ_L, const float* __restrict__ Dp,
    const float* __restrict__ out_w, const float* __restrict__ altho,
    const float* __restrict__ ynew, float* __restrict__ yfin){
  __shared__ float s_ow[9*18], s_dp[18];
  for(int i=threadIdx.x;i<162;i+=256) s_ow[i]=out_w[i];
  if(threadIdx.x<18) s_dp[threadIdx.x]=Dp[threadIdx.x];
  __syncthreads();
  int idx = blockIdx.x*blockDim.x + threadIdx.x;
  int b = idx>>14, l = idx&16383;
  size_t lb = (size_t)b*LSEQ + l;
  float y[18];
  #pragma unroll
  for(int d=0;d<18;d++){
    float z = ZZ_L[lb*18+d];
    float sz = z/(1.f+__expf(-z));
    y[d] = (YST_L[lb*18+d] + s_dp[d]*XI_L[lb*18+d]) * sz;
  }
  float av = altho[0];
  float sp = fmaxf(av,0.f)+__logf(1.f+__expf(-fabsf(av)));
  float wgt = fmaxf(sp, 0.01f);
  int h = ((l>>8)<<1) | (l&1);
  int w = (l>>1)&127;
  int pix = h*WW + w;
  #pragma unroll
  for(int m=0;m<9;m++){
    float a=0.f;
    #pragma unroll
    for(int d=0;d<18;d++) a += y[d]*s_ow[m*18+d];
    size_t o = ((size_t)(b*9+m))*HW + pix;
    yfin[o] = wgt*a + ynew[o];
  }
}

// ---------------- K10: fused sample + 9x1 conv, F=fp16-high, W split, + GN2 stats ---
__global__ __launch_bounds__(256) void sample_conv_kernel(
    const _Float16* __restrict__ xTh, const float* __restrict__ yfin,
    const _Float16* __restrict__ AH, const _Float16* __restrict__ AL,
    const float* __restrict__ bias, float* __restrict__ outpre,
    float* __restrict__ gn2sums){
  __shared__ _Float16 F[2][64][72];      // [buf][px][ci pad 72]
  __shared__ float sred2[16][2];
  int blk0 = blockIdx.x;                 // 1024 = 8 XCDs * 128
  int blk = (blk0&7)*128 + (blk0>>3);
  int wo0 = (blk&1)*64;
  int ho  = (blk>>1)&127;
  int b   = blk>>8;
  int lane = threadIdx.x&63;
  int wv   = threadIdx.x>>6;             // 0..3
  int l32  = lane&31, g = lane>>5;
  int co0 = (wv&1)*32, pxh = (wv>>1)*32;
  int px = lane;
  int wo = wo0 + px;
  if(threadIdx.x<32) ((float*)sred2)[threadIdx.x]=0.f;

  const _Float16* ahbase = AH + ((size_t)(co0 + l32)*2 + g)*8;
  const _Float16* albase = AL + ((size_t)(co0 + l32)*2 + g)*8;

  floatx16 acc;
  #pragma unroll
  for(int r=0;r<16;r++) acc[r]=0.f;

  half8 h0[2], h1[2]; _Float16 wyh = (_Float16)0.f;
  auto gather = [&](int k){
    float yv = yfin[((size_t)(b*9+k))*HW + ho*WW + wo];
    float py = fminf(fmaxf(yv,0.f),127.f);
    float y0f = floorf(py);
    wyh = (_Float16)(py - y0f);
    int iy0 = (int)y0f;
    int iy1 = min(iy0+1,127);
    int xc  = min(max(wo + k - 4, 0), 127);
    size_t o0 = (((size_t)(b*HH+iy0))*WW + xc)*64 + wv*16;
    size_t o1 = (((size_t)(b*HH+iy1))*WW + xc)*64 + wv*16;
    h0[0] = *(const half8*)(xTh + o0);
    h0[1] = *(const half8*)(xTh + o0 + 8);
    h1[0] = *(const half8*)(xTh + o1);
    h1[1] = *(const half8*)(xTh + o1 + 8);
  };
  auto writeF = [&](int buf){
    half8 w8 = {wyh,wyh,wyh,wyh,wyh,wyh,wyh,wyh};
    #pragma unroll
    for(int q=0;q<2;q++){
      half8 r = h0[q] + (h1[q]-h0[q])*w8;   // packed fp16 lerp
      *(half8*)&F[buf][px][wv*16 + q*8] = r;
    }
  };

  gather(0); writeF(0);
  __syncthreads();
  #pragma unroll
  for(int k=0;k<9;k++){
    if(k<8) gather(k+1);
    int buf = k&1;
    #pragma unroll
    for(int q=0;q<4;q++){
      half8 bh = *(const half8*)&F[buf][pxh + l32][q*16 + g*8];
      half8 ah = *(const half8*)(ahbase + (size_t)(k*4+q)*1024);
      half8 al = *(const half8*)(albase + (size_t)(k*4+q)*1024);
      acc = __builtin_amdgcn_mfma_f32_32x32x16_f16(ah, bh, acc, 0,0,0);
      acc = __builtin_amdgcn_mfma_f32_32x32x16_f16(al, bh, acc, 0,0,0);
    }
    if(k<8) writeF((k+1)&1);
    __syncthreads();
  }
  // epilogue: write + per-quad stats.  group = co0/4 + 2*(r>>2) + g
  float qs[4][2] = {{0,0},{0,0},{0,0},{0,0}};
  #pragma unroll
  for(int r=0;r<16;r++){
    int row = (r&3) + 8*(r>>2) + 4*g;
    int co = co0 + row;
    float v = acc[r] + bias[co];
    outpre[((size_t)(b*64+co))*HW + ho*WW + wo0 + pxh + l32] = v;
    qs[r>>2][0] += v; qs[r>>2][1] += v*v;
  }
  #pragma unroll
  for(int qi=0;qi<4;qi++){
    int gq = (co0>>2) + 2*qi + g;
    atomicAdd(&sred2[gq][0], qs[qi][0]);
    atomicAdd(&sred2[gq][1], qs[qi][1]);
  }
  __syncthreads();
  if(threadIdx.x<32) atomicAdd(&gn2sums[b*32+threadIdx.x], ((float*)sred2)[threadIdx.x]);
}

// ---------------- K12: final GN apply (inline stats) ----------------
__global__ __launch_bounds__(256) void gn2_apply_kernel(const float* __restrict__ src,
                                                        const float* __restrict__ gn2sums,
                                                        const float* __restrict__ gam,
                                                        const float* __restrict__ bet,
                                                        float* __restrict__ dst){
  int idx = blockIdx.x*blockDim.x + threadIdx.x;  // BB*64*HW
  int c = (idx>>14)&63;
  int b = idx>>20;
  int gi = b*32 + (c>>2)*2;
  float S = gn2sums[gi], S2 = gn2sums[gi+1];
  float mu = S*(1.f/65536.f);
  float inv = rsqrtf(S2*(1.f/65536.f) - mu*mu + 1e-5f);
  dst[idx] = (src[idx]-mu)*inv*gam[c] + bet[c];
}

extern "C" void kernel_launch(void* const* d_in, const int* in_sizes, int n_in,
                              void* d_out, int out_size, void* d_ws, size_t ws_size,
                              hipStream_t stream){
  const float* x        = (const float*)d_in[0];
  const float* offset_w = (const float*)d_in[1];
  const float* offset_b = (const float*)d_in[2];
  const float* gno_g    = (const float*)d_in[3];
  const float* gno_b    = (const float*)d_in[4];
  const float* altho    = (const float*)d_in[5];
  const float* in_proj  = (const float*)d_in[6];
  const float* conv1d_w = (const float*)d_in[7];
  const float* conv1d_b = (const float*)d_in[8];
  const float* x_proj   = (const float*)d_in[9];
  const float* dt_w     = (const float*)d_in[10];
  const float* dt_b     = (const float*)d_in[11];
  const float* A_log    = (const float*)d_in[12];
  const float* D_p      = (const float*)d_in[13];
  const float* out_proj = (const float*)d_in[14];
  const float* dsc_w    = (const float*)d_in[15];
  const float* dsc_b    = (const float*)d_in[16];
  const float* gn_g     = (const float*)d_in[17];
  const float* gn_b     = (const float*)d_in[18];
  float* out = (float*)d_out;
  float* ws  = (float*)d_ws;
  if(ws_size < WS_TOTAL*sizeof(float)) return;

  float* off_raw = ws + OFF_RAW_O;
  float* yseqT   = ws + YSEQT_O;
  float* ynew    = ws + YNEW_O;
  float* gn1s    = ws + GN1_O;
  float* DT_L    = ws + DT_O;
  float* XI_L    = ws + XI_O;
  float* ZZ_L    = ws + ZZ_O;
  float* BS_L    = ws + BS_O;
  float* CS_L    = ws + CS_O;
  float* CP      = ws + CP_O;
  float* CH      = ws + CHC_O;
  float* HIN     = ws + HIN_O;
  float* YST_L   = ws + YS_O;
  float* yfin    = ws + YFIN_O;
  _Float16* xTh  = (_Float16*)(ws + XTH_O);
  _Float16* xTl  = (_Float16*)(ws + XTL_O);
  float* outpre  = ws + OUTPRE_O;
  _Float16* AH   = (_Float16*)(ws + WT_O);
  _Float16* AL   = (_Float16*)(ws + WT_O) + 36864;
  _Float16* AOH  = (_Float16*)(ws + AO_O);
  _Float16* AOL  = (_Float16*)(ws + AO_O) + 9216;
  float* Amat    = ws + AMAT_O;
  float* gn2s    = ws + GN2_O;

  prep_kernel<<<dim3(182), dim3(256), 0, stream>>>(dsc_w, offset_w, A_log, AH, AL, AOH, AOL,
                                                   Amat, gn1s, gn2s);
  transpose_x_kernel<<<dim3(1024), dim3(256), 0, stream>>>(x, xTh, xTl);
  off_conv_kernel<<<dim3(512), dim3(256), 0, stream>>>(xTh, AOH, AOL, offset_b, off_raw, gn1s);
  gn1_apply_kernel<<<dim3(256), dim3(256), 0, stream>>>(off_raw, gn1s, gno_g, gno_b, yseqT, ynew);
  mamba_feat_kernel<<<dim3(256), dim3(256), 0, stream>>>(yseqT, in_proj, conv1d_w, conv1d_b,
                                                         x_proj, dt_w, dt_b,
                                                         DT_L, XI_L, ZZ_L, BS_L, CS_L);
  scan_pass1<<<dim3(BB*NCH/16), dim3(288), 0, stream>>>(DT_L, XI_L, BS_L, Amat, CP, CH);
  scan_carry_kernel<<<dim3(288), dim3(256), 0, stream>>>(CP, CH, HIN);
  scan_pass2<<<dim3(BB*NCH/16), dim3(288), 0, stream>>>(DT_L, XI_L, BS_L, CS_L, Amat, HIN, YST_L);
  mamba_out_kernel<<<dim3(256), dim3(256), 0, stream>>>(YST_L, XI_L, ZZ_L, D_p, out_proj, altho,
                                                        ynew, yfin);
  sample_conv_kernel<<<dim3(1024), dim3(256), 0, stream>>>(xTh, yfin, AH, AL, dsc_b, outpre, gn2s);
  gn2_apply_kernel<<<dim3(16384), dim3(256), 0, stream>>>(outpre, gn2s, gn_g, gn_b, out);
}

// Round 8
// 239.308 us; speedup vs baseline: 1.9427x; 1.0071x over previous
//
#include <hip/hip_runtime.h>
#include <math.h>

#define BB 4
#define HH 128
#define WW 128
#define HW (HH*WW)       // 16384
#define LSEQ HW          // 16384
#define NCH 1024         // chunks per batch
#define CLEN 16          // chunk length

typedef _Float16 half8 __attribute__((ext_vector_type(8)));
typedef float floatx4 __attribute__((ext_vector_type(4)));
typedef float floatx16 __attribute__((ext_vector_type(16)));

// ---------------- workspace layout (in floats) ----------------
constexpr size_t OFF_RAW_O = 0;                      // (B,10,H,W)
constexpr size_t OFF_RAW_N = (size_t)BB*10*HW;
constexpr size_t YSEQT_O = OFF_RAW_O + OFF_RAW_N;    // (B,9,L)
constexpr size_t YSEQT_N = (size_t)BB*9*LSEQ;
constexpr size_t YNEW_O = YSEQT_O + YSEQT_N;         // (B,9,H,W)
constexpr size_t YNEW_N = (size_t)BB*9*HW;
constexpr size_t GN1_O = YNEW_O + YNEW_N;            // raw sums (B,5,2) = 40
constexpr size_t GN1_N = 64;
constexpr size_t CH18 = (size_t)BB*18*LSEQ;
constexpr size_t CH16 = (size_t)BB*16*LSEQ;
constexpr size_t DT_O = GN1_O + GN1_N;               // (B,L,18)
constexpr size_t XI_O = DT_O + CH18;                 // (B,L,18)
constexpr size_t ZZ_O = XI_O + CH18;                 // (B,L,18)
constexpr size_t BS_O = ZZ_O + CH18;                 // (B,L,16)
constexpr size_t CS_O = BS_O + CH16;                 // (B,L,16)
constexpr size_t CARR = (size_t)BB*NCH*288;
constexpr size_t CP_O = CS_O + CH16;                 // (B,288,NCH)  t-major
constexpr size_t CHC_O = CP_O + CARR;
constexpr size_t HIN_O = CHC_O + CARR;
constexpr size_t YS_O = HIN_O + CARR;                // (B,L,18)
constexpr size_t YFIN_O = YS_O + CH18;               // (B,9,H,W)
constexpr size_t XTH_O = YFIN_O + YNEW_N;            // (B,H,W,64) halfs
constexpr size_t XTH_N = (size_t)BB*HW*32;
constexpr size_t XTL_O = XTH_O + XTH_N;
constexpr size_t OUTPRE_O = XTL_O + XTH_N;           // (B,64,H,W)
constexpr size_t OUTPRE_N = (size_t)BB*64*HW;
constexpr size_t WT_O = OUTPRE_O + OUTPRE_N;         // AH(36864 h) + AL(36864 h)
constexpr size_t AO_O = WT_O + 36864;                // AOH(9216 h) + AOL(9216 h)
constexpr size_t AMAT_O = AO_O + 9216;               // (18,16)
constexpr size_t GN2_O = AMAT_O + 288;               // raw sums (B,16,2) = 128
constexpr size_t WS_TOTAL = GN2_O + 128;

// ---------------- K0: MFMA weight frags + A matrix + zero stat sums ----------------
__global__ void prep_kernel(const float* __restrict__ dsc_w, const float* __restrict__ offw,
                            const float* __restrict__ A_log,
                            _Float16* __restrict__ AH, _Float16* __restrict__ AL,
                            _Float16* __restrict__ AOH, _Float16* __restrict__ AOL,
                            float* __restrict__ Amat,
                            float* __restrict__ gn1s, float* __restrict__ gn2s){
  int i = blockIdx.x*blockDim.x + threadIdx.x;
  if(blockIdx.x==0){
    if(threadIdx.x<40) gn1s[threadIdx.x]=0.f;
    if(threadIdx.x>=64 && threadIdx.x<192) gn2s[threadIdx.x-64]=0.f;
  }
  if(i < 36864){
    int jj = i&7, gg = (i>>3)&1, co = (i>>4)&63, ks = i>>10;
    int k = ks>>2, q = ks&3;
    int ci = q*16 + gg*8 + jj;
    float w = dsc_w[((size_t)(co*64 + ci))*9 + k];   // dsc_w (co,ci,9,1)
    _Float16 h = (_Float16)w;
    AH[i] = h;
    AL[i] = (_Float16)(w - (float)h);
  }
  int j = i - 36864;
  if(j >= 0 && j < 9216){
    int jj = j&7, lane = (j>>3)&63, ksl = j>>9;      // ksl 0..17
    int tap = ksl>>1, ks = ksl&1;
    int co = lane&15, kg = lane>>4;
    int ci = ks*32 + kg*8 + jj;
    int dy = tap/3, dx = tap%3;
    float w = (co<10) ? offw[((size_t)(co*64 + ci)*3 + dy)*3 + dx] : 0.f;
    _Float16 h = (_Float16)w;
    AOH[j] = h;
    AOL[j] = (_Float16)(w - (float)h);
  }
  int a = i - 46080;
  if(a >= 0 && a < 288) Amat[a] = -__expf(A_log[a]);
}

// ---------------- K1: x (B,C,H,W) -> xTh/xTl (B,H,W,C) fp16 split ----------------
__global__ __launch_bounds__(256) void transpose_x_kernel(const float* __restrict__ x,
                                                          _Float16* __restrict__ xTh,
                                                          _Float16* __restrict__ xTl){
  __shared__ float tile[64][65];
  int blk = blockIdx.x;            // B*H*2
  int w0 = (blk&1)*64;
  int h  = (blk>>1)&127;
  int b  = blk>>8;
  int lane = threadIdx.x&63, q = threadIdx.x>>6;
  #pragma unroll
  for(int r=0;r<16;r++){
    int ci = r*4 + q;
    tile[ci][lane] = x[((size_t)(b*64+ci)*HH + h)*WW + w0 + lane];
  }
  __syncthreads();
  #pragma unroll
  for(int r=0;r<16;r++){
    int w = r*4 + q;
    float v = tile[lane][w];
    size_t o = (((size_t)(b*HH+h))*WW + w0 + w)*64 + lane;
    _Float16 hv = (_Float16)v;
    xTh[o] = hv;
    xTl[o] = (_Float16)(v - (float)hv);
  }
}

// ---------------- K2: 3x3 offset conv (out-ch 0..9), 2-term MFMA + fused GN1 stats --
__global__ __launch_bounds__(256) void off_conv_kernel(
    const _Float16* __restrict__ xTh,
    const _Float16* __restrict__ AOH, const _Float16* __restrict__ AOL,
    const float* __restrict__ offb, float* __restrict__ off_raw,
    float* __restrict__ gn1sums){
  __shared__ float sred[6][2];
  int blk0 = blockIdx.x;               // 512 = 8 XCDs * 64
  int blk = (blk0&7)*64 + (blk0>>3);   // XCD-contiguous h ranges
  int h = blk&127, b = blk>>7;
  int lane = threadIdx.x&63, wv = threadIdx.x>>6;
  int col = lane&15, kg = lane>>4;
  if(threadIdx.x<10) ((float*)sred)[threadIdx.x]=0.f;
  __syncthreads();
  floatx4 acc[2];
  acc[0] = (floatx4)0.f; acc[1] = (floatx4)0.f;
  for(int dy=0; dy<3; dy++){
    int hr = h + dy - 1;
    if(hr < 0 || hr >= HH) continue;
    for(int dx=0; dx<3; dx++){
      int tap = dy*3 + dx;
      #pragma unroll
      for(int ks=0; ks<2; ks++){
        half8 ah = *(const half8*)(AOH + (size_t)((tap*2+ks)*64 + lane)*8);
        half8 al = *(const half8*)(AOL + (size_t)((tap*2+ks)*64 + lane)*8);
        #pragma unroll
        for(int tt=0; tt<2; tt++){
          int px = wv*32 + tt*16 + col;
          int wc = px + dx - 1;
          half8 bh = {};
          if(wc >= 0 && wc < WW)
            bh = *(const half8*)(xTh + (((size_t)(b*HH+hr))*WW + wc)*64 + ks*32 + kg*8);
          acc[tt] = __builtin_amdgcn_mfma_f32_16x16x32_f16(ah, bh, acc[tt], 0,0,0);
          acc[tt] = __builtin_amdgcn_mfma_f32_16x16x32_f16(al, bh, acc[tt], 0,0,0);
        }
      }
    }
  }
  float gs[2][2] = {{0.f,0.f},{0.f,0.f}};
  #pragma unroll
  for(int tt=0; tt<2; tt++){
    #pragma unroll
    for(int r=0; r<4; r++){
      int co = kg*4 + r;
      if(co < 10){
        int px = wv*32 + tt*16 + col;
        float v = acc[tt][r] + offb[co];
        off_raw[((size_t)(b*10+co)*HH + h)*WW + px] = v;
        gs[r>>1][0] += v; gs[r>>1][1] += v*v;
      }
    }
  }
  #pragma unroll
  for(int m=1;m<16;m<<=1){
    gs[0][0]+=__shfl_xor(gs[0][0],m,16); gs[0][1]+=__shfl_xor(gs[0][1],m,16);
    gs[1][0]+=__shfl_xor(gs[1][0],m,16); gs[1][1]+=__shfl_xor(gs[1][1],m,16);
  }
  if((lane&15)==0){
    int g0 = kg*2;
    if(g0<5){ atomicAdd(&sred[g0][0],gs[0][0]); atomicAdd(&sred[g0][1],gs[0][1]); }
    if(g0+1<5){ atomicAdd(&sred[g0+1][0],gs[1][0]); atomicAdd(&sred[g0+1][1],gs[1][1]); }
  }
  __syncthreads();
  if(threadIdx.x<10) atomicAdd(&gn1sums[b*10+threadIdx.x], ((float*)sred)[threadIdx.x]);
}

// ---------------- K4: GN1 apply (inline stats) + tanh + cumsum + zigzag ----------------
__global__ __launch_bounds__(256) void gn1_apply_kernel(const float* __restrict__ off_raw,
                                                        const float* __restrict__ gn1sums,
                                                        const float* __restrict__ gno_g,
                                                        const float* __restrict__ gno_b,
                                                        float* __restrict__ yseqT,
                                                        float* __restrict__ ynew){
  int idx = blockIdx.x*blockDim.x + threadIdx.x;   // BB*HW
  int b = idx>>14; int pix = idx&16383; int h = pix>>7, w = pix&127;
  float t[9];
  #pragma unroll
  for(int c=0;c<9;c++){
    float v = off_raw[((size_t)(b*10+c))*HW + pix];
    int gi = b*10 + (c>>1)*2;
    float S = gn1sums[gi], S2 = gn1sums[gi+1];
    float mu = S*(1.f/32768.f);
    float inv = rsqrtf(S2*(1.f/32768.f) - mu*mu + 1e-5f);
    float xx = (v-mu)*inv*gno_g[c] + gno_b[c];
    xx = fminf(fmaxf(xx,-15.f),15.f);
    float e2 = __expf(2.f*xx);
    t[c] = (e2-1.f)/(e2+1.f);
  }
  int l = (((h>>1)*WW + w)<<1) | (h&1);
  #pragma unroll
  for(int c=0;c<9;c++) yseqT[((size_t)(b*9+c))*LSEQ + l] = t[c];
  float rows[9];
  rows[4]=0.f;
  rows[5]=t[5]; rows[6]=rows[5]+t[6]; rows[7]=rows[6]+t[7]; rows[8]=rows[7]+t[8];
  rows[3]=t[3]; rows[2]=rows[3]+t[2]; rows[1]=rows[2]+t[1]; rows[0]=rows[1]+t[0];
  #pragma unroll
  for(int k=0;k<9;k++) ynew[((size_t)(b*9+k))*HW + pix] = (float)h + rows[k];
}

// ---------------- K5: mamba featurize (parallel over l, l-major vector stores) ------
__global__ __launch_bounds__(256) void mamba_feat_kernel(
    const float* __restrict__ yseqT, const float* __restrict__ in_proj_w,
    const float* __restrict__ conv_w, const float* __restrict__ conv_b,
    const float* __restrict__ x_proj_w, const float* __restrict__ dt_w,
    const float* __restrict__ dt_b,
    float* __restrict__ DT_L, float* __restrict__ XI_L, float* __restrict__ ZZ_L,
    float* __restrict__ BS_L, float* __restrict__ CS_L){
  __shared__ float s_in[36*9], s_cw[18*4], s_cb[18], s_xw[33*18], s_dw[18], s_db[18];
  for(int i=threadIdx.x;i<324;i+=256) s_in[i]=in_proj_w[i];
  for(int i=threadIdx.x;i<72;i+=256)  s_cw[i]=conv_w[i];
  for(int i=threadIdx.x;i<594;i+=256) s_xw[i]=x_proj_w[i];
  if(threadIdx.x<18){ s_cb[threadIdx.x]=conv_b[threadIdx.x];
                      s_dw[threadIdx.x]=dt_w[threadIdx.x];
                      s_db[threadIdx.x]=dt_b[threadIdx.x]; }
  __syncthreads();
  int idx = blockIdx.x*blockDim.x + threadIdx.x;
  int b = idx>>14, l = idx&16383;
  float ys4[4][9];
  #pragma unroll
  for(int m=0;m<9;m++){
    const float* p = yseqT + (size_t)(b*9+m)*LSEQ;
    #pragma unroll
    for(int t=0;t<4;t++){
      int lp = l-3+t;
      ys4[t][m] = (lp>=0) ? p[lp] : 0.f;
    }
  }
  float xi[18];
  #pragma unroll
  for(int d=0;d<18;d++){
    float cacc = s_cb[d];
    #pragma unroll
    for(int t=0;t<4;t++){
      float xr = 0.f;
      #pragma unroll
      for(int m=0;m<9;m++) xr += ys4[t][m]*s_in[d*9+m];
      cacc += xr * s_cw[d*4+t];
    }
    xi[d] = cacc / (1.f + __expf(-cacc));     // silu
  }
  float dblv[33];
  #pragma unroll
  for(int j=0;j<33;j++){
    float a=0.f;
    #pragma unroll
    for(int d=0;d<18;d++) a += xi[d]*s_xw[j*18+d];
    dblv[j]=a;
  }
  size_t lb = (size_t)b*LSEQ + l;
  {
    float2* xp = (float2*)(XI_L + lb*18);
    #pragma unroll
    for(int i=0;i<9;i++){ float2 v; v.x=xi[i*2]; v.y=xi[i*2+1]; xp[i]=v; }
  }
  float zz[18], dtv[18];
  #pragma unroll
  for(int d=0;d<18;d++){
    float a=0.f;
    #pragma unroll
    for(int m=0;m<9;m++) a += ys4[3][m]*s_in[(18+d)*9+m];
    zz[d] = a;
    float pre = dblv[0]*s_dw[d] + s_db[d];
    dtv[d] = fmaxf(pre,0.f) + __logf(1.f + __expf(-fabsf(pre)));
  }
  {
    float2* zp = (float2*)(ZZ_L + lb*18);
    float2* dp = (float2*)(DT_L + lb*18);
    #pragma unroll
    for(int i=0;i<9;i++){
      float2 v; v.x=zz[i*2]; v.y=zz[i*2+1]; zp[i]=v;
      float2 u; u.x=dtv[i*2]; u.y=dtv[i*2+1]; dp[i]=u;
    }
  }
  {
    float4* bp = (float4*)(BS_L + lb*16);
    float4* cp = (float4*)(CS_L + lb*16);
    #pragma unroll
    for(int i=0;i<4;i++){
      float4 v; v.x=dblv[1+i*4]; v.y=dblv[2+i*4]; v.z=dblv[3+i*4]; v.w=dblv[4+i*4];
      bp[i]=v;
      float4 u; u.x=dblv[17+i*4]; u.y=dblv[18+i*4]; u.z=dblv[19+i*4]; u.w=dblv[20+i*4];
      cp[i]=u;
    }
  }
}

// ---------------- K6: chunk scan, thread=(b,chunk,d), 16 s-states; t-major carry out --
__global__ __launch_bounds__(288) void scan_pass1(const float* __restrict__ DT_L,
                                                  const float* __restrict__ XI_L,
                                                  const float* __restrict__ BS_L,
                                                  const float* __restrict__ Amat,
                                                  float* __restrict__ CP, float* __restrict__ CH){
  __shared__ float tile[16][18][17];     // [s][d][ck]
  int blk = blockIdx.x;                  // B * NCH/16
  int b = blk>>6; int ckb = (blk&63)<<4;
  int tid = threadIdx.x;
  int d = tid%18, ck = tid/18;
  int c = ckb + ck;
  int l0 = c*CLEN;
  float A[16];
  #pragma unroll
  for(int i=0;i<4;i++){
    float4 t = *(const float4*)(Amat + d*16 + i*4);
    A[i*4]=t.x; A[i*4+1]=t.y; A[i*4+2]=t.z; A[i*4+3]=t.w;
  }
  float h[16], P[16];
  #pragma unroll
  for(int s=0;s<16;s++){ h[s]=0.f; P[s]=1.f; }
  const float* dtp = DT_L + ((size_t)b*LSEQ + l0)*18 + d;
  const float* xip = XI_L + ((size_t)b*LSEQ + l0)*18 + d;
  const float* bsp = BS_L + ((size_t)b*LSEQ + l0)*16;
  #pragma unroll 4
  for(int st=0; st<CLEN; ++st){
    float dt  = dtp[st*18];
    float dx  = dt*xip[st*18];
    float Bv[16];
    #pragma unroll
    for(int i=0;i<4;i++){
      float4 t = *(const float4*)(bsp + st*16 + i*4);
      Bv[i*4]=t.x; Bv[i*4+1]=t.y; Bv[i*4+2]=t.z; Bv[i*4+3]=t.w;
    }
    #pragma unroll
    for(int s=0;s<16;s++){
      float a = __expf(dt*A[s]);
      h[s] = a*h[s] + dx*Bv[s];
      P[s] *= a;
    }
  }
  #pragma unroll
  for(int s=0;s<16;s++) tile[s][d][ck] = P[s];
  __syncthreads();
  {
    int t = tid; int d2 = t>>4, s2 = t&15;
    float* dst = CP + ((size_t)(b*288 + t))*NCH + ckb;
    const float* src = &tile[s2][d2][0];
    #pragma unroll
    for(int i=0;i<4;i++) ((float4*)dst)[i] = *(const float4*)(src + i*4);
  }
  __syncthreads();
  #pragma unroll
  for(int s=0;s<16;s++) tile[s][d][ck] = h[s];
  __syncthreads();
  {
    int t = tid; int d2 = t>>4, s2 = t&15;
    float* dst = CH + ((size_t)(b*288 + t))*NCH + ckb;
    const float* src = &tile[s2][d2][0];
    #pragma unroll
    for(int i=0;i<4;i++) ((float4*)dst)[i] = *(const float4*)(src + i*4);
  }
}

// ---------------- K7: parallel carry scan (wave per (b,t) chain), fully coalesced ----
__global__ __launch_bounds__(256) void scan_carry_kernel(const float* __restrict__ CP,
                                                         const float* __restrict__ CH,
                                                         float* __restrict__ HIN){
  int wid = blockIdx.x*4 + (threadIdx.x>>6);   // 0..1151
  int lane = threadIdx.x&63;
  int b = wid/288, t = wid%288;
  size_t base = ((size_t)(b*288 + t))*NCH;
  int c0 = lane*16;
  float P[16], Hh[16];
  #pragma unroll
  for(int i=0;i<4;i++){
    float4 tp = *(const float4*)(CP + base + c0 + i*4);
    float4 th = *(const float4*)(CH + base + c0 + i*4);
    P[i*4]=tp.x; P[i*4+1]=tp.y; P[i*4+2]=tp.z; P[i*4+3]=tp.w;
    Hh[i*4]=th.x; Hh[i*4+1]=th.y; Hh[i*4+2]=th.z; Hh[i*4+3]=th.w;
  }
  float aP = P[0], aH = Hh[0];
  #pragma unroll
  for(int i=1;i<16;i++){ aH = P[i]*aH + Hh[i]; aP = aP*P[i]; }
  float sP = aP, sH = aH;
  #pragma unroll
  for(int off=1; off<64; off<<=1){
    float pP = __shfl_up(sP, off, 64);
    float pH = __shfl_up(sH, off, 64);
    if(lane >= off){ sH = sP*pH + sH; sP = pP*sP; }
  }
  float eH = __shfl_up(sH, 1, 64);
  if(lane==0){ eH=0.f; }
  float cHh = eH;
  float outv[16];
  #pragma unroll
  for(int i=0;i<16;i++){
    outv[i] = cHh;
    cHh = P[i]*cHh + Hh[i];
  }
  #pragma unroll
  for(int i=0;i<4;i++){
    float4 tv; tv.x=outv[i*4]; tv.y=outv[i*4+1]; tv.z=outv[i*4+2]; tv.w=outv[i*4+3];
    *(float4*)(HIN + base + c0 + i*4) = tv;
  }
}

// ---------------- K8: chunk scan with true init (LDS-staged load) + y output -------
__global__ __launch_bounds__(288) void scan_pass2(const float* __restrict__ DT_L,
                                                  const float* __restrict__ XI_L,
                                                  const float* __restrict__ BS_L,
                                                  const float* __restrict__ CS_L,
                                                  const float* __restrict__ Amat,
                                                  const float* __restrict__ HIN,
                                                  float* __restrict__ YST_L){
  __shared__ float tile[16][18][17];     // [s][d][ck]
  int blk = blockIdx.x;
  int b = blk>>6; int ckb = (blk&63)<<4;
  int tid = threadIdx.x;
  int d = tid%18, ck = tid/18;
  int c = ckb + ck;
  int l0 = c*CLEN;
  {
    int t = tid; int d2 = t>>4, s2 = t&15;
    const float* src = HIN + ((size_t)(b*288 + t))*NCH + ckb;
    float* dst = &tile[s2][d2][0];
    #pragma unroll
    for(int i=0;i<4;i++) *(float4*)(dst + i*4) = ((const float4*)src)[i];
  }
  __syncthreads();
  float A[16];
  #pragma unroll
  for(int i=0;i<4;i++){
    float4 t = *(const float4*)(Amat + d*16 + i*4);
    A[i*4]=t.x; A[i*4+1]=t.y; A[i*4+2]=t.z; A[i*4+3]=t.w;
  }
  float h[16];
  #pragma unroll
  for(int s=0;s<16;s++) h[s] = tile[s][d][ck];
  const float* dtp = DT_L + ((size_t)b*LSEQ + l0)*18 + d;
  const float* xip = XI_L + ((size_t)b*LSEQ + l0)*18 + d;
  const float* bsp = BS_L + ((size_t)b*LSEQ + l0)*16;
  const float* csp = CS_L + ((size_t)b*LSEQ + l0)*16;
  float* ysp = YST_L + ((size_t)b*LSEQ + l0)*18 + d;
  #pragma unroll 4
  for(int st=0; st<CLEN; ++st){
    float dt  = dtp[st*18];
    float dx  = dt*xip[st*18];
    float Bv[16], Cv[16];
    #pragma unroll
    for(int i=0;i<4;i++){
      float4 t = *(const float4*)(bsp + st*16 + i*4);
      Bv[i*4]=t.x; Bv[i*4+1]=t.y; Bv[i*4+2]=t.z; Bv[i*4+3]=t.w;
      float4 u = *(const float4*)(csp + st*16 + i*4);
      Cv[i*4]=u.x; Cv[i*4+1]=u.y; Cv[i*4+2]=u.z; Cv[i*4+3]=u.w;
    }
    float pc = 0.f;
    #pragma unroll
    for(int s=0;s<16;s++){
      float a = __expf(dt*A[s]);
      h[s] = a*h[s] + dx*Bv[s];
      pc += h[s]*Cv[s];
    }
    ysp[st*18] = pc;
  }
}

// ---------------- K9: mamba epilogue + y_final ----------------
__global__ __launch_bounds__(256) void mamba_out_kernel(
    const float* __restrict__ YST_L, const float* __restrict__ XI_L,
    const float* __restrict__ ZZ_L, const float* __restrict__ Dp,
    const float* __restrict__ out_w, const float* __restrict__ altho,
    const float* __restrict__ ynew, float* __restrict__ yfin){
  __shared__ float s_ow[9*18], s_dp[18];
  for(int i=threadIdx.x;i<162;i+=256) s_ow[i]=out_w[i];
  if(threadIdx.x<18) s_dp[threadIdx.x]=Dp[threadIdx.x];
  __syncthreads();
  int idx = blockIdx.x*blockDim.x + threadIdx.x;
  int b = idx>>14, l = idx&16383;
  size_t lb = (size_t)b*LSEQ + l;
  float y[18];
  #pragma unroll
  for(int d=0;d<18;d++){
    float z = ZZ_L[lb*18+d];
    float sz = z/(1.f+__expf(-z));
    y[d] = (YST_L[lb*18+d] + s_dp[d]*XI_L[lb*18+d]) * sz;
  }
  float av = altho[0];
  float sp = fmaxf(av,0.f)+__logf(1.f+__expf(-fabsf(av)));
  float wgt = fmaxf(sp, 0.01f);
  int h = ((l>>8)<<1) | (l&1);
  int w = (l>>1)&127;
  int pix = h*WW + w;
  #pragma unroll
  for(int m=0;m<9;m++){
    float a=0.f;
    #pragma unroll
    for(int d=0;d<18;d++) a += y[d]*s_ow[m*18+d];
    size_t o = ((size_t)(b*9+m))*HW + pix;
    yfin[o] = wgt*a + ynew[o];
  }
}

// ---------------- K10: fused sample + 9x1 conv; A reg-pipelined, F fp16-high --------
__global__ __launch_bounds__(256) void sample_conv_kernel(
    const _Float16* __restrict__ xTh, const float* __restrict__ yfin,
    const _Float16* __restrict__ AH, const _Float16* __restrict__ AL,
    const float* __restrict__ bias, float* __restrict__ outpre,
    float* __restrict__ gn2sums){
  __shared__ _Float16 F[2][64][72];      // [buf][px][ci pad 72]
  __shared__ float sred2[16][2];
  int blk0 = blockIdx.x;                 // 1024 = 8 XCDs * 128
  int blk = (blk0&7)*128 + (blk0>>3);
  int wo0 = (blk&1)*64;
  int ho  = (blk>>1)&127;
  int b   = blk>>8;
  int lane = threadIdx.x&63;
  int wv   = threadIdx.x>>6;             // 0..3
  int l32  = lane&31, g = lane>>5;
  int co0 = (wv&1)*32, pxh = (wv>>1)*32;
  int px = lane;
  int wo = wo0 + px;
  if(threadIdx.x<32) ((float*)sred2)[threadIdx.x]=0.f;

  const _Float16* ahbase = AH + ((size_t)(co0 + l32)*2 + g)*8;
  const _Float16* albase = AL + ((size_t)(co0 + l32)*2 + g)*8;

  floatx16 acc;
  #pragma unroll
  for(int r=0;r<16;r++) acc[r]=0.f;

  half8 h0[2], h1[2]; _Float16 wyh = (_Float16)0.f;
  auto gather = [&](int k){
    float yv = yfin[((size_t)(b*9+k))*HW + ho*WW + wo];
    float py = fminf(fmaxf(yv,0.f),127.f);
    float y0f = floorf(py);
    wyh = (_Float16)(py - y0f);
    int iy0 = (int)y0f;
    int iy1 = min(iy0+1,127);
    int xc  = min(max(wo + k - 4, 0), 127);
    size_t o0 = (((size_t)(b*HH+iy0))*WW + xc)*64 + wv*16;
    size_t o1 = (((size_t)(b*HH+iy1))*WW + xc)*64 + wv*16;
    h0[0] = *(const half8*)(xTh + o0);
    h0[1] = *(const half8*)(xTh + o0 + 8);
    h1[0] = *(const half8*)(xTh + o1);
    h1[1] = *(const half8*)(xTh + o1 + 8);
  };
  auto writeF = [&](int buf){
    half8 w8 = {wyh,wyh,wyh,wyh,wyh,wyh,wyh,wyh};
    #pragma unroll
    for(int q=0;q<2;q++){
      half8 r = h0[q] + (h1[q]-h0[q])*w8;   // packed fp16 lerp
      *(half8*)&F[buf][px][wv*16 + q*8] = r;
    }
  };

  // A(0) preload into registers; pipeline A(k+1) one iteration ahead so MFMAs
  // never wait on same-iteration global loads (vmcnt drains oldest-first).
  half8 ahc[4], alc[4];
  #pragma unroll
  for(int q=0;q<4;q++){
    ahc[q] = *(const half8*)(ahbase + (size_t)q*1024);
    alc[q] = *(const half8*)(albase + (size_t)q*1024);
  }
  gather(0); writeF(0);
  __syncthreads();
  #pragma unroll
  for(int k=0;k<9;k++){
    half8 ahn[4], aln[4];
    if(k<8){
      #pragma unroll
      for(int q=0;q<4;q++){
        ahn[q] = *(const half8*)(ahbase + (size_t)((k+1)*4+q)*1024);
        aln[q] = *(const half8*)(albase + (size_t)((k+1)*4+q)*1024);
      }
      gather(k+1);
    }
    int buf = k&1;
    #pragma unroll
    for(int q=0;q<4;q++){
      half8 bh = *(const half8*)&F[buf][pxh + l32][q*16 + g*8];
      acc = __builtin_amdgcn_mfma_f32_32x32x16_f16(ahc[q], bh, acc, 0,0,0);
      acc = __builtin_amdgcn_mfma_f32_32x32x16_f16(alc[q], bh, acc, 0,0,0);
    }
    if(k<8){
      writeF((k+1)&1);
      __syncthreads();
      #pragma unroll
      for(int q=0;q<4;q++){ ahc[q]=ahn[q]; alc[q]=aln[q]; }
    }
  }
  // epilogue: write + per-quad stats.  group = co0/4 + 2*(r>>2) + g
  float qs[4][2] = {{0,0},{0,0},{0,0},{0,0}};
  #pragma unroll
  for(int r=0;r<16;r++){
    int row = (r&3) + 8*(r>>2) + 4*g;
    int co = co0 + row;
    float v = acc[r] + bias[co];
    outpre[((size_t)(b*64+co))*HW + ho*WW + wo0 + pxh + l32] = v;
    qs[r>>2][0] += v; qs[r>>2][1] += v*v;
  }
  #pragma unroll
  for(int qi=0;qi<4;qi++){
    int gq = (co0>>2) + 2*qi + g;
    atomicAdd(&sred2[gq][0], qs[qi][0]);
    atomicAdd(&sred2[gq][1], qs[qi][1]);
  }
  __syncthreads();
  if(threadIdx.x<32) atomicAdd(&gn2sums[b*32+threadIdx.x], ((float*)sred2)[threadIdx.x]);
}

// ---------------- K12: final GN apply (inline stats) ----------------
__global__ __launch_bounds__(256) void gn2_apply_kernel(const float* __restrict__ src,
                                                        const float* __restrict__ gn2sums,
                                                        const float* __restrict__ gam,
                                                        const float* __restrict__ bet,
                                                        float* __restrict__ dst){
  int idx = blockIdx.x*blockDim.x + threadIdx.x;  // BB*64*HW
  int c = (idx>>14)&63;
  int b = idx>>20;
  int gi = b*32 + (c>>2)*2;
  float S = gn2sums[gi], S2 = gn2sums[gi+1];
  float mu = S*(1.f/65536.f);
  float inv = rsqrtf(S2*(1.f/65536.f) - mu*mu + 1e-5f);
  dst[idx] = (src[idx]-mu)*inv*gam[c] + bet[c];
}

extern "C" void kernel_launch(void* const* d_in, const int* in_sizes, int n_in,
                              void* d_out, int out_size, void* d_ws, size_t ws_size,
                              hipStream_t stream){
  const float* x        = (const float*)d_in[0];
  const float* offset_w = (const float*)d_in[1];
  const float* offset_b = (const float*)d_in[2];
  const float* gno_g    = (const float*)d_in[3];
  const float* gno_b    = (const float*)d_in[4];
  const float* altho    = (const float*)d_in[5];
  const float* in_proj  = (const float*)d_in[6];
  const float* conv1d_w = (const float*)d_in[7];
  const float* conv1d_b = (const float*)d_in[8];
  const float* x_proj   = (const float*)d_in[9];
  const float* dt_w     = (const float*)d_in[10];
  const float* dt_b     = (const float*)d_in[11];
  const float* A_log    = (const float*)d_in[12];
  const float* D_p      = (const float*)d_in[13];
  const float* out_proj = (const float*)d_in[14];
  const float* dsc_w    = (const float*)d_in[15];
  const float* dsc_b    = (const float*)d_in[16];
  const float* gn_g     = (const float*)d_in[17];
  const float* gn_b     = (const float*)d_in[18];
  float* out = (float*)d_out;
  float* ws  = (float*)d_ws;
  if(ws_size < WS_TOTAL*sizeof(float)) return;

  float* off_raw = ws + OFF_RAW_O;
  float* yseqT   = ws + YSEQT_O;
  float* ynew    = ws + YNEW_O;
  float* gn1s    = ws + GN1_O;
  float* DT_L    = ws + DT_O;
  float* XI_L    = ws + XI_O;
  float* ZZ_L    = ws + ZZ_O;
  float* BS_L    = ws + BS_O;
  float* CS_L    = ws + CS_O;
  float* CP      = ws + CP_O;
  float* CH      = ws + CHC_O;
  float* HIN     = ws + HIN_O;
  float* YST_L   = ws + YS_O;
  float* yfin    = ws + YFIN_O;
  _Float16* xTh  = (_Float16*)(ws + XTH_O);
  _Float16* xTl  = (_Float16*)(ws + XTL_O);
  float* outpre  = ws + OUTPRE_O;
  _Float16* AH   = (_Float16*)(ws + WT_O);
  _Float16* AL   = (_Float16*)(ws + WT_O) + 36864;
  _Float16* AOH  = (_Float16*)(ws + AO_O);
  _Float16* AOL  = (_Float16*)(ws + AO_O) + 9216;
  float* Amat    = ws + AMAT_O;
  float* gn2s    = ws + GN2_O;

  prep_kernel<<<dim3(182), dim3(256), 0, stream>>>(dsc_w, offset_w, A_log, AH, AL, AOH, AOL,
                                                   Amat, gn1s, gn2s);
  transpose_x_kernel<<<dim3(1024), dim3(256), 0, stream>>>(x, xTh, xTl);
  off_conv_kernel<<<dim3(512), dim3(256), 0, stream>>>(xTh, AOH, AOL, offset_b, off_raw, gn1s);
  gn1_apply_kernel<<<dim3(256), dim3(256), 0, stream>>>(off_raw, gn1s, gno_g, gno_b, yseqT, ynew);
  mamba_feat_kernel<<<dim3(256), dim3(256), 0, stream>>>(yseqT, in_proj, conv1d_w, conv1d_b,
                                                         x_proj, dt_w, dt_b,
                                                         DT_L, XI_L, ZZ_L, BS_L, CS_L);
  scan_pass1<<<dim3(BB*NCH/16), dim3(288), 0, stream>>>(DT_L, XI_L, BS_L, Amat, CP, CH);
  scan_carry_kernel<<<dim3(288), dim3(256), 0, stream>>>(CP, CH, HIN);
  scan_pass2<<<dim3(BB*NCH/16), dim3(288), 0, stream>>>(DT_L, XI_L, BS_L, CS_L, Amat, HIN, YST_L);
  mamba_out_kernel<<<dim3(256), dim3(256), 0, stream>>>(YST_L, XI_L, ZZ_L, D_p, out_proj, altho,
                                                        ynew, yfin);
  sample_conv_kernel<<<dim3(1024), dim3(256), 0, stream>>>(xTh, yfin, AH, AL, dsc_b, outpre, gn2s);
  gn2_apply_kernel<<<dim3(16384), dim3(256), 0, stream>>>(outpre, gn2s, gn_g, gn_b, out);
}